// Round 6
// baseline (13144.476 us; speedup 1.0000x reference)
//
#include <hip/hip_runtime.h>

typedef __attribute__((ext_vector_type(2))) float f32x2;
typedef __attribute__((ext_vector_type(4))) float f32x4;

// ---------------- sentinel (workspace too small -> report ws MiB via absmax) ----------------
__global__ void fillsent(float* __restrict__ out, int n, float val)
{
    for (int i = blockIdx.x * blockDim.x + threadIdx.x; i < n; i += gridDim.x * blockDim.x)
        out[i] = val;
}

// ---------------- d_out = interp (f32 copy) ----------------
__global__ void cpy4(const f32x4* __restrict__ in, f32x4* __restrict__ out, int n4)
{
    for (int i = blockIdx.x * blockDim.x + threadIdx.x; i < n4; i += gridDim.x * blockDim.x)
        out[i] = in[i];
}

// ---------------- RMSNorm over D=2048, f32 -> f32 ----------------
__global__ __launch_bounds__(256) void rms32(const float* __restrict__ in,
                                             const float* __restrict__ sc,
                                             float* __restrict__ out)
{
    __shared__ float red[4];
    const int row = blockIdx.x, tid = threadIdx.x;
    const float* p = in + (size_t)row * 2048 + tid * 8;
    f32x4 a = *(const f32x4*)p;
    f32x4 b = *(const f32x4*)(p + 4);
    float ss = a[0]*a[0] + a[1]*a[1] + a[2]*a[2] + a[3]*a[3]
             + b[0]*b[0] + b[1]*b[1] + b[2]*b[2] + b[3]*b[3];
    for (int d = 1; d < 64; d <<= 1) ss += __shfl_xor(ss, d, 64);
    if ((tid & 63) == 0) red[tid >> 6] = ss;
    __syncthreads();
    float rs = rsqrtf((red[0] + red[1] + red[2] + red[3]) * (1.0f / 2048.0f) + 1e-6f);
    const float* s = sc + tid * 8;
    float* o = out + (size_t)row * 2048 + tid * 8;
#pragma unroll
    for (int i = 0; i < 4; ++i) o[i] = a[i] * rs * s[i];
#pragma unroll
    for (int i = 0; i < 4; ++i) o[4 + i] = b[i] * rs * s[4 + i];
}

// ---------------- per-head RMSNorm over 128, in-place f32, one wave per (row,head) ----------------
__global__ __launch_bounds__(256) void qkn32(float* __restrict__ buf, const float* __restrict__ sc)
{
    const int tid = threadIdx.x, w = tid >> 6, l = tid & 63;
    float* p = buf + ((size_t)blockIdx.x * 4 + w) * 128 + l * 2;
    f32x2 v = *(const f32x2*)p;
    float ss = v[0] * v[0] + v[1] * v[1];
    for (int d = 1; d < 64; d <<= 1) ss += __shfl_xor(ss, d, 64);
    float rs = rsqrtf(ss * (1.0f / 128.0f) + 1e-6f);
    v[0] *= rs * sc[l * 2];
    v[1] *= rs * sc[l * 2 + 1];
    *(f32x2*)p = v;
}

// ---------------- naive f32 GEMM: C[M,N] = A[M,K] * B[K,N] ----------------
// A row stride = K; B row stride = ldb, column window starts at bcol0; C row stride = N.
// EPI 0: C = acc
// EPI 1: C = acc + res           (residual add, res stride N)
// EPI 2: C = silu(C) * acc       (in-place gated-MLP combine; C pre-holds h@wi0 half)
// EPI 3: C += acc                (accumulate into pre-initialized C)
template <int EPI>
__global__ __launch_bounds__(256)
void sgemm(const float* __restrict__ A, const float* __restrict__ B, float* __restrict__ C,
           const float* __restrict__ res, int M, int N, int K, int ldb, int bcol0)
{
    __shared__ float As[16][68];  // As[k][m]
    __shared__ float Bs[16][68];  // Bs[k][n]
    const int tid = threadIdx.x, tx = tid & 15, ty = tid >> 4;
    const int m0 = blockIdx.y * 64, n0 = blockIdx.x * 64;
    float acc[4][4] = {};
    for (int k0 = 0; k0 < K; k0 += 16) {
#pragma unroll
        for (int j = 0; j < 4; ++j) {
            int i = tid + j * 256;
            As[i & 15][i >> 4] = A[(size_t)(m0 + (i >> 4)) * K + k0 + (i & 15)];
        }
#pragma unroll
        for (int j = 0; j < 4; ++j) {
            int i = tid + j * 256;
            Bs[i >> 6][i & 63] = B[(size_t)(k0 + (i >> 6)) * ldb + bcol0 + n0 + (i & 63)];
        }
        __syncthreads();
#pragma unroll
        for (int kk = 0; kk < 16; ++kk) {
            f32x4 a = *(const f32x4*)&As[kk][ty * 4];
            f32x4 b = *(const f32x4*)&Bs[kk][tx * 4];
#pragma unroll
            for (int u = 0; u < 4; ++u)
#pragma unroll
                for (int v = 0; v < 4; ++v)
                    acc[u][v] += a[u] * b[v];
        }
        __syncthreads();
    }
#pragma unroll
    for (int u = 0; u < 4; ++u)
#pragma unroll
        for (int v = 0; v < 4; ++v) {
            int m = m0 + ty * 4 + u, n = n0 + tx * 4 + v;
            size_t idx = (size_t)m * N + n;
            float val = acc[u][v];
            if constexpr (EPI == 0) {
                C[idx] = val;
            } else if constexpr (EPI == 1) {
                C[idx] = val + res[idx];
            } else if constexpr (EPI == 2) {
                float sa = C[idx];
                C[idx] = sa / (1.0f + __expf(-sa)) * val;
            } else {
                C[idx] += val;
            }
        }
}

// ---------------- naive causal attention: one wave per (b,h,sq), online softmax, f32 ----------------
// Q,K,V,O all [B*S][H*128] f32 (rows b*2048+s, head h at cols h*128..h*128+127)
__global__ __launch_bounds__(256) void flashn(const float* __restrict__ Q, const float* __restrict__ Km,
                                              const float* __restrict__ V, float* __restrict__ O)
{
    const int tid = threadIdx.x, w = tid >> 6, l = tid & 63;
    const int gid = blockIdx.x * 4 + w;        // ((b*16+h)<<11) | sq
    const int sq = gid & 2047, bh = gid >> 11, b = bh >> 4, h = bh & 15;
    const size_t rowb = (size_t)b * 2048;
    const float* qp = Q + (rowb + sq) * 2048 + h * 128 + l * 2;
    f32x2 qv = *(const f32x2*)qp;
    float m = -1e30f, s = 0.0f, o0 = 0.0f, o1 = 0.0f;
    for (int sk = 0; sk <= sq; ++sk) {
        const float* kp = Km + (rowb + sk) * 2048 + h * 128 + l * 2;
        f32x2 kv = *(const f32x2*)kp;
        float d = qv[0] * kv[0] + qv[1] * kv[1];
        for (int t = 1; t < 64; t <<= 1) d += __shfl_xor(d, t, 64);
        float mn = fmaxf(m, d);
        float c = __expf(m - mn), p = __expf(d - mn);
        const float* vp = V + (rowb + sk) * 2048 + h * 128 + l * 2;
        f32x2 vv = *(const f32x2*)vp;
        s = s * c + p;
        o0 = o0 * c + p * vv[0];
        o1 = o1 * c + p * vv[1];
        m = mn;
    }
    float* op = O + (rowb + sq) * 2048 + h * 128 + l * 2;
    op[0] = o0 / s;
    op[1] = o1 / s;
}

extern "C" void kernel_launch(void* const* d_in, const int* in_sizes, int n_in,
                              void* d_out, int out_size, void* d_ws, size_t ws_size,
                              hipStream_t stream)
{
    (void)in_sizes; (void)n_in;
    const float* x    = (const float*)d_in[0];
    const float* ln1  = (const float*)d_in[1];
    const float* wq   = (const float*)d_in[2];
    const float* wk   = (const float*)d_in[3];
    const float* wv   = (const float*)d_in[4];
    const float* qln  = (const float*)d_in[5];
    const float* kln  = (const float*)d_in[6];
    const float* wo   = (const float*)d_in[7];
    const float* ln2  = (const float*)d_in[8];
    const float* wi0  = (const float*)d_in[9];
    const float* wi1  = (const float*)d_in[10];
    const float* wout = (const float*)d_in[11];

    const size_t MB = 1ull << 20;
    char* ws = (char*)d_ws;
    if (ws_size < 224 * MB) {
        fillsent<<<2048, 256, 0, stream>>>((float*)d_out, out_size, (float)(ws_size >> 20));
        return;
    }

    // Arena (224 MiB), all f32 [4096][2048] = 32 MiB slots unless noted:
    //   0: lnx -> attn
    //  32: q   -> h
    //  64: k
    //  96: v
    // 128: interp
    // 160: ga [4096][4096] = 64 MiB (per-half MLP scratch)
    float* lnx    = (float*)(ws + 0 * MB);
    float* attn   = lnx;
    float* q      = (float*)(ws + 32 * MB);
    float* h      = q;
    float* k      = (float*)(ws + 64 * MB);
    float* v      = (float*)(ws + 96 * MB);
    float* interp = (float*)(ws + 128 * MB);
    float* ga     = (float*)(ws + 160 * MB);
    float* out    = (float*)d_out;

    dim3 blk(256);
    rms32<<<4096, blk, 0, stream>>>(x, ln1, lnx);

    sgemm<0><<<dim3(32, 64), blk, 0, stream>>>(lnx, wq, q, nullptr, 4096, 2048, 2048, 2048, 0);
    sgemm<0><<<dim3(32, 64), blk, 0, stream>>>(lnx, wk, k, nullptr, 4096, 2048, 2048, 2048, 0);
    sgemm<0><<<dim3(32, 64), blk, 0, stream>>>(lnx, wv, v, nullptr, 4096, 2048, 2048, 2048, 0);

    qkn32<<<16384, blk, 0, stream>>>(q, qln);
    qkn32<<<16384, blk, 0, stream>>>(k, kln);

    flashn<<<16384, blk, 0, stream>>>(q, k, v, attn);

    sgemm<1><<<dim3(32, 64), blk, 0, stream>>>(attn, wo, interp, x, 4096, 2048, 2048, 2048, 0);

    rms32<<<4096, blk, 0, stream>>>(interp, ln2, h);

    // d_out = interp, then accumulate the two MLP halves: out += g_half @ wout_half
    cpy4<<<2048, blk, 0, stream>>>((const f32x4*)interp, (f32x4*)out, 2097152);
    for (int hf = 0; hf < 2; ++hf) {
        sgemm<0><<<dim3(64, 64), blk, 0, stream>>>(h, wi0, ga, nullptr, 4096, 4096, 2048, 8192, hf * 4096);
        sgemm<2><<<dim3(64, 64), blk, 0, stream>>>(h, wi1, ga, nullptr, 4096, 4096, 2048, 8192, hf * 4096);
        sgemm<3><<<dim3(32, 64), blk, 0, stream>>>(ga, wout + (size_t)hf * 4096 * 2048, out, nullptr,
                                                   4096, 2048, 4096, 2048, 0);
    }
}

// Round 8
// 1015.706 us; speedup vs baseline: 12.9412x; 12.9412x over previous
//
#include <hip/hip_runtime.h>

typedef unsigned short u16;
typedef unsigned int u32;
typedef __attribute__((ext_vector_type(8))) short bf16x8;
typedef __attribute__((ext_vector_type(2))) float f32x2;
typedef __attribute__((ext_vector_type(4))) float f32x4;
typedef __attribute__((ext_vector_type(4))) u32 u32x4;

#define DEV __device__ __forceinline__

DEV u16 f2bf(float x) {
    u32 u = __builtin_bit_cast(u32, x);
    u += 0x7fffu + ((u >> 16) & 1u);
    return (u16)(u >> 16);
}
DEV float bf2f(u16 b) {
    u32 u = ((u32)b) << 16;
    return __builtin_bit_cast(float, u);
}

#define MFMA16(a, b, c) __builtin_amdgcn_mfma_f32_16x16x32_bf16((a), (b), (c), 0, 0, 0)

// async global->LDS, 16B per lane; LDS dest = wave-uniform base + lane*16
#define GLL16(gp, lp)                                                      \
    __builtin_amdgcn_global_load_lds(                                      \
        (const __attribute__((address_space(1))) u32*)(const void*)(gp),   \
        (__attribute__((address_space(3))) u32*)(void*)(lp), 16, 0, 0)

// ---------------- sentinel (workspace too small -> report ws MiB via absmax) ----------------
__global__ void fillsent(float* __restrict__ out, int n, float val)
{
    for (int i = blockIdx.x * blockDim.x + threadIdx.x; i < n; i += gridDim.x * blockDim.x)
        out[i] = val;
}

// ---------------- weight cast+transpose: f32 [K,N] -> bf16 [N,K] ----------------
__global__ void wtrans(const float* __restrict__ in, u16* __restrict__ out, int K, int N)
{
    __shared__ u16 t[64][65];
    const int n0 = blockIdx.x * 64, k0 = blockIdx.y * 64, tid = threadIdx.x;
    for (int i = tid; i < 4096; i += 256) {
        int r = i >> 6, c = i & 63;
        t[r][c] = f2bf(in[(size_t)(k0 + r) * N + n0 + c]);
    }
    __syncthreads();
    for (int i = tid; i < 4096; i += 256) {
        int r = i >> 6, c = i & 63;
        out[(size_t)(n0 + r) * K + k0 + c] = t[c][r];
    }
}

// ---------------- weight cast+transpose, hi/lo split: f32 [K,N] -> bf16 hi/lo [N,K] ----------------
__global__ void wtrans_split(const float* __restrict__ in, u16* __restrict__ ohi,
                             u16* __restrict__ olo, int K, int N)
{
    __shared__ float t[64][65];
    const int n0 = blockIdx.x * 64, k0 = blockIdx.y * 64, tid = threadIdx.x;
    for (int i = tid; i < 4096; i += 256) {
        int r = i >> 6, c = i & 63;
        t[r][c] = in[(size_t)(k0 + r) * N + n0 + c];
    }
    __syncthreads();
    for (int i = tid; i < 4096; i += 256) {
        int r = i >> 6, c = i & 63;
        float v = t[c][r];
        u16 h = f2bf(v);
        size_t idx = (size_t)(n0 + r) * K + k0 + c;
        ohi[idx] = h;
        olo[idx] = f2bf(v - bf2f(h));
    }
}

// ---------------- V relayout: bf16 [BH,S,128] -> [BH,128,S] ----------------
__global__ void vtrans(const u16* __restrict__ in, u16* __restrict__ out)
{
    __shared__ u16 t[64][65];
    const int d0 = blockIdx.x * 64, s0 = blockIdx.y * 64, bh = blockIdx.z, tid = threadIdx.x;
    const u16* ip = in + (size_t)bh * 2048 * 128;
    u16* op = out + (size_t)bh * 128 * 2048;
    for (int i = tid; i < 4096; i += 256) {
        int r = i >> 6, c = i & 63;
        t[r][c] = ip[(size_t)(s0 + r) * 128 + d0 + c];
    }
    __syncthreads();
    for (int i = tid; i < 4096; i += 256) {
        int r = i >> 6, c = i & 63;
        op[(size_t)(d0 + r) * 2048 + s0 + c] = t[c][r];
    }
}

// ---------------- RMSNorm over D=2048: f32 in -> bf16 out (single) ----------------
__global__ __launch_bounds__(256) void rmsnorm_d(const float* __restrict__ in,
                                                 const float* __restrict__ sc,
                                                 u16* __restrict__ out)
{
    __shared__ float red[4];
    const int row = blockIdx.x, tid = threadIdx.x;
    const float* p = in + (size_t)row * 2048 + tid * 8;
    f32x4 a = *(const f32x4*)p;
    f32x4 b = *(const f32x4*)(p + 4);
    float ss = a[0]*a[0] + a[1]*a[1] + a[2]*a[2] + a[3]*a[3]
             + b[0]*b[0] + b[1]*b[1] + b[2]*b[2] + b[3]*b[3];
    for (int d = 1; d < 64; d <<= 1) ss += __shfl_xor(ss, d, 64);
    if ((tid & 63) == 0) red[tid >> 6] = ss;
    __syncthreads();
    float rs = rsqrtf((red[0] + red[1] + red[2] + red[3]) * (1.0f / 2048.0f) + 1e-6f);
    const float* s = sc + tid * 8;
    u32x4 ov;
#pragma unroll
    for (int i = 0; i < 2; ++i) {
        f32x4 v = i ? b : a;
#pragma unroll
        for (int j = 0; j < 2; ++j) {
            float v0 = v[j * 2] * rs * s[i * 4 + j * 2];
            float v1 = v[j * 2 + 1] * rs * s[i * 4 + j * 2 + 1];
            ov[i * 2 + j] = (u32)f2bf(v0) | ((u32)f2bf(v1) << 16);
        }
    }
    *(u32x4*)(out + (size_t)row * 2048 + tid * 8) = ov;
}

// ---------------- RMSNorm over D=2048: f32 in -> bf16 hi/lo out ----------------
__global__ __launch_bounds__(256) void rmsnorm_split(const float* __restrict__ in,
                                                     const float* __restrict__ sc,
                                                     u16* __restrict__ ohi,
                                                     u16* __restrict__ olo)
{
    __shared__ float red[4];
    const int row = blockIdx.x, tid = threadIdx.x;
    const float* p = in + (size_t)row * 2048 + tid * 8;
    f32x4 a = *(const f32x4*)p;
    f32x4 b = *(const f32x4*)(p + 4);
    float ss = a[0]*a[0] + a[1]*a[1] + a[2]*a[2] + a[3]*a[3]
             + b[0]*b[0] + b[1]*b[1] + b[2]*b[2] + b[3]*b[3];
    for (int d = 1; d < 64; d <<= 1) ss += __shfl_xor(ss, d, 64);
    if ((tid & 63) == 0) red[tid >> 6] = ss;
    __syncthreads();
    float rs = rsqrtf((red[0] + red[1] + red[2] + red[3]) * (1.0f / 2048.0f) + 1e-6f);
    const float* s = sc + tid * 8;
    u32x4 oh, ol;
#pragma unroll
    for (int i = 0; i < 2; ++i) {
        f32x4 v = i ? b : a;
#pragma unroll
        for (int j = 0; j < 2; ++j) {
            float v0 = v[j * 2] * rs * s[i * 4 + j * 2];
            float v1 = v[j * 2 + 1] * rs * s[i * 4 + j * 2 + 1];
            u16 h0 = f2bf(v0), h1 = f2bf(v1);
            u16 l0 = f2bf(v0 - bf2f(h0)), l1 = f2bf(v1 - bf2f(h1));
            oh[i * 2 + j] = (u32)h0 | ((u32)h1 << 16);
            ol[i * 2 + j] = (u32)l0 | ((u32)l1 << 16);
        }
    }
    *(u32x4*)(ohi + (size_t)row * 2048 + tid * 8) = oh;
    *(u32x4*)(olo + (size_t)row * 2048 + tid * 8) = ol;
}

// ---------------- per-head RMSNorm over HD=128: f32 in -> bf16 hi/lo out, one wave/row ----------------
__global__ __launch_bounds__(256) void qknorm_split(const float* __restrict__ in,
                                                    const float* __restrict__ sc,
                                                    u16* __restrict__ ohi,
                                                    u16* __restrict__ olo)
{
    const int tid = threadIdx.x, w = tid >> 6, l = tid & 63;
    const size_t row = (size_t)blockIdx.x * 4 + w;
    f32x2 v = *(const f32x2*)(in + row * 128 + l * 2);
    float ss = v[0] * v[0] + v[1] * v[1];
    for (int d = 1; d < 64; d <<= 1) ss += __shfl_xor(ss, d, 64);
    float rs = rsqrtf(ss * (1.0f / 128.0f) + 1e-6f);
    float v0 = v[0] * rs * sc[l * 2];
    float v1 = v[1] * rs * sc[l * 2 + 1];
    u16 h0 = f2bf(v0), h1 = f2bf(v1);
    u16 l0 = f2bf(v0 - bf2f(h0)), l1 = f2bf(v1 - bf2f(h1));
    *(u32*)(ohi + row * 128 + l * 2) = (u32)h0 | ((u32)h1 << 16);
    *(u32*)(olo + row * 128 + l * 2) = (u32)l0 | ((u32)l1 << 16);
}

// ---------------- GEMM: C[M,N] = A[M,K](bf16) x Bt[N,K](bf16), 128x128 tile, BK=64 ----------------
// EPI 0 QKV : write bf16 scattered to [BH,S,128]
// EPI 1 RESF: outf = acc + resf (f32 out, f32 residual)
template <int EPI>
__global__ __launch_bounds__(256, 2)
void gemm_bt_k(const u16* __restrict__ A, const u16* __restrict__ Bt,
               float* __restrict__ outf, u16* __restrict__ outb,
               const float* __restrict__ resf, int M, int N, int K)
{
    __shared__ u16 As[128 * 64];
    __shared__ u16 Bs[128 * 64];
    const int tid = threadIdx.x, w = tid >> 6, l = tid & 63;
    const int lr = l & 15, lg = l >> 4;
    const int m0 = blockIdx.y * 128, n0 = blockIdx.x * 128;
    const int wr = (w >> 1) * 64, wc = (w & 1) * 64;
    f32x4 acc[4][4] = {};
    int prow[4], pcol[4];
#pragma unroll
    for (int j = 0; j < 4; ++j) {
        int p = (j * 4 + w) * 1024 + l * 16;
        prow[j] = p >> 7;
        pcol[j] = (p ^ ((prow[j] & 7) << 4)) & 127;
    }
    const char* Ab = (const char*)A;
    const char* Bb = (const char*)Bt;
    const size_t ldb = (size_t)K * 2;
    const int nkt = K / 64;
    for (int kt = 0; kt < nkt; ++kt) {
#pragma unroll
        for (int j = 0; j < 4; ++j) {
            GLL16(Ab + (size_t)(m0 + prow[j]) * ldb + kt * 128 + pcol[j], (char*)As + (j * 4 + w) * 1024);
            GLL16(Bb + (size_t)(n0 + prow[j]) * ldb + kt * 128 + pcol[j], (char*)Bs + (j * 4 + w) * 1024);
        }
        __syncthreads();
#pragma unroll
        for (int kc = 0; kc < 2; ++kc) {
            bf16x8 af[4], bf[4];
#pragma unroll
            for (int f = 0; f < 4; ++f) {
                int ra = wr + f * 16 + lr;
                af[f] = *(const bf16x8*)((const char*)As + ((ra * 128 + kc * 64 + lg * 16) ^ ((ra & 7) << 4)));
                int rb = wc + f * 16 + lr;
                bf[f] = *(const bf16x8*)((const char*)Bs + ((rb * 128 + kc * 64 + lg * 16) ^ ((rb & 7) << 4)));
            }
#pragma unroll
            for (int mf = 0; mf < 4; ++mf)
#pragma unroll
                for (int nf = 0; nf < 4; ++nf)
                    acc[mf][nf] = MFMA16(af[mf], bf[nf], acc[mf][nf]);
        }
        __syncthreads();
    }
#pragma unroll
    for (int mf = 0; mf < 4; ++mf) {
#pragma unroll
        for (int nf = 0; nf < 4; ++nf) {
#pragma unroll
            for (int r = 0; r < 4; ++r) {
                int m = m0 + wr + mf * 16 + lg * 4 + r;
                int n = n0 + wc + nf * 16 + lr;
                float v = acc[mf][nf][r];
                if constexpr (EPI == 0) {
                    outb[(((m >> 11) * 16 + (n >> 7)) << 18) + ((m & 2047) << 7) + (n & 127)] = f2bf(v);
                } else {
                    size_t idx = (size_t)m * N + n;
                    outf[idx] = v + resf[idx];
                }
            }
        }
    }
}

// ---------------- split-precision GEMM: C_f32 = (Ahi+Alo)(Bhi+Blo)^T, f32 scatter to [BH,S,128] ----------------
__global__ __launch_bounds__(256, 2)
void gemm3(const u16* __restrict__ Ahi, const u16* __restrict__ Alo,
           const u16* __restrict__ Bhi, const u16* __restrict__ Blo,
           float* __restrict__ outf, int M, int N, int K)
{
    __shared__ u16 Ah[128 * 64];
    __shared__ u16 Al[128 * 64];
    __shared__ u16 Bh[128 * 64];
    __shared__ u16 Bl[128 * 64];
    const int tid = threadIdx.x, w = tid >> 6, l = tid & 63;
    const int lr = l & 15, lg = l >> 4;
    const int m0 = blockIdx.y * 128, n0 = blockIdx.x * 128;
    const int wr = (w >> 1) * 64, wc = (w & 1) * 64;
    f32x4 acc[4][4] = {};
    int prow[4], pcol[4];
#pragma unroll
    for (int j = 0; j < 4; ++j) {
        int p = (j * 4 + w) * 1024 + l * 16;
        prow[j] = p >> 7;
        pcol[j] = (p ^ ((prow[j] & 7) << 4)) & 127;
    }
    const size_t ldb = (size_t)K * 2;
    const int nkt = K / 64;
    for (int kt = 0; kt < nkt; ++kt) {
#pragma unroll
        for (int j = 0; j < 4; ++j) {
            size_t ao = (size_t)(m0 + prow[j]) * ldb + kt * 128 + pcol[j];
            size_t bo = (size_t)(n0 + prow[j]) * ldb + kt * 128 + pcol[j];
            GLL16((const char*)Ahi + ao, (char*)Ah + (j * 4 + w) * 1024);
            GLL16((const char*)Alo + ao, (char*)Al + (j * 4 + w) * 1024);
            GLL16((const char*)Bhi + bo, (char*)Bh + (j * 4 + w) * 1024);
            GLL16((const char*)Blo + bo, (char*)Bl + (j * 4 + w) * 1024);
        }
        __syncthreads();
#pragma unroll
        for (int kc = 0; kc < 2; ++kc) {
            bf16x8 ahf[4], alf[4], bhf[4], blf[4];
#pragma unroll
            for (int f = 0; f < 4; ++f) {
                int ra = wr + f * 16 + lr;
                int oa = (ra * 128 + kc * 64 + lg * 16) ^ ((ra & 7) << 4);
                ahf[f] = *(const bf16x8*)((const char*)Ah + oa);
                alf[f] = *(const bf16x8*)((const char*)Al + oa);
                int rb = wc + f * 16 + lr;
                int ob = (rb * 128 + kc * 64 + lg * 16) ^ ((rb & 7) << 4);
                bhf[f] = *(const bf16x8*)((const char*)Bh + ob);
                blf[f] = *(const bf16x8*)((const char*)Bl + ob);
            }
#pragma unroll
            for (int mf = 0; mf < 4; ++mf)
#pragma unroll
                for (int nf = 0; nf < 4; ++nf) {
                    acc[mf][nf] = MFMA16(ahf[mf], bhf[nf], acc[mf][nf]);
                    acc[mf][nf] = MFMA16(ahf[mf], blf[nf], acc[mf][nf]);
                    acc[mf][nf] = MFMA16(alf[mf], bhf[nf], acc[mf][nf]);
                }
        }
        __syncthreads();
    }
#pragma unroll
    for (int mf = 0; mf < 4; ++mf) {
#pragma unroll
        for (int nf = 0; nf < 4; ++nf) {
#pragma unroll
            for (int r = 0; r < 4; ++r) {
                int m = m0 + wr + mf * 16 + lg * 4 + r;
                int n = n0 + wc + nf * 16 + lr;
                outf[(((m >> 11) * 16 + (n >> 7)) << 18) + ((m & 2047) << 7) + (n & 127)] = acc[mf][nf][r];
            }
        }
    }
}

// ---------------- fused MLP up: g = silu(A@wi0) * (A@wi1), bf16 out ----------------
__global__ __launch_bounds__(256, 2)
void gemm_up(const u16* __restrict__ A, const u16* __restrict__ B0, const u16* __restrict__ B1,
             u16* __restrict__ G, int M, int N, int K)
{
    __shared__ u16 As[128 * 64];
    __shared__ u16 Bs0[128 * 64];
    __shared__ u16 Bs1[128 * 64];
    const int tid = threadIdx.x, w = tid >> 6, l = tid & 63;
    const int lr = l & 15, lg = l >> 4;
    const int m0 = blockIdx.y * 128, n0 = blockIdx.x * 128;
    const int wr = (w >> 1) * 64, wc = (w & 1) * 64;
    f32x4 acc0[4][4] = {}, acc1[4][4] = {};
    int prow[4], pcol[4];
#pragma unroll
    for (int j = 0; j < 4; ++j) {
        int p = (j * 4 + w) * 1024 + l * 16;
        prow[j] = p >> 7;
        pcol[j] = (p ^ ((prow[j] & 7) << 4)) & 127;
    }
    const size_t ldb = (size_t)K * 2;
    const int nkt = K / 64;
    for (int kt = 0; kt < nkt; ++kt) {
#pragma unroll
        for (int j = 0; j < 4; ++j) {
            GLL16((const char*)A + (size_t)(m0 + prow[j]) * ldb + kt * 128 + pcol[j], (char*)As + (j * 4 + w) * 1024);
            GLL16((const char*)B0 + (size_t)(n0 + prow[j]) * ldb + kt * 128 + pcol[j], (char*)Bs0 + (j * 4 + w) * 1024);
            GLL16((const char*)B1 + (size_t)(n0 + prow[j]) * ldb + kt * 128 + pcol[j], (char*)Bs1 + (j * 4 + w) * 1024);
        }
        __syncthreads();
#pragma unroll
        for (int kc = 0; kc < 2; ++kc) {
            bf16x8 af[4], b0f[4], b1f[4];
#pragma unroll
            for (int f = 0; f < 4; ++f) {
                int ra = wr + f * 16 + lr;
                af[f] = *(const bf16x8*)((const char*)As + ((ra * 128 + kc * 64 + lg * 16) ^ ((ra & 7) << 4)));
                int rb = wc + f * 16 + lr;
                int ob = (rb * 128 + kc * 64 + lg * 16) ^ ((rb & 7) << 4);
                b0f[f] = *(const bf16x8*)((const char*)Bs0 + ob);
                b1f[f] = *(const bf16x8*)((const char*)Bs1 + ob);
            }
#pragma unroll
            for (int mf = 0; mf < 4; ++mf)
#pragma unroll
                for (int nf = 0; nf < 4; ++nf) {
                    acc0[mf][nf] = MFMA16(af[mf], b0f[nf], acc0[mf][nf]);
                    acc1[mf][nf] = MFMA16(af[mf], b1f[nf], acc1[mf][nf]);
                }
        }
        __syncthreads();
    }
#pragma unroll
    for (int mf = 0; mf < 4; ++mf) {
#pragma unroll
        for (int nf = 0; nf < 4; ++nf) {
#pragma unroll
            for (int r = 0; r < 4; ++r) {
                int m = m0 + wr + mf * 16 + lg * 4 + r;
                int n = n0 + wc + nf * 16 + lr;
                float a = acc0[mf][nf][r];
                float b = acc1[mf][nf][r];
                G[(size_t)m * N + n] = f2bf(a / (1.0f + __expf(-a)) * b);
            }
        }
    }
}

// ---------------- causal flash attention, split-precision Q,K ----------------
// Qh/Ql,Kh/Kl: [BH,S,128] bf16; Vt: [BH,128,S] bf16; Out: [B,S,H,128] bf16
__global__ __launch_bounds__(256, 2)
void flash(const u16* __restrict__ Qh, const u16* __restrict__ Ql,
           const u16* __restrict__ Kh, const u16* __restrict__ Kl,
           const u16* __restrict__ Vt, u16* __restrict__ O)
{
    __shared__ u16 Ksh[64 * 128];  // rows 256B, swizzled
    __shared__ u16 Ksl[64 * 128];
    __shared__ u16 Vs[128 * 64];   // rows 128B, swizzled
    __shared__ u16 Ps[4][16 * 64]; // per-wave P, rows 128B, swizzled
    const int tid = threadIdx.x, w = tid >> 6, l = tid & 63;
    const int lr = l & 15, lg = l >> 4;
    const int qb0 = blockIdx.x * 64, bh = blockIdx.y;

    const size_t qoff = ((size_t)bh * 2048 + qb0 + w * 16) * 128;
    bf16x8 qfh[4], qfl[4];
#pragma unroll
    for (int kc = 0; kc < 4; ++kc) {
        qfh[kc] = *(const bf16x8*)(Qh + qoff + lr * 128 + kc * 32 + lg * 8);
        qfl[kc] = *(const bf16x8*)(Ql + qoff + lr * 128 + kc * 32 + lg * 8);
    }

    f32x4 o[8] = {};
    float mrun[4] = {-1e30f, -1e30f, -1e30f, -1e30f};
    float lrun[4] = {};

    int kgo[4], vdo[4], voff[4];
#pragma unroll
    for (int j = 0; j < 4; ++j) {
        int p = (j * 4 + w) * 1024 + l * 16;
        kgo[j] = p ^ (((p >> 8) & 7) << 4);
        int d = p >> 7, c0 = (p >> 4) & 7;
        vdo[j] = d;
        voff[j] = (c0 ^ (d & 7)) << 4;
    }
    const char* kbh = (const char*)(Kh + (size_t)bh * 2048 * 128);
    const char* kbl = (const char*)(Kl + (size_t)bh * 2048 * 128);
    const char* vbase = (const char*)(Vt + (size_t)bh * 128 * 2048);
    const int tmax = blockIdx.x;

    for (int t = 0; t <= tmax; ++t) {
        const char* kgh = kbh + (size_t)t * 16384;
        const char* kgl = kbl + (size_t)t * 16384;
        const char* vg = vbase + t * 128;
#pragma unroll
        for (int j = 0; j < 4; ++j) {
            GLL16(kgh + kgo[j], (char*)Ksh + (j * 4 + w) * 1024);
            GLL16(kgl + kgo[j], (char*)Ksl + (j * 4 + w) * 1024);
            GLL16(vg + (size_t)vdo[j] * 4096 + voff[j], (char*)Vs + (j * 4 + w) * 1024);
        }
        __syncthreads();

        // S = (Qh+Ql)(Kh+Kl)^T, lo*lo dropped
        f32x4 sf[4];
#pragma unroll
        for (int kf = 0; kf < 4; ++kf) {
            f32x4 a = {};
            int row = kf * 16 + lr;
#pragma unroll
            for (int kc = 0; kc < 4; ++kc) {
                int off = (row * 256 + kc * 64 + lg * 16) ^ ((row & 7) << 4);
                bf16x8 khf = *(const bf16x8*)((const char*)Ksh + off);
                bf16x8 klf = *(const bf16x8*)((const char*)Ksl + off);
                a = MFMA16(qfh[kc], khf, a);
                a = MFMA16(qfh[kc], klf, a);
                a = MFMA16(qfl[kc], khf, a);
            }
            sf[kf] = a;
        }
        if (t == tmax) {
#pragma unroll
            for (int kf = 0; kf < 4; ++kf)
#pragma unroll
                for (int r = 0; r < 4; ++r)
                    if (t * 64 + kf * 16 + lr > qb0 + w * 16 + lg * 4 + r) sf[kf][r] = -1e30f;
        }
        float scl[4];
#pragma unroll
        for (int r = 0; r < 4; ++r) {
            float m_ = fmaxf(fmaxf(sf[0][r], sf[1][r]), fmaxf(sf[2][r], sf[3][r]));
            m_ = fmaxf(m_, __shfl_xor(m_, 1, 64));
            m_ = fmaxf(m_, __shfl_xor(m_, 2, 64));
            m_ = fmaxf(m_, __shfl_xor(m_, 4, 64));
            m_ = fmaxf(m_, __shfl_xor(m_, 8, 64));
            float mn = fmaxf(mrun[r], m_);
            scl[r] = __expf(mrun[r] - mn);
            mrun[r] = mn;
            float s_ = 0.0f;
#pragma unroll
            for (int kf = 0; kf < 4; ++kf) {
                float e = __expf(sf[kf][r] - mn);
                sf[kf][r] = e;
                s_ += e;
            }
            s_ += __shfl_xor(s_, 1, 64);
            s_ += __shfl_xor(s_, 2, 64);
            s_ += __shfl_xor(s_, 4, 64);
            s_ += __shfl_xor(s_, 8, 64);
            lrun[r] = lrun[r] * scl[r] + s_;
        }
#pragma unroll
        for (int f = 0; f < 8; ++f) {
            o[f][0] *= scl[0]; o[f][1] *= scl[1]; o[f][2] *= scl[2]; o[f][3] *= scl[3];
        }
        // P -> LDS (bf16, swizzled)
        char* pb = (char*)&Ps[w][0];
#pragma unroll
        for (int kf = 0; kf < 4; ++kf)
#pragma unroll
            for (int r = 0; r < 4; ++r) {
                int q = lg * 4 + r;
                int byte = (q * 128 + kf * 32 + lr * 2) ^ ((q & 7) << 4);
                *(u16*)(pb + byte) = f2bf(sf[kf][r]);
            }
        __syncthreads();
        // O += P V
#pragma unroll
        for (int kc = 0; kc < 2; ++kc) {
            bf16x8 pa = *(const bf16x8*)(pb + ((lr * 128 + kc * 64 + lg * 16) ^ ((lr & 7) << 4)));
#pragma unroll
            for (int df = 0; df < 8; ++df) {
                int vr = df * 16 + lr;
                bf16x8 vf = *(const bf16x8*)((const char*)Vs +
                    ((vr * 128 + kc * 64 + lg * 16) ^ ((vr & 7) << 4)));
                o[df] = MFMA16(pa, vf, o[df]);
            }
        }
        __syncthreads();
    }
    float inv[4];
#pragma unroll
    for (int r = 0; r < 4; ++r) inv[r] = 1.0f / lrun[r];
    const int b = bh >> 4, h = bh & 15;
#pragma unroll
    for (int df = 0; df < 8; ++df)
#pragma unroll
        for (int r = 0; r < 4; ++r) {
            int q = qb0 + w * 16 + lg * 4 + r;
            int d = df * 16 + lr;
            O[(((size_t)b * 2048 + q) * 16 + h) * 128 + d] = f2bf(o[df][r] * inv[r]);
        }
}

extern "C" void kernel_launch(void* const* d_in, const int* in_sizes, int n_in,
                              void* d_out, int out_size, void* d_ws, size_t ws_size,
                              hipStream_t stream)
{
    (void)in_sizes; (void)n_in;
    const float* x    = (const float*)d_in[0];
    const float* ln1  = (const float*)d_in[1];
    const float* wq   = (const float*)d_in[2];
    const float* wk   = (const float*)d_in[3];
    const float* wv   = (const float*)d_in[4];
    const float* qln  = (const float*)d_in[5];
    const float* kln  = (const float*)d_in[6];
    const float* wo   = (const float*)d_in[7];
    const float* ln2  = (const float*)d_in[8];
    const float* wi0  = (const float*)d_in[9];
    const float* wi1  = (const float*)d_in[10];
    const float* wout = (const float*)d_in[11];

    const size_t MB = 1ull << 20;
    char* ws = (char*)d_ws;
    if (ws_size < 256 * MB) {
        fillsent<<<2048, 256, 0, stream>>>((float*)d_out, out_size, (float)(ws_size >> 20));
        return;
    }

    // Arena, 256 MiB, verified phase-by-phase (no live overlaps):
    //  [0,16)    lnx_hi        -> attn (after v-GEMM / at flash)
    //  [16,32)   lnx_lo        -> h (after k-GEMM / at rmsnorm2)
    //  [32,64)   q_f32         -> g[0:32) (after qknorm / at gemm_up)
    //  [64,96)   k_f32         -> vt[64,80) (after k qknorm) -> g[32:64)
    //  [96,128)  wi0t          -> wo2t (after gemm_up)
    //  [128,160) wi1t
    //  [160,176) q_hi          -> (dead after flash)
    //  [176,192) q_lo
    //  [192,208) wqt_hi+lo     -> k_hi (after q-GEMM) -> interp[192,224) (after flash)
    //  [208,224) wkt_hi+lo     -> k_lo (after k-GEMM)
    //  [224,232) wvt   [232,240) wot
    //  [240,256) v
    u16* lnx_hi = (u16*)(ws + 0 * MB);
    u16* lnx_lo = (u16*)(ws + 16 * MB);
    u16* attn   = (u16*)(ws + 0 * MB);
    u16* h      = (u16*)(ws + 16 * MB);
    float* qf32 = (float*)(ws + 32 * MB);
    float* kf32 = (float*)(ws + 64 * MB);
    u16* vt     = (u16*)(ws + 64 * MB);
    u16* g      = (u16*)(ws + 32 * MB);
    u16* wi0t   = (u16*)(ws + 96 * MB);
    u16* wo2t   = (u16*)(ws + 96 * MB);
    u16* wi1t   = (u16*)(ws + 128 * MB);
    u16* q_hi   = (u16*)(ws + 160 * MB);
    u16* q_lo   = (u16*)(ws + 176 * MB);
    u16* wqt_hi = (u16*)(ws + 192 * MB);
    u16* wqt_lo = (u16*)(ws + 200 * MB);
    u16* k_hi   = (u16*)(ws + 192 * MB);
    float* interp = (float*)(ws + 192 * MB);
    u16* wkt_hi = (u16*)(ws + 208 * MB);
    u16* wkt_lo = (u16*)(ws + 216 * MB);
    u16* k_lo   = (u16*)(ws + 208 * MB);
    u16* wvt    = (u16*)(ws + 224 * MB);
    u16* wot    = (u16*)(ws + 232 * MB);
    u16* v      = (u16*)(ws + 240 * MB);

    dim3 blk(256);
    wtrans<<<dim3(32, 32), blk, 0, stream>>>(wv, wvt, 2048, 2048);
    wtrans<<<dim3(32, 32), blk, 0, stream>>>(wo, wot, 2048, 2048);
    wtrans<<<dim3(128, 32), blk, 0, stream>>>(wi0, wi0t, 2048, 8192);
    wtrans<<<dim3(128, 32), blk, 0, stream>>>(wi1, wi1t, 2048, 8192);

    rmsnorm_split<<<4096, blk, 0, stream>>>(x, ln1, lnx_hi, lnx_lo);

    // ---- Q path (split precision) ----
    wtrans_split<<<dim3(32, 32), blk, 0, stream>>>(wq, wqt_hi, wqt_lo, 2048, 2048);
    gemm3<<<dim3(16, 32), blk, 0, stream>>>(lnx_hi, lnx_lo, wqt_hi, wqt_lo, qf32, 4096, 2048, 2048);
    qknorm_split<<<16384, blk, 0, stream>>>(qf32, qln, q_hi, q_lo);

    // ---- K path (split precision) ----
    wtrans_split<<<dim3(32, 32), blk, 0, stream>>>(wk, wkt_hi, wkt_lo, 2048, 2048);
    gemm3<<<dim3(16, 32), blk, 0, stream>>>(lnx_hi, lnx_lo, wkt_hi, wkt_lo, kf32, 4096, 2048, 2048);
    qknorm_split<<<16384, blk, 0, stream>>>(kf32, kln, k_hi, k_lo);

    // ---- V path (single precision) ----
    gemm_bt_k<0><<<dim3(16, 32), blk, 0, stream>>>(lnx_hi, wvt, nullptr, v, nullptr, 4096, 2048, 2048);
    vtrans<<<dim3(2, 32, 32), blk, 0, stream>>>(v, vt);

    flash<<<dim3(32, 32), blk, 0, stream>>>(q_hi, q_lo, k_hi, k_lo, vt, attn);

    gemm_bt_k<1><<<dim3(16, 32), blk, 0, stream>>>(attn, wot, interp, nullptr, x, 4096, 2048, 2048);

    rmsnorm_d<<<4096, blk, 0, stream>>>(interp, ln2, h);

    gemm_up<<<dim3(64, 32), blk, 0, stream>>>(h, wi0t, wi1t, g, 4096, 8192, 2048);

    wtrans<<<dim3(32, 128), blk, 0, stream>>>(wout, wo2t, 8192, 2048);
    gemm_bt_k<1><<<dim3(16, 32), blk, 0, stream>>>(g, wo2t, (float*)d_out, nullptr, interp, 4096, 2048, 8192);
}

// Round 10
// 992.465 us; speedup vs baseline: 13.2443x; 1.0234x over previous
//
#include <hip/hip_runtime.h>

typedef unsigned short u16;
typedef unsigned int u32;
typedef __attribute__((ext_vector_type(8))) short bf16x8;
typedef __attribute__((ext_vector_type(2))) float f32x2;
typedef __attribute__((ext_vector_type(4))) float f32x4;
typedef __attribute__((ext_vector_type(4))) u32 u32x4;

#define DEV __device__ __forceinline__

DEV u16 f2bf(float x) {
    u32 u = __builtin_bit_cast(u32, x);
    u += 0x7fffu + ((u >> 16) & 1u);
    return (u16)(u >> 16);
}
DEV float bf2f(u16 b) {
    u32 u = ((u32)b) << 16;
    return __builtin_bit_cast(float, u);
}

#define MFMA16(a, b, c) __builtin_amdgcn_mfma_f32_16x16x32_bf16((a), (b), (c), 0, 0, 0)

// async global->LDS, 16B per lane; LDS dest = wave-uniform base + lane*16
#define GLL16(gp, lp)                                                      \
    __builtin_amdgcn_global_load_lds(                                      \
        (const __attribute__((address_space(1))) u32*)(const void*)(gp),   \
        (__attribute__((address_space(3))) u32*)(void*)(lp), 16, 0, 0)

// ---------------- sentinel (workspace too small -> report ws MiB via absmax) ----------------
__global__ void fillsent(float* __restrict__ out, int n, float val)
{
    for (int i = blockIdx.x * blockDim.x + threadIdx.x; i < n; i += gridDim.x * blockDim.x)
        out[i] = val;
}

// ---------------- weight cast+transpose: f32 [K,N] -> bf16 [N,K] ----------------
__global__ void wtrans(const float* __restrict__ in, u16* __restrict__ out, int K, int N)
{
    __shared__ u16 t[64][65];
    const int n0 = blockIdx.x * 64, k0 = blockIdx.y * 64, tid = threadIdx.x;
    for (int i = tid; i < 4096; i += 256) {
        int r = i >> 6, c = i & 63;
        t[r][c] = f2bf(in[(size_t)(k0 + r) * N + n0 + c]);
    }
    __syncthreads();
    for (int i = tid; i < 4096; i += 256) {
        int r = i >> 6, c = i & 63;
        out[(size_t)(n0 + r) * K + k0 + c] = t[c][r];
    }
}

// ---------------- weight cast+transpose, hi/lo split: f32 [K,N] -> bf16 hi/lo [N,K] ----------------
__global__ void wtrans_split(const float* __restrict__ in, u16* __restrict__ ohi,
                             u16* __restrict__ olo, int K, int N)
{
    __shared__ float t[64][65];
    const int n0 = blockIdx.x * 64, k0 = blockIdx.y * 64, tid = threadIdx.x;
    for (int i = tid; i < 4096; i += 256) {
        int r = i >> 6, c = i & 63;
        t[r][c] = in[(size_t)(k0 + r) * N + n0 + c];
    }
    __syncthreads();
    for (int i = tid; i < 4096; i += 256) {
        int r = i >> 6, c = i & 63;
        float v = t[c][r];
        u16 h = f2bf(v);
        size_t idx = (size_t)(n0 + r) * K + k0 + c;
        ohi[idx] = h;
        olo[idx] = f2bf(v - bf2f(h));
    }
}

// ---------------- V relayout: bf16 [BH,S,128] -> [BH,128,S] ----------------
__global__ void vtrans(const u16* __restrict__ in, u16* __restrict__ out)
{
    __shared__ u16 t[64][65];
    const int d0 = blockIdx.x * 64, s0 = blockIdx.y * 64, bh = blockIdx.z, tid = threadIdx.x;
    const u16* ip = in + (size_t)bh * 2048 * 128;
    u16* op = out + (size_t)bh * 128 * 2048;
    for (int i = tid; i < 4096; i += 256) {
        int r = i >> 6, c = i & 63;
        t[r][c] = ip[(size_t)(s0 + r) * 128 + d0 + c];
    }
    __syncthreads();
    for (int i = tid; i < 4096; i += 256) {
        int r = i >> 6, c = i & 63;
        op[(size_t)(d0 + r) * 2048 + s0 + c] = t[c][r];
    }
}

// ---------------- RMSNorm over D=2048: f32 in -> bf16 out (single) ----------------
__global__ __launch_bounds__(256) void rmsnorm_d(const float* __restrict__ in,
                                                 const float* __restrict__ sc,
                                                 u16* __restrict__ out)
{
    __shared__ float red[4];
    const int row = blockIdx.x, tid = threadIdx.x;
    const float* p = in + (size_t)row * 2048 + tid * 8;
    f32x4 a = *(const f32x4*)p;
    f32x4 b = *(const f32x4*)(p + 4);
    float ss = a[0]*a[0] + a[1]*a[1] + a[2]*a[2] + a[3]*a[3]
             + b[0]*b[0] + b[1]*b[1] + b[2]*b[2] + b[3]*b[3];
    for (int d = 1; d < 64; d <<= 1) ss += __shfl_xor(ss, d, 64);
    if ((tid & 63) == 0) red[tid >> 6] = ss;
    __syncthreads();
    float rs = rsqrtf((red[0] + red[1] + red[2] + red[3]) * (1.0f / 2048.0f) + 1e-6f);
    const float* s = sc + tid * 8;
    u32x4 ov;
#pragma unroll
    for (int i = 0; i < 2; ++i) {
        f32x4 v = i ? b : a;
#pragma unroll
        for (int j = 0; j < 2; ++j) {
            float v0 = v[j * 2] * rs * s[i * 4 + j * 2];
            float v1 = v[j * 2 + 1] * rs * s[i * 4 + j * 2 + 1];
            ov[i * 2 + j] = (u32)f2bf(v0) | ((u32)f2bf(v1) << 16);
        }
    }
    *(u32x4*)(out + (size_t)row * 2048 + tid * 8) = ov;
}

// ---------------- RMSNorm over D=2048: f32 in -> bf16 hi/lo out ----------------
__global__ __launch_bounds__(256) void rmsnorm_split(const float* __restrict__ in,
                                                     const float* __restrict__ sc,
                                                     u16* __restrict__ ohi,
                                                     u16* __restrict__ olo)
{
    __shared__ float red[4];
    const int row = blockIdx.x, tid = threadIdx.x;
    const float* p = in + (size_t)row * 2048 + tid * 8;
    f32x4 a = *(const f32x4*)p;
    f32x4 b = *(const f32x4*)(p + 4);
    float ss = a[0]*a[0] + a[1]*a[1] + a[2]*a[2] + a[3]*a[3]
             + b[0]*b[0] + b[1]*b[1] + b[2]*b[2] + b[3]*b[3];
    for (int d = 1; d < 64; d <<= 1) ss += __shfl_xor(ss, d, 64);
    if ((tid & 63) == 0) red[tid >> 6] = ss;
    __syncthreads();
    float rs = rsqrtf((red[0] + red[1] + red[2] + red[3]) * (1.0f / 2048.0f) + 1e-6f);
    const float* s = sc + tid * 8;
    u32x4 oh, ol;
#pragma unroll
    for (int i = 0; i < 2; ++i) {
        f32x4 v = i ? b : a;
#pragma unroll
        for (int j = 0; j < 2; ++j) {
            float v0 = v[j * 2] * rs * s[i * 4 + j * 2];
            float v1 = v[j * 2 + 1] * rs * s[i * 4 + j * 2 + 1];
            u16 h0 = f2bf(v0), h1 = f2bf(v1);
            u16 l0 = f2bf(v0 - bf2f(h0)), l1 = f2bf(v1 - bf2f(h1));
            oh[i * 2 + j] = (u32)h0 | ((u32)h1 << 16);
            ol[i * 2 + j] = (u32)l0 | ((u32)l1 << 16);
        }
    }
    *(u32x4*)(ohi + (size_t)row * 2048 + tid * 8) = oh;
    *(u32x4*)(olo + (size_t)row * 2048 + tid * 8) = ol;
}

// ---------------- GEMM: C[M,N] = A[M,K](bf16) x Bt[N,K](bf16), 128x128 tile, BK=64 ----------------
// EPI 0 QKV : write bf16 scattered to [BH,S,128]
// EPI 1 RESF: outf = acc + resf (f32 out, f32 residual)
template <int EPI>
__global__ __launch_bounds__(256, 2)
void gemm_bt_k(const u16* __restrict__ A, const u16* __restrict__ Bt,
               float* __restrict__ outf, u16* __restrict__ outb,
               const float* __restrict__ resf, int M, int N, int K)
{
    __shared__ u16 As[128 * 64];
    __shared__ u16 Bs[128 * 64];
    const int tid = threadIdx.x, w = tid >> 6, l = tid & 63;
    const int lr = l & 15, lg = l >> 4;
    const int m0 = blockIdx.y * 128, n0 = blockIdx.x * 128;
    const int wr = (w >> 1) * 64, wc = (w & 1) * 64;
    f32x4 acc[4][4] = {};
    int prow[4], pcol[4];
#pragma unroll
    for (int j = 0; j < 4; ++j) {
        int p = (j * 4 + w) * 1024 + l * 16;
        prow[j] = p >> 7;
        pcol[j] = (p ^ ((prow[j] & 7) << 4)) & 127;
    }
    const char* Ab = (const char*)A;
    const char* Bb = (const char*)Bt;
    const size_t ldb = (size_t)K * 2;
    const int nkt = K / 64;
    for (int kt = 0; kt < nkt; ++kt) {
#pragma unroll
        for (int j = 0; j < 4; ++j) {
            GLL16(Ab + (size_t)(m0 + prow[j]) * ldb + kt * 128 + pcol[j], (char*)As + (j * 4 + w) * 1024);
            GLL16(Bb + (size_t)(n0 + prow[j]) * ldb + kt * 128 + pcol[j], (char*)Bs + (j * 4 + w) * 1024);
        }
        __syncthreads();
#pragma unroll
        for (int kc = 0; kc < 2; ++kc) {
            bf16x8 af[4], bf[4];
#pragma unroll
            for (int f = 0; f < 4; ++f) {
                int ra = wr + f * 16 + lr;
                af[f] = *(const bf16x8*)((const char*)As + ((ra * 128 + kc * 64 + lg * 16) ^ ((ra & 7) << 4)));
                int rb = wc + f * 16 + lr;
                bf[f] = *(const bf16x8*)((const char*)Bs + ((rb * 128 + kc * 64 + lg * 16) ^ ((rb & 7) << 4)));
            }
#pragma unroll
            for (int mf = 0; mf < 4; ++mf)
#pragma unroll
                for (int nf = 0; nf < 4; ++nf)
                    acc[mf][nf] = MFMA16(af[mf], bf[nf], acc[mf][nf]);
        }
        __syncthreads();
    }
#pragma unroll
    for (int mf = 0; mf < 4; ++mf) {
#pragma unroll
        for (int nf = 0; nf < 4; ++nf) {
#pragma unroll
            for (int r = 0; r < 4; ++r) {
                int m = m0 + wr + mf * 16 + lg * 4 + r;
                int n = n0 + wc + nf * 16 + lr;
                float v = acc[mf][nf][r];
                if constexpr (EPI == 0) {
                    outb[(((m >> 11) * 16 + (n >> 7)) << 18) + ((m & 2047) << 7) + (n & 127)] = f2bf(v);
                } else {
                    size_t idx = (size_t)m * N + n;
                    outf[idx] = v + resf[idx];
                }
            }
        }
    }
}

// ---------------- split-precision GEMM + fused per-head RMSNorm + hi/lo split ----------------
// C = (Ahi+Alo)(Bhi+Blo)^T (lo*lo dropped), then rmsnorm over the block's 128 cols (= one head),
// scaled by sc, written as bf16 hi/lo to [BH,S,128].
__global__ __launch_bounds__(256, 2)
void gemm3(const u16* __restrict__ Ahi, const u16* __restrict__ Alo,
           const u16* __restrict__ Bhi, const u16* __restrict__ Blo,
           const float* __restrict__ sc,
           u16* __restrict__ ohi, u16* __restrict__ olo, int M, int N, int K)
{
    __shared__ u16 Ah[128 * 64];
    __shared__ u16 Al[128 * 64];
    __shared__ u16 Bh[128 * 64];
    __shared__ u16 Bl[128 * 64];
    __shared__ float ssq[128][2];
    const int tid = threadIdx.x, w = tid >> 6, l = tid & 63;
    const int lr = l & 15, lg = l >> 4;
    const int m0 = blockIdx.y * 128, n0 = blockIdx.x * 128;
    const int wr = (w >> 1) * 64, wc = (w & 1) * 64;
    f32x4 acc[4][4] = {};
    int prow[4], pcol[4];
#pragma unroll
    for (int j = 0; j < 4; ++j) {
        int p = (j * 4 + w) * 1024 + l * 16;
        prow[j] = p >> 7;
        pcol[j] = (p ^ ((prow[j] & 7) << 4)) & 127;
    }
    const size_t ldb = (size_t)K * 2;
    const int nkt = K / 64;
    for (int kt = 0; kt < nkt; ++kt) {
#pragma unroll
        for (int j = 0; j < 4; ++j) {
            size_t ao = (size_t)(m0 + prow[j]) * ldb + kt * 128 + pcol[j];
            size_t bo = (size_t)(n0 + prow[j]) * ldb + kt * 128 + pcol[j];
            GLL16((const char*)Ahi + ao, (char*)Ah + (j * 4 + w) * 1024);
            GLL16((const char*)Alo + ao, (char*)Al + (j * 4 + w) * 1024);
            GLL16((const char*)Bhi + bo, (char*)Bh + (j * 4 + w) * 1024);
            GLL16((const char*)Blo + bo, (char*)Bl + (j * 4 + w) * 1024);
        }
        __syncthreads();
#pragma unroll
        for (int kc = 0; kc < 2; ++kc) {
            bf16x8 ahf[4], alf[4], bhf[4], blf[4];
#pragma unroll
            for (int f = 0; f < 4; ++f) {
                int ra = wr + f * 16 + lr;
                int oa = (ra * 128 + kc * 64 + lg * 16) ^ ((ra & 7) << 4);
                ahf[f] = *(const bf16x8*)((const char*)Ah + oa);
                alf[f] = *(const bf16x8*)((const char*)Al + oa);
                int rb = wc + f * 16 + lr;
                int ob = (rb * 128 + kc * 64 + lg * 16) ^ ((rb & 7) << 4);
                bhf[f] = *(const bf16x8*)((const char*)Bh + ob);
                blf[f] = *(const bf16x8*)((const char*)Bl + ob);
            }
#pragma unroll
            for (int mf = 0; mf < 4; ++mf)
#pragma unroll
                for (int nf = 0; nf < 4; ++nf) {
                    acc[mf][nf] = MFMA16(ahf[mf], bhf[nf], acc[mf][nf]);
                    acc[mf][nf] = MFMA16(ahf[mf], blf[nf], acc[mf][nf]);
                    acc[mf][nf] = MFMA16(alf[mf], bhf[nf], acc[mf][nf]);
                }
        }
        __syncthreads();
    }
    // ---- fused per-head RMSNorm epilogue ----
    float sp[4][4];
#pragma unroll
    for (int mf = 0; mf < 4; ++mf)
#pragma unroll
        for (int r = 0; r < 4; ++r) {
            float s = 0.0f;
#pragma unroll
            for (int nf = 0; nf < 4; ++nf) { float v = acc[mf][nf][r]; s += v * v; }
            s += __shfl_xor(s, 1, 64); s += __shfl_xor(s, 2, 64);
            s += __shfl_xor(s, 4, 64); s += __shfl_xor(s, 8, 64);
            sp[mf][r] = s;
        }
    if (lr == 0) {
#pragma unroll
        for (int mf = 0; mf < 4; ++mf)
#pragma unroll
            for (int r = 0; r < 4; ++r)
                ssq[wr + mf * 16 + lg * 4 + r][w & 1] = sp[mf][r];
    }
    __syncthreads();
    const int head = n0 >> 7;
#pragma unroll
    for (int mf = 0; mf < 4; ++mf)
#pragma unroll
        for (int r = 0; r < 4; ++r) {
            int mloc = wr + mf * 16 + lg * 4 + r;
            int m = m0 + mloc;
            float rs = rsqrtf((ssq[mloc][0] + ssq[mloc][1]) * (1.0f / 128.0f) + 1e-6f);
            size_t base = (((size_t)(m >> 11) * 16 + head) << 18) + ((size_t)(m & 2047) << 7);
#pragma unroll
            for (int nf = 0; nf < 4; ++nf) {
                int hd = wc + nf * 16 + lr;
                float v = acc[mf][nf][r] * rs * sc[hd];
                u16 hv = f2bf(v);
                ohi[base + hd] = hv;
                olo[base + hd] = f2bf(v - bf2f(hv));
            }
        }
}

// ---------------- fused MLP up: g = silu(A@wi0) * (A@wi1), bf16 out ----------------
__global__ __launch_bounds__(256, 2)
void gemm_up(const u16* __restrict__ A, const u16* __restrict__ B0, const u16* __restrict__ B1,
             u16* __restrict__ G, int M, int N, int K)
{
    __shared__ u16 As[128 * 64];
    __shared__ u16 Bs0[128 * 64];
    __shared__ u16 Bs1[128 * 64];
    const int tid = threadIdx.x, w = tid >> 6, l = tid & 63;
    const int lr = l & 15, lg = l >> 4;
    const int m0 = blockIdx.y * 128, n0 = blockIdx.x * 128;
    const int wr = (w >> 1) * 64, wc = (w & 1) * 64;
    f32x4 acc0[4][4] = {}, acc1[4][4] = {};
    int prow[4], pcol[4];
#pragma unroll
    for (int j = 0; j < 4; ++j) {
        int p = (j * 4 + w) * 1024 + l * 16;
        prow[j] = p >> 7;
        pcol[j] = (p ^ ((prow[j] & 7) << 4)) & 127;
    }
    const size_t ldb = (size_t)K * 2;
    const int nkt = K / 64;
    for (int kt = 0; kt < nkt; ++kt) {
#pragma unroll
        for (int j = 0; j < 4; ++j) {
            GLL16((const char*)A + (size_t)(m0 + prow[j]) * ldb + kt * 128 + pcol[j], (char*)As + (j * 4 + w) * 1024);
            GLL16((const char*)B0 + (size_t)(n0 + prow[j]) * ldb + kt * 128 + pcol[j], (char*)Bs0 + (j * 4 + w) * 1024);
            GLL16((const char*)B1 + (size_t)(n0 + prow[j]) * ldb + kt * 128 + pcol[j], (char*)Bs1 + (j * 4 + w) * 1024);
        }
        __syncthreads();
#pragma unroll
        for (int kc = 0; kc < 2; ++kc) {
            bf16x8 af[4], b0f[4], b1f[4];
#pragma unroll
            for (int f = 0; f < 4; ++f) {
                int ra = wr + f * 16 + lr;
                af[f] = *(const bf16x8*)((const char*)As + ((ra * 128 + kc * 64 + lg * 16) ^ ((ra & 7) << 4)));
                int rb = wc + f * 16 + lr;
                int ob = (rb * 128 + kc * 64 + lg * 16) ^ ((rb & 7) << 4);
                b0f[f] = *(const bf16x8*)((const char*)Bs0 + ob);
                b1f[f] = *(const bf16x8*)((const char*)Bs1 + ob);
            }
#pragma unroll
            for (int mf = 0; mf < 4; ++mf)
#pragma unroll
                for (int nf = 0; nf < 4; ++nf) {
                    acc0[mf][nf] = MFMA16(af[mf], b0f[nf], acc0[mf][nf]);
                    acc1[mf][nf] = MFMA16(af[mf], b1f[nf], acc1[mf][nf]);
                }
        }
        __syncthreads();
    }
#pragma unroll
    for (int mf = 0; mf < 4; ++mf) {
#pragma unroll
        for (int nf = 0; nf < 4; ++nf) {
#pragma unroll
            for (int r = 0; r < 4; ++r) {
                int m = m0 + wr + mf * 16 + lg * 4 + r;
                int n = n0 + wc + nf * 16 + lr;
                float a = acc0[mf][nf][r];
                float b = acc1[mf][nf][r];
                G[(size_t)m * N + n] = f2bf(a / (1.0f + __expf(-a)) * b);
            }
        }
    }
}

// ---------------- causal flash attention, split-precision Q,K ----------------
// Qh/Ql,Kh/Kl: [BH,S,128] bf16; Vt: [BH,128,S] bf16; Out: [B,S,H,128] bf16
__global__ __launch_bounds__(256, 2)
void flash(const u16* __restrict__ Qh, const u16* __restrict__ Ql,
           const u16* __restrict__ Kh, const u16* __restrict__ Kl,
           const u16* __restrict__ Vt, u16* __restrict__ O)
{
    __shared__ u16 Ksh[64 * 128];  // rows 256B, swizzled
    __shared__ u16 Ksl[64 * 128];
    __shared__ u16 Vs[128 * 64];   // rows 128B, swizzled
    __shared__ u16 Ps[4][16 * 64]; // per-wave P, rows 128B, swizzled
    const int tid = threadIdx.x, w = tid >> 6, l = tid & 63;
    const int lr = l & 15, lg = l >> 4;
    const int qb0 = blockIdx.x * 64, bh = blockIdx.y;

    const size_t qoff = ((size_t)bh * 2048 + qb0 + w * 16) * 128;
    bf16x8 qfh[4], qfl[4];
#pragma unroll
    for (int kc = 0; kc < 4; ++kc) {
        qfh[kc] = *(const bf16x8*)(Qh + qoff + lr * 128 + kc * 32 + lg * 8);
        qfl[kc] = *(const bf16x8*)(Ql + qoff + lr * 128 + kc * 32 + lg * 8);
    }

    f32x4 o[8] = {};
    float mrun[4] = {-1e30f, -1e30f, -1e30f, -1e30f};
    float lrun[4] = {};

    int kgo[4], vdo[4], voff[4];
#pragma unroll
    for (int j = 0; j < 4; ++j) {
        int p = (j * 4 + w) * 1024 + l * 16;
        kgo[j] = p ^ (((p >> 8) & 7) << 4);
        int d = p >> 7, c0 = (p >> 4) & 7;
        vdo[j] = d;
        voff[j] = (c0 ^ (d & 7)) << 4;
    }
    const char* kbh = (const char*)(Kh + (size_t)bh * 2048 * 128);
    const char* kbl = (const char*)(Kl + (size_t)bh * 2048 * 128);
    const char* vbase = (const char*)(Vt + (size_t)bh * 128 * 2048);
    const int tmax = blockIdx.x;

    for (int t = 0; t <= tmax; ++t) {
        const char* kgh = kbh + (size_t)t * 16384;
        const char* kgl = kbl + (size_t)t * 16384;
        const char* vg = vbase + t * 128;
#pragma unroll
        for (int j = 0; j < 4; ++j) {
            GLL16(kgh + kgo[j], (char*)Ksh + (j * 4 + w) * 1024);
            GLL16(kgl + kgo[j], (char*)Ksl + (j * 4 + w) * 1024);
            GLL16(vg + (size_t)vdo[j] * 4096 + voff[j], (char*)Vs + (j * 4 + w) * 1024);
        }
        __syncthreads();

        // S = (Qh+Ql)(Kh+Kl)^T, lo*lo dropped
        f32x4 sf[4];
#pragma unroll
        for (int kf = 0; kf < 4; ++kf) {
            f32x4 a = {};
            int row = kf * 16 + lr;
#pragma unroll
            for (int kc = 0; kc < 4; ++kc) {
                int off = (row * 256 + kc * 64 + lg * 16) ^ ((row & 7) << 4);
                bf16x8 khf = *(const bf16x8*)((const char*)Ksh + off);
                bf16x8 klf = *(const bf16x8*)((const char*)Ksl + off);
                a = MFMA16(qfh[kc], khf, a);
                a = MFMA16(qfh[kc], klf, a);
                a = MFMA16(qfl[kc], khf, a);
            }
            sf[kf] = a;
        }
        if (t == tmax) {
#pragma unroll
            for (int kf = 0; kf < 4; ++kf)
#pragma unroll
                for (int r = 0; r < 4; ++r)
                    if (t * 64 + kf * 16 + lr > qb0 + w * 16 + lg * 4 + r) sf[kf][r] = -1e30f;
        }
        float scl[4];
#pragma unroll
        for (int r = 0; r < 4; ++r) {
            float m_ = fmaxf(fmaxf(sf[0][r], sf[1][r]), fmaxf(sf[2][r], sf[3][r]));
            m_ = fmaxf(m_, __shfl_xor(m_, 1, 64));
            m_ = fmaxf(m_, __shfl_xor(m_, 2, 64));
            m_ = fmaxf(m_, __shfl_xor(m_, 4, 64));
            m_ = fmaxf(m_, __shfl_xor(m_, 8, 64));
            float mn = fmaxf(mrun[r], m_);
            scl[r] = __expf(mrun[r] - mn);
            mrun[r] = mn;
            float s_ = 0.0f;
#pragma unroll
            for (int kf = 0; kf < 4; ++kf) {
                float e = __expf(sf[kf][r] - mn);
                sf[kf][r] = e;
                s_ += e;
            }
            s_ += __shfl_xor(s_, 1, 64);
            s_ += __shfl_xor(s_, 2, 64);
            s_ += __shfl_xor(s_, 4, 64);
            s_ += __shfl_xor(s_, 8, 64);
            lrun[r] = lrun[r] * scl[r] + s_;
        }
#pragma unroll
        for (int f = 0; f < 8; ++f) {
            o[f][0] *= scl[0]; o[f][1] *= scl[1]; o[f][2] *= scl[2]; o[f][3] *= scl[3];
        }
        // P -> LDS (bf16, swizzled)
        char* pb = (char*)&Ps[w][0];
#pragma unroll
        for (int kf = 0; kf < 4; ++kf)
#pragma unroll
            for (int r = 0; r < 4; ++r) {
                int q = lg * 4 + r;
                int byte = (q * 128 + kf * 32 + lr * 2) ^ ((q & 7) << 4);
                *(u16*)(pb + byte) = f2bf(sf[kf][r]);
            }
        __syncthreads();
        // O += P V
#pragma unroll
        for (int kc = 0; kc < 2; ++kc) {
            bf16x8 pa = *(const bf16x8*)(pb + ((lr * 128 + kc * 64 + lg * 16) ^ ((lr & 7) << 4)));
#pragma unroll
            for (int df = 0; df < 8; ++df) {
                int vr = df * 16 + lr;
                bf16x8 vf = *(const bf16x8*)((const char*)Vs +
                    ((vr * 128 + kc * 64 + lg * 16) ^ ((vr & 7) << 4)));
                o[df] = MFMA16(pa, vf, o[df]);
            }
        }
        __syncthreads();
    }
    float inv[4];
#pragma unroll
    for (int r = 0; r < 4; ++r) inv[r] = 1.0f / lrun[r];
    const int b = bh >> 4, h = bh & 15;
#pragma unroll
    for (int df = 0; df < 8; ++df)
#pragma unroll
        for (int r = 0; r < 4; ++r) {
            int q = qb0 + w * 16 + lg * 4 + r;
            int d = df * 16 + lr;
            O[(((size_t)b * 2048 + q) * 16 + h) * 128 + d] = f2bf(o[df][r] * inv[r]);
        }
}

extern "C" void kernel_launch(void* const* d_in, const int* in_sizes, int n_in,
                              void* d_out, int out_size, void* d_ws, size_t ws_size,
                              hipStream_t stream)
{
    (void)in_sizes; (void)n_in;
    const float* x    = (const float*)d_in[0];
    const float* ln1  = (const float*)d_in[1];
    const float* wq   = (const float*)d_in[2];
    const float* wk   = (const float*)d_in[3];
    const float* wv   = (const float*)d_in[4];
    const float* qln  = (const float*)d_in[5];
    const float* kln  = (const float*)d_in[6];
    const float* wo   = (const float*)d_in[7];
    const float* ln2  = (const float*)d_in[8];
    const float* wi0  = (const float*)d_in[9];
    const float* wi1  = (const float*)d_in[10];
    const float* wout = (const float*)d_in[11];

    const size_t MB = 1ull << 20;
    char* ws = (char*)d_ws;
    if (ws_size < 256 * MB) {
        fillsent<<<2048, 256, 0, stream>>>((float*)d_out, out_size, (float)(ws_size >> 20));
        return;
    }

    // Arena (240 MiB used), live-span audited:
    //  [0,16)    lnx_hi (rmsnorm->v-gemm) -> attn (born at flash)
    //  [16,32)   lnx_lo (rmsnorm->K gemm3) -> h (born at rmsnorm2)
    //  [32,64)   q_hi,q_lo (gemm3->flash) \
    //  [64,96)   k_hi,k_lo (gemm3->flash)  > g [32,96) 64MiB (born at gemm_up)
    //  [96,112)  v  (v-gemm->vtrans)      \
    //  [112,128) vt (vtrans->flash)        > wo2t [96,128) (born after gemm_up)
    //  [128,160) wqt_hi/lo,wkt_hi/lo (wtrans->gemm3s) -> interp f32 (born at wo-gemm)
    //  [160,192) wi0t   [192,224) wi1t
    //  [224,232) wvt    [232,240) wot
    u16* lnx_hi = (u16*)(ws + 0 * MB);
    u16* attn   = (u16*)(ws + 0 * MB);
    u16* lnx_lo = (u16*)(ws + 16 * MB);
    u16* h      = (u16*)(ws + 16 * MB);
    u16* q_hi   = (u16*)(ws + 32 * MB);
    u16* q_lo   = (u16*)(ws + 48 * MB);
    u16* g      = (u16*)(ws + 32 * MB);
    u16* k_hi   = (u16*)(ws + 64 * MB);
    u16* k_lo   = (u16*)(ws + 80 * MB);
    u16* v      = (u16*)(ws + 96 * MB);
    u16* vt     = (u16*)(ws + 112 * MB);
    u16* wo2t   = (u16*)(ws + 96 * MB);
    u16* wqt_hi = (u16*)(ws + 128 * MB);
    u16* wqt_lo = (u16*)(ws + 136 * MB);
    u16* wkt_hi = (u16*)(ws + 144 * MB);
    u16* wkt_lo = (u16*)(ws + 152 * MB);
    float* interp = (float*)(ws + 128 * MB);
    u16* wi0t   = (u16*)(ws + 160 * MB);
    u16* wi1t   = (u16*)(ws + 192 * MB);
    u16* wvt    = (u16*)(ws + 224 * MB);
    u16* wot    = (u16*)(ws + 232 * MB);

    dim3 blk(256);
    wtrans<<<dim3(32, 32), blk, 0, stream>>>(wv, wvt, 2048, 2048);
    wtrans<<<dim3(32, 32), blk, 0, stream>>>(wo, wot, 2048, 2048);
    wtrans<<<dim3(128, 32), blk, 0, stream>>>(wi0, wi0t, 2048, 8192);
    wtrans<<<dim3(128, 32), blk, 0, stream>>>(wi1, wi1t, 2048, 8192);

    rmsnorm_split<<<4096, blk, 0, stream>>>(x, ln1, lnx_hi, lnx_lo);

    // ---- Q path: split GEMM + fused per-head norm ----
    wtrans_split<<<dim3(32, 32), blk, 0, stream>>>(wq, wqt_hi, wqt_lo, 2048, 2048);
    gemm3<<<dim3(16, 32), blk, 0, stream>>>(lnx_hi, lnx_lo, wqt_hi, wqt_lo, qln, q_hi, q_lo, 4096, 2048, 2048);

    // ---- K path ----
    wtrans_split<<<dim3(32, 32), blk, 0, stream>>>(wk, wkt_hi, wkt_lo, 2048, 2048);
    gemm3<<<dim3(16, 32), blk, 0, stream>>>(lnx_hi, lnx_lo, wkt_hi, wkt_lo, kln, k_hi, k_lo, 4096, 2048, 2048);

    // ---- V path (single precision) ----
    gemm_bt_k<0><<<dim3(16, 32), blk, 0, stream>>>(lnx_hi, wvt, nullptr, v, nullptr, 4096, 2048, 2048);
    vtrans<<<dim3(2, 32, 32), blk, 0, stream>>>(v, vt);

    flash<<<dim3(32, 32), blk, 0, stream>>>(q_hi, q_lo, k_hi, k_lo, vt, attn);

    gemm_bt_k<1><<<dim3(16, 32), blk, 0, stream>>>(attn, wot, interp, nullptr, x, 4096, 2048, 2048);

    rmsnorm_d<<<4096, blk, 0, stream>>>(interp, ln2, h);

    gemm_up<<<dim3(64, 32), blk, 0, stream>>>(h, wi0t, wi1t, g, 4096, 8192, 2048);

    wtrans<<<dim3(32, 128), blk, 0, stream>>>(wout, wo2t, 8192, 2048);
    gemm_bt_k<1><<<dim3(16, 32), blk, 0, stream>>>(g, wo2t, (float*)d_out, nullptr, interp, 4096, 2048, 8192);
}

// Round 11
// 986.259 us; speedup vs baseline: 13.3276x; 1.0063x over previous
//
#include <hip/hip_runtime.h>

typedef unsigned short u16;
typedef unsigned int u32;
typedef __attribute__((ext_vector_type(8))) short bf16x8;
typedef __attribute__((ext_vector_type(2))) float f32x2;
typedef __attribute__((ext_vector_type(4))) float f32x4;
typedef __attribute__((ext_vector_type(4))) u32 u32x4;

#define DEV __device__ __forceinline__

DEV u16 f2bf(float x) {
    u32 u = __builtin_bit_cast(u32, x);
    u += 0x7fffu + ((u >> 16) & 1u);
    return (u16)(u >> 16);
}
DEV float bf2f(u16 b) {
    u32 u = ((u32)b) << 16;
    return __builtin_bit_cast(float, u);
}

#define MFMA16(a, b, c) __builtin_amdgcn_mfma_f32_16x16x32_bf16((a), (b), (c), 0, 0, 0)

// async global->LDS, 16B per lane; LDS dest = wave-uniform base + lane*16
#define GLL16(gp, lp)                                                      \
    __builtin_amdgcn_global_load_lds(                                      \
        (const __attribute__((address_space(1))) u32*)(const void*)(gp),   \
        (__attribute__((address_space(3))) u32*)(void*)(lp), 16, 0, 0)

// ---------------- sentinel (workspace too small -> report ws MiB via absmax) ----------------
__global__ void fillsent(float* __restrict__ out, int n, float val)
{
    for (int i = blockIdx.x * blockDim.x + threadIdx.x; i < n; i += gridDim.x * blockDim.x)
        out[i] = val;
}

// ---------------- weight cast+transpose: f32 [K,N] -> bf16 [N,K] ----------------
__global__ void wtrans(const float* __restrict__ in, u16* __restrict__ out, int K, int N)
{
    __shared__ u16 t[64][65];
    const int n0 = blockIdx.x * 64, k0 = blockIdx.y * 64, tid = threadIdx.x;
    for (int i = tid; i < 4096; i += 256) {
        int r = i >> 6, c = i & 63;
        t[r][c] = f2bf(in[(size_t)(k0 + r) * N + n0 + c]);
    }
    __syncthreads();
    for (int i = tid; i < 4096; i += 256) {
        int r = i >> 6, c = i & 63;
        out[(size_t)(n0 + r) * K + k0 + c] = t[c][r];
    }
}

// ---------------- weight cast+transpose, hi/lo split: f32 [K,N] -> bf16 hi/lo [N,K] ----------------
__global__ void wtrans_split(const float* __restrict__ in, u16* __restrict__ ohi,
                             u16* __restrict__ olo, int K, int N)
{
    __shared__ float t[64][65];
    const int n0 = blockIdx.x * 64, k0 = blockIdx.y * 64, tid = threadIdx.x;
    for (int i = tid; i < 4096; i += 256) {
        int r = i >> 6, c = i & 63;
        t[r][c] = in[(size_t)(k0 + r) * N + n0 + c];
    }
    __syncthreads();
    for (int i = tid; i < 4096; i += 256) {
        int r = i >> 6, c = i & 63;
        float v = t[c][r];
        u16 h = f2bf(v);
        size_t idx = (size_t)(n0 + r) * K + k0 + c;
        ohi[idx] = h;
        olo[idx] = f2bf(v - bf2f(h));
    }
}

// ---------------- V relayout: bf16 [BH,S,128] -> [BH,128,S] ----------------
__global__ void vtrans(const u16* __restrict__ in, u16* __restrict__ out)
{
    __shared__ u16 t[64][65];
    const int d0 = blockIdx.x * 64, s0 = blockIdx.y * 64, bh = blockIdx.z, tid = threadIdx.x;
    const u16* ip = in + (size_t)bh * 2048 * 128;
    u16* op = out + (size_t)bh * 128 * 2048;
    for (int i = tid; i < 4096; i += 256) {
        int r = i >> 6, c = i & 63;
        t[r][c] = ip[(size_t)(s0 + r) * 128 + d0 + c];
    }
    __syncthreads();
    for (int i = tid; i < 4096; i += 256) {
        int r = i >> 6, c = i & 63;
        op[(size_t)(d0 + r) * 2048 + s0 + c] = t[c][r];
    }
}

// ---------------- RMSNorm over D=2048: f32 in -> bf16 out (single) ----------------
__global__ __launch_bounds__(256) void rmsnorm_d(const float* __restrict__ in,
                                                 const float* __restrict__ sc,
                                                 u16* __restrict__ out)
{
    __shared__ float red[4];
    const int row = blockIdx.x, tid = threadIdx.x;
    const float* p = in + (size_t)row * 2048 + tid * 8;
    f32x4 a = *(const f32x4*)p;
    f32x4 b = *(const f32x4*)(p + 4);
    float ss = a[0]*a[0] + a[1]*a[1] + a[2]*a[2] + a[3]*a[3]
             + b[0]*b[0] + b[1]*b[1] + b[2]*b[2] + b[3]*b[3];
    for (int d = 1; d < 64; d <<= 1) ss += __shfl_xor(ss, d, 64);
    if ((tid & 63) == 0) red[tid >> 6] = ss;
    __syncthreads();
    float rs = rsqrtf((red[0] + red[1] + red[2] + red[3]) * (1.0f / 2048.0f) + 1e-6f);
    const float* s = sc + tid * 8;
    u32x4 ov;
#pragma unroll
    for (int i = 0; i < 2; ++i) {
        f32x4 v = i ? b : a;
#pragma unroll
        for (int j = 0; j < 2; ++j) {
            float v0 = v[j * 2] * rs * s[i * 4 + j * 2];
            float v1 = v[j * 2 + 1] * rs * s[i * 4 + j * 2 + 1];
            ov[i * 2 + j] = (u32)f2bf(v0) | ((u32)f2bf(v1) << 16);
        }
    }
    *(u32x4*)(out + (size_t)row * 2048 + tid * 8) = ov;
}

// ---------------- RMSNorm over D=2048: f32 in -> bf16 hi/lo out ----------------
__global__ __launch_bounds__(256) void rmsnorm_split(const float* __restrict__ in,
                                                     const float* __restrict__ sc,
                                                     u16* __restrict__ ohi,
                                                     u16* __restrict__ olo)
{
    __shared__ float red[4];
    const int row = blockIdx.x, tid = threadIdx.x;
    const float* p = in + (size_t)row * 2048 + tid * 8;
    f32x4 a = *(const f32x4*)p;
    f32x4 b = *(const f32x4*)(p + 4);
    float ss = a[0]*a[0] + a[1]*a[1] + a[2]*a[2] + a[3]*a[3]
             + b[0]*b[0] + b[1]*b[1] + b[2]*b[2] + b[3]*b[3];
    for (int d = 1; d < 64; d <<= 1) ss += __shfl_xor(ss, d, 64);
    if ((tid & 63) == 0) red[tid >> 6] = ss;
    __syncthreads();
    float rs = rsqrtf((red[0] + red[1] + red[2] + red[3]) * (1.0f / 2048.0f) + 1e-6f);
    const float* s = sc + tid * 8;
    u32x4 oh, ol;
#pragma unroll
    for (int i = 0; i < 2; ++i) {
        f32x4 v = i ? b : a;
#pragma unroll
        for (int j = 0; j < 2; ++j) {
            float v0 = v[j * 2] * rs * s[i * 4 + j * 2];
            float v1 = v[j * 2 + 1] * rs * s[i * 4 + j * 2 + 1];
            u16 h0 = f2bf(v0), h1 = f2bf(v1);
            u16 l0 = f2bf(v0 - bf2f(h0)), l1 = f2bf(v1 - bf2f(h1));
            oh[i * 2 + j] = (u32)h0 | ((u32)h1 << 16);
            ol[i * 2 + j] = (u32)l0 | ((u32)l1 << 16);
        }
    }
    *(u32x4*)(ohi + (size_t)row * 2048 + tid * 8) = oh;
    *(u32x4*)(olo + (size_t)row * 2048 + tid * 8) = ol;
}

// ---------------- 8-wave pipelined GEMM: C[M,N] = A[M,K] x Bt[N,K] ----------------
// BM=128, BN=256, BK=64, 512 threads (8 waves, 2x4), 3 LDS buffers (144 KiB),
// prefetch depth 2, counted vmcnt(6) per K-tile (T3+T4), per-phase setprio (T5).
// EPI 0: bf16 scatter to [BH,S,128];  EPI 1: outf = acc + resf (f32).
template <int EPI>
__global__ __launch_bounds__(512, 2)
void gemm_bt8(const u16* __restrict__ Ap, const u16* __restrict__ Bt,
              float* __restrict__ outf, u16* __restrict__ outb,
              const float* __restrict__ resf, int M, int N, int K)
{
    extern __shared__ char lds[];
    char* AB = lds;            // 3 x 16384 (A: 128x64 bf16)
    char* BB = lds + 49152;    // 3 x 32768 (B: 256x64 bf16)
    const int tid = threadIdx.x, w = tid >> 6, l = tid & 63;
    const int lr = l & 15, lg = l >> 4;
    const int m0 = blockIdx.y * 128, n0 = blockIdx.x * 256;
    const int wr = (w >> 2) * 64, wc = (w & 3) * 64;
    const size_t ldb = (size_t)K * 2;
    const char* Ag = (const char*)Ap;
    const char* Bg = (const char*)Bt;
    const int ldsw = w * 1024;

    size_t ago[2], bgo[4];
#pragma unroll
    for (int i = 0; i < 2; ++i) {
        int p = (i * 512 + tid) * 16;
        int pr = p >> 7;
        int pc = (p ^ ((pr & 7) << 4)) & 127;
        ago[i] = (size_t)(m0 + pr) * ldb + pc;
    }
#pragma unroll
    for (int i = 0; i < 4; ++i) {
        int p = (i * 512 + tid) * 16;
        int pr = p >> 7;
        int pc = (p ^ ((pr & 7) << 4)) & 127;
        bgo[i] = (size_t)(n0 + pr) * ldb + pc;
    }

    f32x4 acc[4][4] = {};
    const int nkt = K / 64;

    // ---- prologue: stage tiles 0 (buf0) and 1 (buf1) ----
    GLL16(Ag + ago[0], AB + ldsw);
    GLL16(Ag + ago[1], AB + 8192 + ldsw);
    GLL16(Bg + bgo[0], BB + ldsw);
    GLL16(Bg + bgo[1], BB + 8192 + ldsw);
    GLL16(Bg + bgo[2], BB + 16384 + ldsw);
    GLL16(Bg + bgo[3], BB + 24576 + ldsw);
    if (nkt > 1) {
        char* Ad = AB + 16384;
        char* Bd = BB + 32768;
        GLL16(Ag + ago[0] + 128, Ad + ldsw);
        GLL16(Ag + ago[1] + 128, Ad + 8192 + ldsw);
        GLL16(Bg + bgo[0] + 128, Bd + ldsw);
        GLL16(Bg + bgo[1] + 128, Bd + 8192 + ldsw);
        GLL16(Bg + bgo[2] + 128, Bd + 16384 + ldsw);
        GLL16(Bg + bgo[3] + 128, Bd + 24576 + ldsw);
        asm volatile("s_waitcnt vmcnt(6)" ::: "memory");
    } else {
        asm volatile("s_waitcnt vmcnt(0)" ::: "memory");
    }
    __builtin_amdgcn_s_barrier();

    int cur = 0, stg = 2;
    for (int kt = 0; kt < nkt; ++kt) {
        char* Ac = AB + cur * 16384;
        char* Bc = BB + cur * 32768;
        char* Asd = AB + stg * 16384;
        char* Bsd = BB + stg * 32768;
        const bool dost = (kt + 2 < nkt);
        const size_t koff = (size_t)(kt + 2) * 128;

        bf16x8 af[4], bfa, bfb;
        // ======== phase 0: kc=0, nf=0,1 ========
#pragma unroll
        for (int mf = 0; mf < 4; ++mf) {
            int ra = wr + mf * 16 + lr;
            af[mf] = *(const bf16x8*)(Ac + ((ra * 128 + lg * 16) ^ ((ra & 7) << 4)));
        }
        {
            int rb = wc + lr;
            bfa = *(const bf16x8*)(Bc + ((rb * 128 + lg * 16) ^ ((rb & 7) << 4)));
            rb = wc + 16 + lr;
            bfb = *(const bf16x8*)(Bc + ((rb * 128 + lg * 16) ^ ((rb & 7) << 4)));
        }
        if (dost) {
            GLL16(Ag + ago[0] + koff, Asd + ldsw);
            GLL16(Ag + ago[1] + koff, Asd + 8192 + ldsw);
        }
        __builtin_amdgcn_s_barrier();
        __builtin_amdgcn_s_setprio(1);
#pragma unroll
        for (int mf = 0; mf < 4; ++mf) acc[mf][0] = MFMA16(af[mf], bfa, acc[mf][0]);
#pragma unroll
        for (int mf = 0; mf < 4; ++mf) acc[mf][1] = MFMA16(af[mf], bfb, acc[mf][1]);
        __builtin_amdgcn_s_setprio(0);
        __builtin_amdgcn_s_barrier();
        // ======== phase 1: kc=0, nf=2,3 ========
        {
            int rb = wc + 32 + lr;
            bfa = *(const bf16x8*)(Bc + ((rb * 128 + lg * 16) ^ ((rb & 7) << 4)));
            rb = wc + 48 + lr;
            bfb = *(const bf16x8*)(Bc + ((rb * 128 + lg * 16) ^ ((rb & 7) << 4)));
        }
        if (dost) {
            GLL16(Bg + bgo[0] + koff, Bsd + ldsw);
            GLL16(Bg + bgo[1] + koff, Bsd + 8192 + ldsw);
        }
        __builtin_amdgcn_s_barrier();
        __builtin_amdgcn_s_setprio(1);
#pragma unroll
        for (int mf = 0; mf < 4; ++mf) acc[mf][2] = MFMA16(af[mf], bfa, acc[mf][2]);
#pragma unroll
        for (int mf = 0; mf < 4; ++mf) acc[mf][3] = MFMA16(af[mf], bfb, acc[mf][3]);
        __builtin_amdgcn_s_setprio(0);
        __builtin_amdgcn_s_barrier();
        // ======== phase 2: kc=1, nf=0,1 ========
#pragma unroll
        for (int mf = 0; mf < 4; ++mf) {
            int ra = wr + mf * 16 + lr;
            af[mf] = *(const bf16x8*)(Ac + ((ra * 128 + 64 + lg * 16) ^ ((ra & 7) << 4)));
        }
        {
            int rb = wc + lr;
            bfa = *(const bf16x8*)(Bc + ((rb * 128 + 64 + lg * 16) ^ ((rb & 7) << 4)));
            rb = wc + 16 + lr;
            bfb = *(const bf16x8*)(Bc + ((rb * 128 + 64 + lg * 16) ^ ((rb & 7) << 4)));
        }
        if (dost) {
            GLL16(Bg + bgo[2] + koff, Bsd + 16384 + ldsw);
        }
        __builtin_amdgcn_s_barrier();
        __builtin_amdgcn_s_setprio(1);
#pragma unroll
        for (int mf = 0; mf < 4; ++mf) acc[mf][0] = MFMA16(af[mf], bfa, acc[mf][0]);
#pragma unroll
        for (int mf = 0; mf < 4; ++mf) acc[mf][1] = MFMA16(af[mf], bfb, acc[mf][1]);
        __builtin_amdgcn_s_setprio(0);
        __builtin_amdgcn_s_barrier();
        // ======== phase 3: kc=1, nf=2,3 ========
        {
            int rb = wc + 32 + lr;
            bfa = *(const bf16x8*)(Bc + ((rb * 128 + 64 + lg * 16) ^ ((rb & 7) << 4)));
            rb = wc + 48 + lr;
            bfb = *(const bf16x8*)(Bc + ((rb * 128 + 64 + lg * 16) ^ ((rb & 7) << 4)));
        }
        if (dost) {
            GLL16(Bg + bgo[3] + koff, Bsd + 24576 + ldsw);
        }
        __builtin_amdgcn_s_barrier();
        __builtin_amdgcn_s_setprio(1);
#pragma unroll
        for (int mf = 0; mf < 4; ++mf) acc[mf][2] = MFMA16(af[mf], bfa, acc[mf][2]);
#pragma unroll
        for (int mf = 0; mf < 4; ++mf) acc[mf][3] = MFMA16(af[mf], bfb, acc[mf][3]);
        __builtin_amdgcn_s_setprio(0);
        // ---- tile boundary: counted wait for next tile, block-wide ----
        if (kt < nkt - 2) {
            asm volatile("s_waitcnt vmcnt(6)" ::: "memory");
            __builtin_amdgcn_s_barrier();
        } else if (kt == nkt - 2) {
            asm volatile("s_waitcnt vmcnt(0)" ::: "memory");
            __builtin_amdgcn_s_barrier();
        }
        cur = (cur == 2) ? 0 : cur + 1;
        stg = (stg == 2) ? 0 : stg + 1;
    }

#pragma unroll
    for (int mf = 0; mf < 4; ++mf) {
#pragma unroll
        for (int nf = 0; nf < 4; ++nf) {
#pragma unroll
            for (int r = 0; r < 4; ++r) {
                int m = m0 + wr + mf * 16 + lg * 4 + r;
                int n = n0 + wc + nf * 16 + lr;
                float v = acc[mf][nf][r];
                if constexpr (EPI == 0) {
                    outb[(((m >> 11) * 16 + (n >> 7)) << 18) + ((m & 2047) << 7) + (n & 127)] = f2bf(v);
                } else {
                    size_t idx = (size_t)m * N + n;
                    outf[idx] = v + resf[idx];
                }
            }
        }
    }
}

// ---------------- split-precision GEMM + fused per-head RMSNorm + hi/lo split ----------------
__global__ __launch_bounds__(256, 2)
void gemm3(const u16* __restrict__ Ahi, const u16* __restrict__ Alo,
           const u16* __restrict__ Bhi, const u16* __restrict__ Blo,
           const float* __restrict__ sc,
           u16* __restrict__ ohi, u16* __restrict__ olo, int M, int N, int K)
{
    __shared__ u16 Ah[128 * 64];
    __shared__ u16 Al[128 * 64];
    __shared__ u16 Bh[128 * 64];
    __shared__ u16 Bl[128 * 64];
    __shared__ float ssq[128][2];
    const int tid = threadIdx.x, w = tid >> 6, l = tid & 63;
    const int lr = l & 15, lg = l >> 4;
    const int m0 = blockIdx.y * 128, n0 = blockIdx.x * 128;
    const int wr = (w >> 1) * 64, wc = (w & 1) * 64;
    f32x4 acc[4][4] = {};
    int prow[4], pcol[4];
#pragma unroll
    for (int j = 0; j < 4; ++j) {
        int p = (j * 4 + w) * 1024 + l * 16;
        prow[j] = p >> 7;
        pcol[j] = (p ^ ((prow[j] & 7) << 4)) & 127;
    }
    const size_t ldb = (size_t)K * 2;
    const int nkt = K / 64;
    for (int kt = 0; kt < nkt; ++kt) {
#pragma unroll
        for (int j = 0; j < 4; ++j) {
            size_t ao = (size_t)(m0 + prow[j]) * ldb + kt * 128 + pcol[j];
            size_t bo = (size_t)(n0 + prow[j]) * ldb + kt * 128 + pcol[j];
            GLL16((const char*)Ahi + ao, (char*)Ah + (j * 4 + w) * 1024);
            GLL16((const char*)Alo + ao, (char*)Al + (j * 4 + w) * 1024);
            GLL16((const char*)Bhi + bo, (char*)Bh + (j * 4 + w) * 1024);
            GLL16((const char*)Blo + bo, (char*)Bl + (j * 4 + w) * 1024);
        }
        __syncthreads();
#pragma unroll
        for (int kc = 0; kc < 2; ++kc) {
            bf16x8 ahf[4], alf[4], bhf[4], blf[4];
#pragma unroll
            for (int f = 0; f < 4; ++f) {
                int ra = wr + f * 16 + lr;
                int oa = (ra * 128 + kc * 64 + lg * 16) ^ ((ra & 7) << 4);
                ahf[f] = *(const bf16x8*)((const char*)Ah + oa);
                alf[f] = *(const bf16x8*)((const char*)Al + oa);
                int rb = wc + f * 16 + lr;
                int ob = (rb * 128 + kc * 64 + lg * 16) ^ ((rb & 7) << 4);
                bhf[f] = *(const bf16x8*)((const char*)Bh + ob);
                blf[f] = *(const bf16x8*)((const char*)Bl + ob);
            }
#pragma unroll
            for (int mf = 0; mf < 4; ++mf)
#pragma unroll
                for (int nf = 0; nf < 4; ++nf) {
                    acc[mf][nf] = MFMA16(ahf[mf], bhf[nf], acc[mf][nf]);
                    acc[mf][nf] = MFMA16(ahf[mf], blf[nf], acc[mf][nf]);
                    acc[mf][nf] = MFMA16(alf[mf], bhf[nf], acc[mf][nf]);
                }
        }
        __syncthreads();
    }
    // ---- fused per-head RMSNorm epilogue ----
    float sp[4][4];
#pragma unroll
    for (int mf = 0; mf < 4; ++mf)
#pragma unroll
        for (int r = 0; r < 4; ++r) {
            float s = 0.0f;
#pragma unroll
            for (int nf = 0; nf < 4; ++nf) { float v = acc[mf][nf][r]; s += v * v; }
            s += __shfl_xor(s, 1, 64); s += __shfl_xor(s, 2, 64);
            s += __shfl_xor(s, 4, 64); s += __shfl_xor(s, 8, 64);
            sp[mf][r] = s;
        }
    if (lr == 0) {
#pragma unroll
        for (int mf = 0; mf < 4; ++mf)
#pragma unroll
            for (int r = 0; r < 4; ++r)
                ssq[wr + mf * 16 + lg * 4 + r][w & 1] = sp[mf][r];
    }
    __syncthreads();
    const int head = n0 >> 7;
#pragma unroll
    for (int mf = 0; mf < 4; ++mf)
#pragma unroll
        for (int r = 0; r < 4; ++r) {
            int mloc = wr + mf * 16 + lg * 4 + r;
            int m = m0 + mloc;
            float rs = rsqrtf((ssq[mloc][0] + ssq[mloc][1]) * (1.0f / 128.0f) + 1e-6f);
            size_t base = (((size_t)(m >> 11) * 16 + head) << 18) + ((size_t)(m & 2047) << 7);
#pragma unroll
            for (int nf = 0; nf < 4; ++nf) {
                int hd = wc + nf * 16 + lr;
                float v = acc[mf][nf][r] * rs * sc[hd];
                u16 hv = f2bf(v);
                ohi[base + hd] = hv;
                olo[base + hd] = f2bf(v - bf2f(hv));
            }
        }
}

// ---------------- fused MLP up: g = silu(A@wi0) * (A@wi1), bf16 out ----------------
__global__ __launch_bounds__(256, 2)
void gemm_up(const u16* __restrict__ A, const u16* __restrict__ B0, const u16* __restrict__ B1,
             u16* __restrict__ G, int M, int N, int K)
{
    __shared__ u16 As[128 * 64];
    __shared__ u16 Bs0[128 * 64];
    __shared__ u16 Bs1[128 * 64];
    const int tid = threadIdx.x, w = tid >> 6, l = tid & 63;
    const int lr = l & 15, lg = l >> 4;
    const int m0 = blockIdx.y * 128, n0 = blockIdx.x * 128;
    const int wr = (w >> 1) * 64, wc = (w & 1) * 64;
    f32x4 acc0[4][4] = {}, acc1[4][4] = {};
    int prow[4], pcol[4];
#pragma unroll
    for (int j = 0; j < 4; ++j) {
        int p = (j * 4 + w) * 1024 + l * 16;
        prow[j] = p >> 7;
        pcol[j] = (p ^ ((prow[j] & 7) << 4)) & 127;
    }
    const size_t ldb = (size_t)K * 2;
    const int nkt = K / 64;
    for (int kt = 0; kt < nkt; ++kt) {
#pragma unroll
        for (int j = 0; j < 4; ++j) {
            GLL16((const char*)A + (size_t)(m0 + prow[j]) * ldb + kt * 128 + pcol[j], (char*)As + (j * 4 + w) * 1024);
            GLL16((const char*)B0 + (size_t)(n0 + prow[j]) * ldb + kt * 128 + pcol[j], (char*)Bs0 + (j * 4 + w) * 1024);
            GLL16((const char*)B1 + (size_t)(n0 + prow[j]) * ldb + kt * 128 + pcol[j], (char*)Bs1 + (j * 4 + w) * 1024);
        }
        __syncthreads();
#pragma unroll
        for (int kc = 0; kc < 2; ++kc) {
            bf16x8 af[4], b0f[4], b1f[4];
#pragma unroll
            for (int f = 0; f < 4; ++f) {
                int ra = wr + f * 16 + lr;
                af[f] = *(const bf16x8*)((const char*)As + ((ra * 128 + kc * 64 + lg * 16) ^ ((ra & 7) << 4)));
                int rb = wc + f * 16 + lr;
                int ob = (rb * 128 + kc * 64 + lg * 16) ^ ((rb & 7) << 4);
                b0f[f] = *(const bf16x8*)((const char*)Bs0 + ob);
                b1f[f] = *(const bf16x8*)((const char*)Bs1 + ob);
            }
#pragma unroll
            for (int mf = 0; mf < 4; ++mf)
#pragma unroll
                for (int nf = 0; nf < 4; ++nf) {
                    acc0[mf][nf] = MFMA16(af[mf], b0f[nf], acc0[mf][nf]);
                    acc1[mf][nf] = MFMA16(af[mf], b1f[nf], acc1[mf][nf]);
                }
        }
        __syncthreads();
    }
#pragma unroll
    for (int mf = 0; mf < 4; ++mf) {
#pragma unroll
        for (int nf = 0; nf < 4; ++nf) {
#pragma unroll
            for (int r = 0; r < 4; ++r) {
                int m = m0 + wr + mf * 16 + lg * 4 + r;
                int n = n0 + wc + nf * 16 + lr;
                float a = acc0[mf][nf][r];
                float b = acc1[mf][nf][r];
                G[(size_t)m * N + n] = f2bf(a / (1.0f + __expf(-a)) * b);
            }
        }
    }
}

// ---------------- causal flash attention, split-precision Q,K ----------------
__global__ __launch_bounds__(256, 2)
void flash(const u16* __restrict__ Qh, const u16* __restrict__ Ql,
           const u16* __restrict__ Kh, const u16* __restrict__ Kl,
           const u16* __restrict__ Vt, u16* __restrict__ O)
{
    __shared__ u16 Ksh[64 * 128];
    __shared__ u16 Ksl[64 * 128];
    __shared__ u16 Vs[128 * 64];
    __shared__ u16 Ps[4][16 * 64];
    const int tid = threadIdx.x, w = tid >> 6, l = tid & 63;
    const int lr = l & 15, lg = l >> 4;
    const int qb0 = blockIdx.x * 64, bh = blockIdx.y;

    const size_t qoff = ((size_t)bh * 2048 + qb0 + w * 16) * 128;
    bf16x8 qfh[4], qfl[4];
#pragma unroll
    for (int kc = 0; kc < 4; ++kc) {
        qfh[kc] = *(const bf16x8*)(Qh + qoff + lr * 128 + kc * 32 + lg * 8);
        qfl[kc] = *(const bf16x8*)(Ql + qoff + lr * 128 + kc * 32 + lg * 8);
    }

    f32x4 o[8] = {};
    float mrun[4] = {-1e30f, -1e30f, -1e30f, -1e30f};
    float lrun[4] = {};

    int kgo[4], vdo[4], voff[4];
#pragma unroll
    for (int j = 0; j < 4; ++j) {
        int p = (j * 4 + w) * 1024 + l * 16;
        kgo[j] = p ^ (((p >> 8) & 7) << 4);
        int d = p >> 7, c0 = (p >> 4) & 7;
        vdo[j] = d;
        voff[j] = (c0 ^ (d & 7)) << 4;
    }
    const char* kbh = (const char*)(Kh + (size_t)bh * 2048 * 128);
    const char* kbl = (const char*)(Kl + (size_t)bh * 2048 * 128);
    const char* vbase = (const char*)(Vt + (size_t)bh * 128 * 2048);
    const int tmax = blockIdx.x;

    for (int t = 0; t <= tmax; ++t) {
        const char* kgh = kbh + (size_t)t * 16384;
        const char* kgl = kbl + (size_t)t * 16384;
        const char* vg = vbase + t * 128;
#pragma unroll
        for (int j = 0; j < 4; ++j) {
            GLL16(kgh + kgo[j], (char*)Ksh + (j * 4 + w) * 1024);
            GLL16(kgl + kgo[j], (char*)Ksl + (j * 4 + w) * 1024);
            GLL16(vg + (size_t)vdo[j] * 4096 + voff[j], (char*)Vs + (j * 4 + w) * 1024);
        }
        __syncthreads();

        f32x4 sf[4];
#pragma unroll
        for (int kf = 0; kf < 4; ++kf) {
            f32x4 a = {};
            int row = kf * 16 + lr;
#pragma unroll
            for (int kc = 0; kc < 4; ++kc) {
                int off = (row * 256 + kc * 64 + lg * 16) ^ ((row & 7) << 4);
                bf16x8 khf = *(const bf16x8*)((const char*)Ksh + off);
                bf16x8 klf = *(const bf16x8*)((const char*)Ksl + off);
                a = MFMA16(qfh[kc], khf, a);
                a = MFMA16(qfh[kc], klf, a);
                a = MFMA16(qfl[kc], khf, a);
            }
            sf[kf] = a;
        }
        if (t == tmax) {
#pragma unroll
            for (int kf = 0; kf < 4; ++kf)
#pragma unroll
                for (int r = 0; r < 4; ++r)
                    if (t * 64 + kf * 16 + lr > qb0 + w * 16 + lg * 4 + r) sf[kf][r] = -1e30f;
        }
        float scl[4];
#pragma unroll
        for (int r = 0; r < 4; ++r) {
            float m_ = fmaxf(fmaxf(sf[0][r], sf[1][r]), fmaxf(sf[2][r], sf[3][r]));
            m_ = fmaxf(m_, __shfl_xor(m_, 1, 64));
            m_ = fmaxf(m_, __shfl_xor(m_, 2, 64));
            m_ = fmaxf(m_, __shfl_xor(m_, 4, 64));
            m_ = fmaxf(m_, __shfl_xor(m_, 8, 64));
            float mn = fmaxf(mrun[r], m_);
            scl[r] = __expf(mrun[r] - mn);
            mrun[r] = mn;
            float s_ = 0.0f;
#pragma unroll
            for (int kf = 0; kf < 4; ++kf) {
                float e = __expf(sf[kf][r] - mn);
                sf[kf][r] = e;
                s_ += e;
            }
            s_ += __shfl_xor(s_, 1, 64);
            s_ += __shfl_xor(s_, 2, 64);
            s_ += __shfl_xor(s_, 4, 64);
            s_ += __shfl_xor(s_, 8, 64);
            lrun[r] = lrun[r] * scl[r] + s_;
        }
#pragma unroll
        for (int f = 0; f < 8; ++f) {
            o[f][0] *= scl[0]; o[f][1] *= scl[1]; o[f][2] *= scl[2]; o[f][3] *= scl[3];
        }
        char* pb = (char*)&Ps[w][0];
#pragma unroll
        for (int kf = 0; kf < 4; ++kf)
#pragma unroll
            for (int r = 0; r < 4; ++r) {
                int q = lg * 4 + r;
                int byte = (q * 128 + kf * 32 + lr * 2) ^ ((q & 7) << 4);
                *(u16*)(pb + byte) = f2bf(sf[kf][r]);
            }
        __syncthreads();
#pragma unroll
        for (int kc = 0; kc < 2; ++kc) {
            bf16x8 pa = *(const bf16x8*)(pb + ((lr * 128 + kc * 64 + lg * 16) ^ ((lr & 7) << 4)));
#pragma unroll
            for (int df = 0; df < 8; ++df) {
                int vr = df * 16 + lr;
                bf16x8 vf = *(const bf16x8*)((const char*)Vs +
                    ((vr * 128 + kc * 64 + lg * 16) ^ ((vr & 7) << 4)));
                o[df] = MFMA16(pa, vf, o[df]);
            }
        }
        __syncthreads();
    }
    float inv[4];
#pragma unroll
    for (int r = 0; r < 4; ++r) inv[r] = 1.0f / lrun[r];
    const int b = bh >> 4, h = bh & 15;
#pragma unroll
    for (int df = 0; df < 8; ++df)
#pragma unroll
        for (int r = 0; r < 4; ++r) {
            int q = qb0 + w * 16 + lg * 4 + r;
            int d = df * 16 + lr;
            O[(((size_t)b * 2048 + q) * 16 + h) * 128 + d] = f2bf(o[df][r] * inv[r]);
        }
}

extern "C" void kernel_launch(void* const* d_in, const int* in_sizes, int n_in,
                              void* d_out, int out_size, void* d_ws, size_t ws_size,
                              hipStream_t stream)
{
    (void)in_sizes; (void)n_in;
    const float* x    = (const float*)d_in[0];
    const float* ln1  = (const float*)d_in[1];
    const float* wq   = (const float*)d_in[2];
    const float* wk   = (const float*)d_in[3];
    const float* wv   = (const float*)d_in[4];
    const float* qln  = (const float*)d_in[5];
    const float* kln  = (const float*)d_in[6];
    const float* wo   = (const float*)d_in[7];
    const float* ln2  = (const float*)d_in[8];
    const float* wi0  = (const float*)d_in[9];
    const float* wi1  = (const float*)d_in[10];
    const float* wout = (const float*)d_in[11];

    const size_t MB = 1ull << 20;
    char* ws = (char*)d_ws;
    if (ws_size < 256 * MB) {
        fillsent<<<2048, 256, 0, stream>>>((float*)d_out, out_size, (float)(ws_size >> 20));
        return;
    }

    // allow 144 KiB dynamic LDS for the pipelined GEMM
    (void)hipFuncSetAttribute((const void*)gemm_bt8<0>,
                              hipFuncAttributeMaxDynamicSharedMemorySize, 147456);
    (void)hipFuncSetAttribute((const void*)gemm_bt8<1>,
                              hipFuncAttributeMaxDynamicSharedMemorySize, 147456);

    // Arena (240 MiB used), live-span audited (same as round 10):
    u16* lnx_hi = (u16*)(ws + 0 * MB);
    u16* attn   = (u16*)(ws + 0 * MB);
    u16* lnx_lo = (u16*)(ws + 16 * MB);
    u16* h      = (u16*)(ws + 16 * MB);
    u16* q_hi   = (u16*)(ws + 32 * MB);
    u16* q_lo   = (u16*)(ws + 48 * MB);
    u16* g      = (u16*)(ws + 32 * MB);
    u16* k_hi   = (u16*)(ws + 64 * MB);
    u16* k_lo   = (u16*)(ws + 80 * MB);
    u16* v      = (u16*)(ws + 96 * MB);
    u16* vt     = (u16*)(ws + 112 * MB);
    u16* wo2t   = (u16*)(ws + 96 * MB);
    u16* wqt_hi = (u16*)(ws + 128 * MB);
    u16* wqt_lo = (u16*)(ws + 136 * MB);
    u16* wkt_hi = (u16*)(ws + 144 * MB);
    u16* wkt_lo = (u16*)(ws + 152 * MB);
    float* interp = (float*)(ws + 128 * MB);
    u16* wi0t   = (u16*)(ws + 160 * MB);
    u16* wi1t   = (u16*)(ws + 192 * MB);
    u16* wvt    = (u16*)(ws + 224 * MB);
    u16* wot    = (u16*)(ws + 232 * MB);

    dim3 blk(256);
    wtrans<<<dim3(32, 32), blk, 0, stream>>>(wv, wvt, 2048, 2048);
    wtrans<<<dim3(32, 32), blk, 0, stream>>>(wo, wot, 2048, 2048);
    wtrans<<<dim3(128, 32), blk, 0, stream>>>(wi0, wi0t, 2048, 8192);
    wtrans<<<dim3(128, 32), blk, 0, stream>>>(wi1, wi1t, 2048, 8192);

    rmsnorm_split<<<4096, blk, 0, stream>>>(x, ln1, lnx_hi, lnx_lo);

    wtrans_split<<<dim3(32, 32), blk, 0, stream>>>(wq, wqt_hi, wqt_lo, 2048, 2048);
    gemm3<<<dim3(16, 32), blk, 0, stream>>>(lnx_hi, lnx_lo, wqt_hi, wqt_lo, qln, q_hi, q_lo, 4096, 2048, 2048);

    wtrans_split<<<dim3(32, 32), blk, 0, stream>>>(wk, wkt_hi, wkt_lo, 2048, 2048);
    gemm3<<<dim3(16, 32), blk, 0, stream>>>(lnx_hi, lnx_lo, wkt_hi, wkt_lo, kln, k_hi, k_lo, 4096, 2048, 2048);

    gemm_bt8<0><<<dim3(8, 32), dim3(512), 147456, stream>>>(lnx_hi, wvt, nullptr, v, nullptr, 4096, 2048, 2048);
    vtrans<<<dim3(2, 32, 32), blk, 0, stream>>>(v, vt);

    flash<<<dim3(32, 32), blk, 0, stream>>>(q_hi, q_lo, k_hi, k_lo, vt, attn);

    gemm_bt8<1><<<dim3(8, 32), dim3(512), 147456, stream>>>(attn, wot, interp, nullptr, x, 4096, 2048, 2048);

    rmsnorm_d<<<4096, blk, 0, stream>>>(interp, ln2, h);

    gemm_up<<<dim3(64, 32), blk, 0, stream>>>(h, wi0t, wi1t, g, 4096, 8192, 2048);

    wtrans<<<dim3(32, 128), blk, 0, stream>>>(wout, wo2t, 8192, 2048);
    gemm_bt8<1><<<dim3(8, 32), dim3(512), 147456, stream>>>(g, wo2t, (float*)d_out, nullptr, interp, 4096, 2048, 8192);
}

// Round 12
// 935.939 us; speedup vs baseline: 14.0442x; 1.0538x over previous
//
#include <hip/hip_runtime.h>

typedef unsigned short u16;
typedef unsigned int u32;
typedef __attribute__((ext_vector_type(8))) short bf16x8;
typedef __attribute__((ext_vector_type(2))) float f32x2;
typedef __attribute__((ext_vector_type(4))) float f32x4;
typedef __attribute__((ext_vector_type(4))) u32 u32x4;

#define DEV __device__ __forceinline__

DEV u16 f2bf(float x) {
    u32 u = __builtin_bit_cast(u32, x);
    u += 0x7fffu + ((u >> 16) & 1u);
    return (u16)(u >> 16);
}
DEV float bf2f(u16 b) {
    u32 u = ((u32)b) << 16;
    return __builtin_bit_cast(float, u);
}

#define MFMA16(a, b, c) __builtin_amdgcn_mfma_f32_16x16x32_bf16((a), (b), (c), 0, 0, 0)

// async global->LDS, 16B per lane; LDS dest = wave-uniform base + lane*16
#define GLL16(gp, lp)                                                      \
    __builtin_amdgcn_global_load_lds(                                      \
        (const __attribute__((address_space(1))) u32*)(const void*)(gp),   \
        (__attribute__((address_space(3))) u32*)(void*)(lp), 16, 0, 0)

// ---------------- sentinel (workspace too small -> report ws MiB via absmax) ----------------
__global__ void fillsent(float* __restrict__ out, int n, float val)
{
    for (int i = blockIdx.x * blockDim.x + threadIdx.x; i < n; i += gridDim.x * blockDim.x)
        out[i] = val;
}

// ---------------- weight cast+transpose: f32 [K,N] -> bf16 [N,K] ----------------
__global__ void wtrans(const float* __restrict__ in, u16* __restrict__ out, int K, int N)
{
    __shared__ u16 t[64][65];
    const int n0 = blockIdx.x * 64, k0 = blockIdx.y * 64, tid = threadIdx.x;
    for (int i = tid; i < 4096; i += 256) {
        int r = i >> 6, c = i & 63;
        t[r][c] = f2bf(in[(size_t)(k0 + r) * N + n0 + c]);
    }
    __syncthreads();
    for (int i = tid; i < 4096; i += 256) {
        int r = i >> 6, c = i & 63;
        out[(size_t)(n0 + r) * K + k0 + c] = t[c][r];
    }
}

// ---------------- merged 4x D x D cast+transpose (one launch) ----------------
__global__ void wtrans4(const float* __restrict__ s0, const float* __restrict__ s1,
                        const float* __restrict__ s2, const float* __restrict__ s3,
                        u16* __restrict__ d0, u16* __restrict__ d1,
                        u16* __restrict__ d2, u16* __restrict__ d3)
{
    const float* in;
    u16* out;
    switch (blockIdx.z) {
        case 0: in = s0; out = d0; break;
        case 1: in = s1; out = d1; break;
        case 2: in = s2; out = d2; break;
        default: in = s3; out = d3; break;
    }
    __shared__ u16 t[64][65];
    const int n0 = blockIdx.x * 64, k0 = blockIdx.y * 64, tid = threadIdx.x;
    for (int i = tid; i < 4096; i += 256) {
        int r = i >> 6, c = i & 63;
        t[r][c] = f2bf(in[(size_t)(k0 + r) * 2048 + n0 + c]);
    }
    __syncthreads();
    for (int i = tid; i < 4096; i += 256) {
        int r = i >> 6, c = i & 63;
        out[(size_t)(n0 + r) * 2048 + k0 + c] = t[c][r];
    }
}

// ---------------- V relayout: bf16 [BH,S,128] -> [BH,128,S] ----------------
__global__ void vtrans(const u16* __restrict__ in, u16* __restrict__ out)
{
    __shared__ u16 t[64][65];
    const int d0 = blockIdx.x * 64, s0 = blockIdx.y * 64, bh = blockIdx.z, tid = threadIdx.x;
    const u16* ip = in + (size_t)bh * 2048 * 128;
    u16* op = out + (size_t)bh * 128 * 2048;
    for (int i = tid; i < 4096; i += 256) {
        int r = i >> 6, c = i & 63;
        t[r][c] = ip[(size_t)(s0 + r) * 128 + d0 + c];
    }
    __syncthreads();
    for (int i = tid; i < 4096; i += 256) {
        int r = i >> 6, c = i & 63;
        op[(size_t)(d0 + r) * 2048 + s0 + c] = t[c][r];
    }
}

// ---------------- RMSNorm over D=2048: f32 in -> bf16 out (single) ----------------
__global__ __launch_bounds__(256) void rmsnorm_d(const float* __restrict__ in,
                                                 const float* __restrict__ sc,
                                                 u16* __restrict__ out)
{
    __shared__ float red[4];
    const int row = blockIdx.x, tid = threadIdx.x;
    const float* p = in + (size_t)row * 2048 + tid * 8;
    f32x4 a = *(const f32x4*)p;
    f32x4 b = *(const f32x4*)(p + 4);
    float ss = a[0]*a[0] + a[1]*a[1] + a[2]*a[2] + a[3]*a[3]
             + b[0]*b[0] + b[1]*b[1] + b[2]*b[2] + b[3]*b[3];
    for (int d = 1; d < 64; d <<= 1) ss += __shfl_xor(ss, d, 64);
    if ((tid & 63) == 0) red[tid >> 6] = ss;
    __syncthreads();
    float rs = rsqrtf((red[0] + red[1] + red[2] + red[3]) * (1.0f / 2048.0f) + 1e-6f);
    const float* s = sc + tid * 8;
    u32x4 ov;
#pragma unroll
    for (int i = 0; i < 2; ++i) {
        f32x4 v = i ? b : a;
#pragma unroll
        for (int j = 0; j < 2; ++j) {
            float v0 = v[j * 2] * rs * s[i * 4 + j * 2];
            float v1 = v[j * 2 + 1] * rs * s[i * 4 + j * 2 + 1];
            ov[i * 2 + j] = (u32)f2bf(v0) | ((u32)f2bf(v1) << 16);
        }
    }
    *(u32x4*)(out + (size_t)row * 2048 + tid * 8) = ov;
}

// ---------------- RMSNorm over D=2048: f32 in -> bf16 hi/lo out ----------------
__global__ __launch_bounds__(256) void rmsnorm_split(const float* __restrict__ in,
                                                     const float* __restrict__ sc,
                                                     u16* __restrict__ ohi,
                                                     u16* __restrict__ olo)
{
    __shared__ float red[4];
    const int row = blockIdx.x, tid = threadIdx.x;
    const float* p = in + (size_t)row * 2048 + tid * 8;
    f32x4 a = *(const f32x4*)p;
    f32x4 b = *(const f32x4*)(p + 4);
    float ss = a[0]*a[0] + a[1]*a[1] + a[2]*a[2] + a[3]*a[3]
             + b[0]*b[0] + b[1]*b[1] + b[2]*b[2] + b[3]*b[3];
    for (int d = 1; d < 64; d <<= 1) ss += __shfl_xor(ss, d, 64);
    if ((tid & 63) == 0) red[tid >> 6] = ss;
    __syncthreads();
    float rs = rsqrtf((red[0] + red[1] + red[2] + red[3]) * (1.0f / 2048.0f) + 1e-6f);
    const float* s = sc + tid * 8;
    u32x4 oh, ol;
#pragma unroll
    for (int i = 0; i < 2; ++i) {
        f32x4 v = i ? b : a;
#pragma unroll
        for (int j = 0; j < 2; ++j) {
            float v0 = v[j * 2] * rs * s[i * 4 + j * 2];
            float v1 = v[j * 2 + 1] * rs * s[i * 4 + j * 2 + 1];
            u16 h0 = f2bf(v0), h1 = f2bf(v1);
            u16 l0 = f2bf(v0 - bf2f(h0)), l1 = f2bf(v1 - bf2f(h1));
            oh[i * 2 + j] = (u32)h0 | ((u32)h1 << 16);
            ol[i * 2 + j] = (u32)l0 | ((u32)l1 << 16);
        }
    }
    *(u32x4*)(ohi + (size_t)row * 2048 + tid * 8) = oh;
    *(u32x4*)(olo + (size_t)row * 2048 + tid * 8) = ol;
}

// ---------------- 8-wave pipelined GEMM: C[M,N] = A[M,K] x Bt[N,K] ----------------
template <int EPI>
__global__ __launch_bounds__(512, 2)
void gemm_bt8(const u16* __restrict__ Ap, const u16* __restrict__ Bt,
              float* __restrict__ outf, u16* __restrict__ outb,
              const float* __restrict__ resf, int M, int N, int K)
{
    extern __shared__ char lds[];
    char* AB = lds;
    char* BB = lds + 49152;
    const int tid = threadIdx.x, w = tid >> 6, l = tid & 63;
    const int lr = l & 15, lg = l >> 4;
    const int m0 = blockIdx.y * 128, n0 = blockIdx.x * 256;
    const int wr = (w >> 2) * 64, wc = (w & 3) * 64;
    const size_t ldb = (size_t)K * 2;
    const char* Ag = (const char*)Ap;
    const char* Bg = (const char*)Bt;
    const int ldsw = w * 1024;

    size_t ago[2], bgo[4];
#pragma unroll
    for (int i = 0; i < 2; ++i) {
        int p = (i * 512 + tid) * 16;
        int pr = p >> 7;
        int pc = (p ^ ((pr & 7) << 4)) & 127;
        ago[i] = (size_t)(m0 + pr) * ldb + pc;
    }
#pragma unroll
    for (int i = 0; i < 4; ++i) {
        int p = (i * 512 + tid) * 16;
        int pr = p >> 7;
        int pc = (p ^ ((pr & 7) << 4)) & 127;
        bgo[i] = (size_t)(n0 + pr) * ldb + pc;
    }

    f32x4 acc[4][4] = {};
    const int nkt = K / 64;

    GLL16(Ag + ago[0], AB + ldsw);
    GLL16(Ag + ago[1], AB + 8192 + ldsw);
    GLL16(Bg + bgo[0], BB + ldsw);
    GLL16(Bg + bgo[1], BB + 8192 + ldsw);
    GLL16(Bg + bgo[2], BB + 16384 + ldsw);
    GLL16(Bg + bgo[3], BB + 24576 + ldsw);
    if (nkt > 1) {
        char* Ad = AB + 16384;
        char* Bd = BB + 32768;
        GLL16(Ag + ago[0] + 128, Ad + ldsw);
        GLL16(Ag + ago[1] + 128, Ad + 8192 + ldsw);
        GLL16(Bg + bgo[0] + 128, Bd + ldsw);
        GLL16(Bg + bgo[1] + 128, Bd + 8192 + ldsw);
        GLL16(Bg + bgo[2] + 128, Bd + 16384 + ldsw);
        GLL16(Bg + bgo[3] + 128, Bd + 24576 + ldsw);
        asm volatile("s_waitcnt vmcnt(6)" ::: "memory");
    } else {
        asm volatile("s_waitcnt vmcnt(0)" ::: "memory");
    }
    __builtin_amdgcn_s_barrier();

    int cur = 0, stg = 2;
    for (int kt = 0; kt < nkt; ++kt) {
        char* Ac = AB + cur * 16384;
        char* Bc = BB + cur * 32768;
        char* Asd = AB + stg * 16384;
        char* Bsd = BB + stg * 32768;
        const bool dost = (kt + 2 < nkt);
        const size_t koff = (size_t)(kt + 2) * 128;

        bf16x8 af[4], bfa, bfb;
#pragma unroll
        for (int mf = 0; mf < 4; ++mf) {
            int ra = wr + mf * 16 + lr;
            af[mf] = *(const bf16x8*)(Ac + ((ra * 128 + lg * 16) ^ ((ra & 7) << 4)));
        }
        {
            int rb = wc + lr;
            bfa = *(const bf16x8*)(Bc + ((rb * 128 + lg * 16) ^ ((rb & 7) << 4)));
            rb = wc + 16 + lr;
            bfb = *(const bf16x8*)(Bc + ((rb * 128 + lg * 16) ^ ((rb & 7) << 4)));
        }
        if (dost) {
            GLL16(Ag + ago[0] + koff, Asd + ldsw);
            GLL16(Ag + ago[1] + koff, Asd + 8192 + ldsw);
        }
        __builtin_amdgcn_s_barrier();
        __builtin_amdgcn_s_setprio(1);
#pragma unroll
        for (int mf = 0; mf < 4; ++mf) acc[mf][0] = MFMA16(af[mf], bfa, acc[mf][0]);
#pragma unroll
        for (int mf = 0; mf < 4; ++mf) acc[mf][1] = MFMA16(af[mf], bfb, acc[mf][1]);
        __builtin_amdgcn_s_setprio(0);
        __builtin_amdgcn_s_barrier();
        {
            int rb = wc + 32 + lr;
            bfa = *(const bf16x8*)(Bc + ((rb * 128 + lg * 16) ^ ((rb & 7) << 4)));
            rb = wc + 48 + lr;
            bfb = *(const bf16x8*)(Bc + ((rb * 128 + lg * 16) ^ ((rb & 7) << 4)));
        }
        if (dost) {
            GLL16(Bg + bgo[0] + koff, Bsd + ldsw);
            GLL16(Bg + bgo[1] + koff, Bsd + 8192 + ldsw);
        }
        __builtin_amdgcn_s_barrier();
        __builtin_amdgcn_s_setprio(1);
#pragma unroll
        for (int mf = 0; mf < 4; ++mf) acc[mf][2] = MFMA16(af[mf], bfa, acc[mf][2]);
#pragma unroll
        for (int mf = 0; mf < 4; ++mf) acc[mf][3] = MFMA16(af[mf], bfb, acc[mf][3]);
        __builtin_amdgcn_s_setprio(0);
        __builtin_amdgcn_s_barrier();
#pragma unroll
        for (int mf = 0; mf < 4; ++mf) {
            int ra = wr + mf * 16 + lr;
            af[mf] = *(const bf16x8*)(Ac + ((ra * 128 + 64 + lg * 16) ^ ((ra & 7) << 4)));
        }
        {
            int rb = wc + lr;
            bfa = *(const bf16x8*)(Bc + ((rb * 128 + 64 + lg * 16) ^ ((rb & 7) << 4)));
            rb = wc + 16 + lr;
            bfb = *(const bf16x8*)(Bc + ((rb * 128 + 64 + lg * 16) ^ ((rb & 7) << 4)));
        }
        if (dost) {
            GLL16(Bg + bgo[2] + koff, Bsd + 16384 + ldsw);
        }
        __builtin_amdgcn_s_barrier();
        __builtin_amdgcn_s_setprio(1);
#pragma unroll
        for (int mf = 0; mf < 4; ++mf) acc[mf][0] = MFMA16(af[mf], bfa, acc[mf][0]);
#pragma unroll
        for (int mf = 0; mf < 4; ++mf) acc[mf][1] = MFMA16(af[mf], bfb, acc[mf][1]);
        __builtin_amdgcn_s_setprio(0);
        __builtin_amdgcn_s_barrier();
        {
            int rb = wc + 32 + lr;
            bfa = *(const bf16x8*)(Bc + ((rb * 128 + 64 + lg * 16) ^ ((rb & 7) << 4)));
            rb = wc + 48 + lr;
            bfb = *(const bf16x8*)(Bc + ((rb * 128 + 64 + lg * 16) ^ ((rb & 7) << 4)));
        }
        if (dost) {
            GLL16(Bg + bgo[3] + koff, Bsd + 24576 + ldsw);
        }
        __builtin_amdgcn_s_barrier();
        __builtin_amdgcn_s_setprio(1);
#pragma unroll
        for (int mf = 0; mf < 4; ++mf) acc[mf][2] = MFMA16(af[mf], bfa, acc[mf][2]);
#pragma unroll
        for (int mf = 0; mf < 4; ++mf) acc[mf][3] = MFMA16(af[mf], bfb, acc[mf][3]);
        __builtin_amdgcn_s_setprio(0);
        if (kt < nkt - 2) {
            asm volatile("s_waitcnt vmcnt(6)" ::: "memory");
            __builtin_amdgcn_s_barrier();
        } else if (kt == nkt - 2) {
            asm volatile("s_waitcnt vmcnt(0)" ::: "memory");
            __builtin_amdgcn_s_barrier();
        }
        cur = (cur == 2) ? 0 : cur + 1;
        stg = (stg == 2) ? 0 : stg + 1;
    }

#pragma unroll
    for (int mf = 0; mf < 4; ++mf) {
#pragma unroll
        for (int nf = 0; nf < 4; ++nf) {
#pragma unroll
            for (int r = 0; r < 4; ++r) {
                int m = m0 + wr + mf * 16 + lg * 4 + r;
                int n = n0 + wc + nf * 16 + lr;
                float v = acc[mf][nf][r];
                if constexpr (EPI == 0) {
                    outb[(((m >> 11) * 16 + (n >> 7)) << 18) + ((m & 2047) << 7) + (n & 127)] = f2bf(v);
                } else {
                    size_t idx = (size_t)m * N + n;
                    outf[idx] = v + resf[idx];
                }
            }
        }
    }
}

// ---------------- 2-term split GEMM + fused per-head RMSNorm + hi/lo split ----------------
// C = (Ahi+Alo)(B)^T, then rmsnorm over the block's 128 cols (= one head),
// scaled by sc, written as bf16 hi/lo to [BH,S,128].
__global__ __launch_bounds__(256, 2)
void gemm2(const u16* __restrict__ Ahi, const u16* __restrict__ Alo,
           const u16* __restrict__ Bt, const float* __restrict__ sc,
           u16* __restrict__ ohi, u16* __restrict__ olo, int M, int N, int K)
{
    __shared__ u16 Ah[128 * 64];
    __shared__ u16 Al[128 * 64];
    __shared__ u16 Bh[128 * 64];
    __shared__ float ssq[128][2];
    const int tid = threadIdx.x, w = tid >> 6, l = tid & 63;
    const int lr = l & 15, lg = l >> 4;
    const int m0 = blockIdx.y * 128, n0 = blockIdx.x * 128;
    const int wr = (w >> 1) * 64, wc = (w & 1) * 64;
    f32x4 acc[4][4] = {};
    int prow[4], pcol[4];
#pragma unroll
    for (int j = 0; j < 4; ++j) {
        int p = (j * 4 + w) * 1024 + l * 16;
        prow[j] = p >> 7;
        pcol[j] = (p ^ ((prow[j] & 7) << 4)) & 127;
    }
    const size_t ldb = (size_t)K * 2;
    const int nkt = K / 64;
    for (int kt = 0; kt < nkt; ++kt) {
#pragma unroll
        for (int j = 0; j < 4; ++j) {
            size_t ao = (size_t)(m0 + prow[j]) * ldb + kt * 128 + pcol[j];
            size_t bo = (size_t)(n0 + prow[j]) * ldb + kt * 128 + pcol[j];
            GLL16((const char*)Ahi + ao, (char*)Ah + (j * 4 + w) * 1024);
            GLL16((const char*)Alo + ao, (char*)Al + (j * 4 + w) * 1024);
            GLL16((const char*)Bt + bo, (char*)Bh + (j * 4 + w) * 1024);
        }
        __syncthreads();
#pragma unroll
        for (int kc = 0; kc < 2; ++kc) {
            bf16x8 ahf[4], alf[4], bhf[4];
#pragma unroll
            for (int f = 0; f < 4; ++f) {
                int ra = wr + f * 16 + lr;
                int oa = (ra * 128 + kc * 64 + lg * 16) ^ ((ra & 7) << 4);
                ahf[f] = *(const bf16x8*)((const char*)Ah + oa);
                alf[f] = *(const bf16x8*)((const char*)Al + oa);
                int rb = wc + f * 16 + lr;
                int ob = (rb * 128 + kc * 64 + lg * 16) ^ ((rb & 7) << 4);
                bhf[f] = *(const bf16x8*)((const char*)Bh + ob);
            }
#pragma unroll
            for (int mf = 0; mf < 4; ++mf)
#pragma unroll
                for (int nf = 0; nf < 4; ++nf) {
                    acc[mf][nf] = MFMA16(ahf[mf], bhf[nf], acc[mf][nf]);
                    acc[mf][nf] = MFMA16(alf[mf], bhf[nf], acc[mf][nf]);
                }
        }
        __syncthreads();
    }
    // ---- fused per-head RMSNorm epilogue ----
    float sp[4][4];
#pragma unroll
    for (int mf = 0; mf < 4; ++mf)
#pragma unroll
        for (int r = 0; r < 4; ++r) {
            float s = 0.0f;
#pragma unroll
            for (int nf = 0; nf < 4; ++nf) { float v = acc[mf][nf][r]; s += v * v; }
            s += __shfl_xor(s, 1, 64); s += __shfl_xor(s, 2, 64);
            s += __shfl_xor(s, 4, 64); s += __shfl_xor(s, 8, 64);
            sp[mf][r] = s;
        }
    if (lr == 0) {
#pragma unroll
        for (int mf = 0; mf < 4; ++mf)
#pragma unroll
            for (int r = 0; r < 4; ++r)
                ssq[wr + mf * 16 + lg * 4 + r][w & 1] = sp[mf][r];
    }
    __syncthreads();
    const int head = n0 >> 7;
#pragma unroll
    for (int mf = 0; mf < 4; ++mf)
#pragma unroll
        for (int r = 0; r < 4; ++r) {
            int mloc = wr + mf * 16 + lg * 4 + r;
            int m = m0 + mloc;
            float rs = rsqrtf((ssq[mloc][0] + ssq[mloc][1]) * (1.0f / 128.0f) + 1e-6f);
            size_t base = (((size_t)(m >> 11) * 16 + head) << 18) + ((size_t)(m & 2047) << 7);
#pragma unroll
            for (int nf = 0; nf < 4; ++nf) {
                int hd = wc + nf * 16 + lr;
                float v = acc[mf][nf][r] * rs * sc[hd];
                u16 hv = f2bf(v);
                ohi[base + hd] = hv;
                olo[base + hd] = f2bf(v - bf2f(hv));
            }
        }
}

// ---------------- fused MLP up: g = silu(A@wi0) * (A@wi1), bf16 out ----------------
__global__ __launch_bounds__(256, 2)
void gemm_up(const u16* __restrict__ A, const u16* __restrict__ B0, const u16* __restrict__ B1,
             u16* __restrict__ G, int M, int N, int K)
{
    __shared__ u16 As[128 * 64];
    __shared__ u16 Bs0[128 * 64];
    __shared__ u16 Bs1[128 * 64];
    const int tid = threadIdx.x, w = tid >> 6, l = tid & 63;
    const int lr = l & 15, lg = l >> 4;
    const int m0 = blockIdx.y * 128, n0 = blockIdx.x * 128;
    const int wr = (w >> 1) * 64, wc = (w & 1) * 64;
    f32x4 acc0[4][4] = {}, acc1[4][4] = {};
    int prow[4], pcol[4];
#pragma unroll
    for (int j = 0; j < 4; ++j) {
        int p = (j * 4 + w) * 1024 + l * 16;
        prow[j] = p >> 7;
        pcol[j] = (p ^ ((prow[j] & 7) << 4)) & 127;
    }
    const size_t ldb = (size_t)K * 2;
    const int nkt = K / 64;
    for (int kt = 0; kt < nkt; ++kt) {
#pragma unroll
        for (int j = 0; j < 4; ++j) {
            GLL16((const char*)A + (size_t)(m0 + prow[j]) * ldb + kt * 128 + pcol[j], (char*)As + (j * 4 + w) * 1024);
            GLL16((const char*)B0 + (size_t)(n0 + prow[j]) * ldb + kt * 128 + pcol[j], (char*)Bs0 + (j * 4 + w) * 1024);
            GLL16((const char*)B1 + (size_t)(n0 + prow[j]) * ldb + kt * 128 + pcol[j], (char*)Bs1 + (j * 4 + w) * 1024);
        }
        __syncthreads();
#pragma unroll
        for (int kc = 0; kc < 2; ++kc) {
            bf16x8 af[4], b0f[4], b1f[4];
#pragma unroll
            for (int f = 0; f < 4; ++f) {
                int ra = wr + f * 16 + lr;
                af[f] = *(const bf16x8*)((const char*)As + ((ra * 128 + kc * 64 + lg * 16) ^ ((ra & 7) << 4)));
                int rb = wc + f * 16 + lr;
                int ob = (rb * 128 + kc * 64 + lg * 16) ^ ((rb & 7) << 4);
                b0f[f] = *(const bf16x8*)((const char*)Bs0 + ob);
                b1f[f] = *(const bf16x8*)((const char*)Bs1 + ob);
            }
#pragma unroll
            for (int mf = 0; mf < 4; ++mf)
#pragma unroll
                for (int nf = 0; nf < 4; ++nf) {
                    acc0[mf][nf] = MFMA16(af[mf], b0f[nf], acc0[mf][nf]);
                    acc1[mf][nf] = MFMA16(af[mf], b1f[nf], acc1[mf][nf]);
                }
        }
        __syncthreads();
    }
#pragma unroll
    for (int mf = 0; mf < 4; ++mf) {
#pragma unroll
        for (int nf = 0; nf < 4; ++nf) {
#pragma unroll
            for (int r = 0; r < 4; ++r) {
                int m = m0 + wr + mf * 16 + lg * 4 + r;
                int n = n0 + wc + nf * 16 + lr;
                float a = acc0[mf][nf][r];
                float b = acc1[mf][nf][r];
                G[(size_t)m * N + n] = f2bf(a / (1.0f + __expf(-a)) * b);
            }
        }
    }
}

// ---------------- causal flash attention, split-precision Q,K ----------------
__global__ __launch_bounds__(256, 2)
void flash(const u16* __restrict__ Qh, const u16* __restrict__ Ql,
           const u16* __restrict__ Kh, const u16* __restrict__ Kl,
           const u16* __restrict__ Vt, u16* __restrict__ O)
{
    __shared__ u16 Ksh[64 * 128];
    __shared__ u16 Ksl[64 * 128];
    __shared__ u16 Vs[128 * 64];
    __shared__ u16 Ps[4][16 * 64];
    const int tid = threadIdx.x, w = tid >> 6, l = tid & 63;
    const int lr = l & 15, lg = l >> 4;
    const int qb0 = blockIdx.x * 64, bh = blockIdx.y;

    const size_t qoff = ((size_t)bh * 2048 + qb0 + w * 16) * 128;
    bf16x8 qfh[4], qfl[4];
#pragma unroll
    for (int kc = 0; kc < 4; ++kc) {
        qfh[kc] = *(const bf16x8*)(Qh + qoff + lr * 128 + kc * 32 + lg * 8);
        qfl[kc] = *(const bf16x8*)(Ql + qoff + lr * 128 + kc * 32 + lg * 8);
    }

    f32x4 o[8] = {};
    float mrun[4] = {-1e30f, -1e30f, -1e30f, -1e30f};
    float lrun[4] = {};

    int kgo[4], vdo[4], voff[4];
#pragma unroll
    for (int j = 0; j < 4; ++j) {
        int p = (j * 4 + w) * 1024 + l * 16;
        kgo[j] = p ^ (((p >> 8) & 7) << 4);
        int d = p >> 7, c0 = (p >> 4) & 7;
        vdo[j] = d;
        voff[j] = (c0 ^ (d & 7)) << 4;
    }
    const char* kbh = (const char*)(Kh + (size_t)bh * 2048 * 128);
    const char* kbl = (const char*)(Kl + (size_t)bh * 2048 * 128);
    const char* vbase = (const char*)(Vt + (size_t)bh * 128 * 2048);
    const int tmax = blockIdx.x;

    for (int t = 0; t <= tmax; ++t) {
        const char* kgh = kbh + (size_t)t * 16384;
        const char* kgl = kbl + (size_t)t * 16384;
        const char* vg = vbase + t * 128;
#pragma unroll
        for (int j = 0; j < 4; ++j) {
            GLL16(kgh + kgo[j], (char*)Ksh + (j * 4 + w) * 1024);
            GLL16(kgl + kgo[j], (char*)Ksl + (j * 4 + w) * 1024);
            GLL16(vg + (size_t)vdo[j] * 4096 + voff[j], (char*)Vs + (j * 4 + w) * 1024);
        }
        __syncthreads();

        f32x4 sf[4];
#pragma unroll
        for (int kf = 0; kf < 4; ++kf) {
            f32x4 a = {};
            int row = kf * 16 + lr;
#pragma unroll
            for (int kc = 0; kc < 4; ++kc) {
                int off = (row * 256 + kc * 64 + lg * 16) ^ ((row & 7) << 4);
                bf16x8 khf = *(const bf16x8*)((const char*)Ksh + off);
                bf16x8 klf = *(const bf16x8*)((const char*)Ksl + off);
                a = MFMA16(qfh[kc], khf, a);
                a = MFMA16(qfh[kc], klf, a);
                a = MFMA16(qfl[kc], khf, a);
            }
            sf[kf] = a;
        }
        if (t == tmax) {
#pragma unroll
            for (int kf = 0; kf < 4; ++kf)
#pragma unroll
                for (int r = 0; r < 4; ++r)
                    if (t * 64 + kf * 16 + lr > qb0 + w * 16 + lg * 4 + r) sf[kf][r] = -1e30f;
        }
        float scl[4];
#pragma unroll
        for (int r = 0; r < 4; ++r) {
            float m_ = fmaxf(fmaxf(sf[0][r], sf[1][r]), fmaxf(sf[2][r], sf[3][r]));
            m_ = fmaxf(m_, __shfl_xor(m_, 1, 64));
            m_ = fmaxf(m_, __shfl_xor(m_, 2, 64));
            m_ = fmaxf(m_, __shfl_xor(m_, 4, 64));
            m_ = fmaxf(m_, __shfl_xor(m_, 8, 64));
            float mn = fmaxf(mrun[r], m_);
            scl[r] = __expf(mrun[r] - mn);
            mrun[r] = mn;
            float s_ = 0.0f;
#pragma unroll
            for (int kf = 0; kf < 4; ++kf) {
                float e = __expf(sf[kf][r] - mn);
                sf[kf][r] = e;
                s_ += e;
            }
            s_ += __shfl_xor(s_, 1, 64);
            s_ += __shfl_xor(s_, 2, 64);
            s_ += __shfl_xor(s_, 4, 64);
            s_ += __shfl_xor(s_, 8, 64);
            lrun[r] = lrun[r] * scl[r] + s_;
        }
#pragma unroll
        for (int f = 0; f < 8; ++f) {
            o[f][0] *= scl[0]; o[f][1] *= scl[1]; o[f][2] *= scl[2]; o[f][3] *= scl[3];
        }
        char* pb = (char*)&Ps[w][0];
#pragma unroll
        for (int kf = 0; kf < 4; ++kf)
#pragma unroll
            for (int r = 0; r < 4; ++r) {
                int q = lg * 4 + r;
                int byte = (q * 128 + kf * 32 + lr * 2) ^ ((q & 7) << 4);
                *(u16*)(pb + byte) = f2bf(sf[kf][r]);
            }
        __syncthreads();
#pragma unroll
        for (int kc = 0; kc < 2; ++kc) {
            bf16x8 pa = *(const bf16x8*)(pb + ((lr * 128 + kc * 64 + lg * 16) ^ ((lr & 7) << 4)));
#pragma unroll
            for (int df = 0; df < 8; ++df) {
                int vr = df * 16 + lr;
                bf16x8 vf = *(const bf16x8*)((const char*)Vs +
                    ((vr * 128 + kc * 64 + lg * 16) ^ ((vr & 7) << 4)));
                o[df] = MFMA16(pa, vf, o[df]);
            }
        }
        __syncthreads();
    }
    float inv[4];
#pragma unroll
    for (int r = 0; r < 4; ++r) inv[r] = 1.0f / lrun[r];
    const int b = bh >> 4, h = bh & 15;
#pragma unroll
    for (int df = 0; df < 8; ++df)
#pragma unroll
        for (int r = 0; r < 4; ++r) {
            int q = qb0 + w * 16 + lg * 4 + r;
            int d = df * 16 + lr;
            O[(((size_t)b * 2048 + q) * 16 + h) * 128 + d] = f2bf(o[df][r] * inv[r]);
        }
}

extern "C" void kernel_launch(void* const* d_in, const int* in_sizes, int n_in,
                              void* d_out, int out_size, void* d_ws, size_t ws_size,
                              hipStream_t stream)
{
    (void)in_sizes; (void)n_in;
    const float* x    = (const float*)d_in[0];
    const float* ln1  = (const float*)d_in[1];
    const float* wq   = (const float*)d_in[2];
    const float* wk   = (const float*)d_in[3];
    const float* wv   = (const float*)d_in[4];
    const float* qln  = (const float*)d_in[5];
    const float* kln  = (const float*)d_in[6];
    const float* wo   = (const float*)d_in[7];
    const float* ln2  = (const float*)d_in[8];
    const float* wi0  = (const float*)d_in[9];
    const float* wi1  = (const float*)d_in[10];
    const float* wout = (const float*)d_in[11];

    const size_t MB = 1ull << 20;
    char* ws = (char*)d_ws;
    if (ws_size < 256 * MB) {
        fillsent<<<2048, 256, 0, stream>>>((float*)d_out, out_size, (float)(ws_size >> 20));
        return;
    }

    (void)hipFuncSetAttribute((const void*)gemm_bt8<0>,
                              hipFuncAttributeMaxDynamicSharedMemorySize, 147456);
    (void)hipFuncSetAttribute((const void*)gemm_bt8<1>,
                              hipFuncAttributeMaxDynamicSharedMemorySize, 147456);

    // Arena, live-span audited (deltas from round 11: wqt/wkt now single 8MB each):
    //  [0,16)    lnx_hi -> attn        [16,32)  lnx_lo -> h
    //  [32,64)   q_hi,q_lo -> g.lo     [64,96)  k_hi,k_lo -> g.hi
    //  [96,112)  v \                    [112,128) vt \   -> wo2t [96,128)
    //  [128,136) wqt  [136,144) wkt  -> interp [128,160) f32 (born at wo-gemm)
    //  [160,192) wi0t  [192,224) wi1t  [224,232) wvt  [232,240) wot
    u16* lnx_hi = (u16*)(ws + 0 * MB);
    u16* attn   = (u16*)(ws + 0 * MB);
    u16* lnx_lo = (u16*)(ws + 16 * MB);
    u16* h      = (u16*)(ws + 16 * MB);
    u16* q_hi   = (u16*)(ws + 32 * MB);
    u16* q_lo   = (u16*)(ws + 48 * MB);
    u16* g      = (u16*)(ws + 32 * MB);
    u16* k_hi   = (u16*)(ws + 64 * MB);
    u16* k_lo   = (u16*)(ws + 80 * MB);
    u16* v      = (u16*)(ws + 96 * MB);
    u16* vt     = (u16*)(ws + 112 * MB);
    u16* wo2t   = (u16*)(ws + 96 * MB);
    u16* wqt    = (u16*)(ws + 128 * MB);
    u16* wkt    = (u16*)(ws + 136 * MB);
    float* interp = (float*)(ws + 128 * MB);
    u16* wi0t   = (u16*)(ws + 160 * MB);
    u16* wi1t   = (u16*)(ws + 192 * MB);
    u16* wvt    = (u16*)(ws + 224 * MB);
    u16* wot    = (u16*)(ws + 232 * MB);

    dim3 blk(256);
    // all four D x D weight transposes in one launch
    wtrans4<<<dim3(32, 32, 4), blk, 0, stream>>>(wq, wk, wv, wo, wqt, wkt, wvt, wot);
    wtrans<<<dim3(128, 32), blk, 0, stream>>>(wi0, wi0t, 2048, 8192);
    wtrans<<<dim3(128, 32), blk, 0, stream>>>(wi1, wi1t, 2048, 8192);

    rmsnorm_split<<<4096, blk, 0, stream>>>(x, ln1, lnx_hi, lnx_lo);

    // Q/K paths: 2-term split GEMM (A split, weight single) + fused per-head norm
    gemm2<<<dim3(16, 32), blk, 0, stream>>>(lnx_hi, lnx_lo, wqt, qln, q_hi, q_lo, 4096, 2048, 2048);
    gemm2<<<dim3(16, 32), blk, 0, stream>>>(lnx_hi, lnx_lo, wkt, kln, k_hi, k_lo, 4096, 2048, 2048);

    gemm_bt8<0><<<dim3(8, 32), dim3(512), 147456, stream>>>(lnx_hi, wvt, nullptr, v, nullptr, 4096, 2048, 2048);
    vtrans<<<dim3(2, 32, 32), blk, 0, stream>>>(v, vt);

    flash<<<dim3(32, 32), blk, 0, stream>>>(q_hi, q_lo, k_hi, k_lo, vt, attn);

    gemm_bt8<1><<<dim3(8, 32), dim3(512), 147456, stream>>>(attn, wot, interp, nullptr, x, 4096, 2048, 2048);

    rmsnorm_d<<<4096, blk, 0, stream>>>(interp, ln2, h);

    gemm_up<<<dim3(64, 32), blk, 0, stream>>>(h, wi0t, wi1t, g, 4096, 8192, 2048);

    wtrans<<<dim3(32, 128), blk, 0, stream>>>(wout, wo2t, 8192, 2048);
    gemm_bt8<1><<<dim3(8, 32), dim3(512), 147456, stream>>>(g, wo2t, (float*)d_out, nullptr, interp, 4096, 2048, 8192);
}

// Round 13
// 896.445 us; speedup vs baseline: 14.6629x; 1.0441x over previous
//
#include <hip/hip_runtime.h>

typedef unsigned short u16;
typedef unsigned int u32;
typedef __attribute__((ext_vector_type(8))) short bf16x8;
typedef __attribute__((ext_vector_type(2))) float f32x2;
typedef __attribute__((ext_vector_type(4))) float f32x4;
typedef __attribute__((ext_vector_type(4))) u32 u32x4;
typedef __attribute__((ext_vector_type(4))) unsigned short u16x4;

#define DEV __device__ __forceinline__

DEV u16 f2bf(float x) {
    u32 u = __builtin_bit_cast(u32, x);
    u += 0x7fffu + ((u >> 16) & 1u);
    return (u16)(u >> 16);
}
DEV float bf2f(u16 b) {
    u32 u = ((u32)b) << 16;
    return __builtin_bit_cast(float, u);
}

#define MFMA16(a, b, c) __builtin_amdgcn_mfma_f32_16x16x32_bf16((a), (b), (c), 0, 0, 0)

// async global->LDS, 16B per lane; LDS dest = wave-uniform base + lane*16
#define GLL16(gp, lp)                                                      \
    __builtin_amdgcn_global_load_lds(                                      \
        (const __attribute__((address_space(1))) u32*)(const void*)(gp),   \
        (__attribute__((address_space(3))) u32*)(void*)(lp), 16, 0, 0)

// ---------------- sentinel (workspace too small -> report ws MiB via absmax) ----------------
__global__ void fillsent(float* __restrict__ out, int n, float val)
{
    for (int i = blockIdx.x * blockDim.x + threadIdx.x; i < n; i += gridDim.x * blockDim.x)
        out[i] = val;
}

// ---------------- weight cast+transpose: f32 [K,N] -> bf16 [N,K], vectorized ----------------
__global__ void wtrans(const float* __restrict__ in, u16* __restrict__ out, int K, int N)
{
    __shared__ u16 t[64][66];
    const int n0 = blockIdx.x * 64, k0 = blockIdx.y * 64, tid = threadIdx.x;
#pragma unroll
    for (int i = 0; i < 4; ++i) {
        int e = (i * 256 + tid) * 4;
        int r = e >> 6, c = e & 63;
        f32x4 v = *(const f32x4*)&in[(size_t)(k0 + r) * N + n0 + c];
        t[r][c] = f2bf(v[0]); t[r][c + 1] = f2bf(v[1]);
        t[r][c + 2] = f2bf(v[2]); t[r][c + 3] = f2bf(v[3]);
    }
    __syncthreads();
#pragma unroll
    for (int i = 0; i < 4; ++i) {
        int e = (i * 256 + tid) * 4;
        int r = e >> 6, c = e & 63;
        u16x4 wv;
        wv[0] = t[c][r]; wv[1] = t[c + 1][r]; wv[2] = t[c + 2][r]; wv[3] = t[c + 3][r];
        *(u16x4*)&out[(size_t)(n0 + r) * K + k0 + c] = wv;
    }
}

// ---------------- merged 4x D x D cast+transpose (one launch), vectorized ----------------
__global__ void wtrans4(const float* __restrict__ s0, const float* __restrict__ s1,
                        const float* __restrict__ s2, const float* __restrict__ s3,
                        u16* __restrict__ d0, u16* __restrict__ d1,
                        u16* __restrict__ d2, u16* __restrict__ d3)
{
    const float* in;
    u16* out;
    switch (blockIdx.z) {
        case 0: in = s0; out = d0; break;
        case 1: in = s1; out = d1; break;
        case 2: in = s2; out = d2; break;
        default: in = s3; out = d3; break;
    }
    __shared__ u16 t[64][66];
    const int n0 = blockIdx.x * 64, k0 = blockIdx.y * 64, tid = threadIdx.x;
#pragma unroll
    for (int i = 0; i < 4; ++i) {
        int e = (i * 256 + tid) * 4;
        int r = e >> 6, c = e & 63;
        f32x4 v = *(const f32x4*)&in[(size_t)(k0 + r) * 2048 + n0 + c];
        t[r][c] = f2bf(v[0]); t[r][c + 1] = f2bf(v[1]);
        t[r][c + 2] = f2bf(v[2]); t[r][c + 3] = f2bf(v[3]);
    }
    __syncthreads();
#pragma unroll
    for (int i = 0; i < 4; ++i) {
        int e = (i * 256 + tid) * 4;
        int r = e >> 6, c = e & 63;
        u16x4 wv;
        wv[0] = t[c][r]; wv[1] = t[c + 1][r]; wv[2] = t[c + 2][r]; wv[3] = t[c + 3][r];
        *(u16x4*)&out[(size_t)(n0 + r) * 2048 + k0 + c] = wv;
    }
}

// ---------------- V relayout: bf16 [BH,S,128] -> [BH,128,S] ----------------
__global__ void vtrans(const u16* __restrict__ in, u16* __restrict__ out)
{
    __shared__ u16 t[64][65];
    const int d0 = blockIdx.x * 64, s0 = blockIdx.y * 64, bh = blockIdx.z, tid = threadIdx.x;
    const u16* ip = in + (size_t)bh * 2048 * 128;
    u16* op = out + (size_t)bh * 128 * 2048;
    for (int i = tid; i < 4096; i += 256) {
        int r = i >> 6, c = i & 63;
        t[r][c] = ip[(size_t)(s0 + r) * 128 + d0 + c];
    }
    __syncthreads();
    for (int i = tid; i < 4096; i += 256) {
        int r = i >> 6, c = i & 63;
        op[(size_t)(d0 + r) * 2048 + s0 + c] = t[c][r];
    }
}

// ---------------- RMSNorm over D=2048: f32 in -> bf16 out (single) ----------------
__global__ __launch_bounds__(256) void rmsnorm_d(const float* __restrict__ in,
                                                 const float* __restrict__ sc,
                                                 u16* __restrict__ out)
{
    __shared__ float red[4];
    const int row = blockIdx.x, tid = threadIdx.x;
    const float* p = in + (size_t)row * 2048 + tid * 8;
    f32x4 a = *(const f32x4*)p;
    f32x4 b = *(const f32x4*)(p + 4);
    float ss = a[0]*a[0] + a[1]*a[1] + a[2]*a[2] + a[3]*a[3]
             + b[0]*b[0] + b[1]*b[1] + b[2]*b[2] + b[3]*b[3];
    for (int d = 1; d < 64; d <<= 1) ss += __shfl_xor(ss, d, 64);
    if ((tid & 63) == 0) red[tid >> 6] = ss;
    __syncthreads();
    float rs = rsqrtf((red[0] + red[1] + red[2] + red[3]) * (1.0f / 2048.0f) + 1e-6f);
    const float* s = sc + tid * 8;
    u32x4 ov;
#pragma unroll
    for (int i = 0; i < 2; ++i) {
        f32x4 v = i ? b : a;
#pragma unroll
        for (int j = 0; j < 2; ++j) {
            float v0 = v[j * 2] * rs * s[i * 4 + j * 2];
            float v1 = v[j * 2 + 1] * rs * s[i * 4 + j * 2 + 1];
            ov[i * 2 + j] = (u32)f2bf(v0) | ((u32)f2bf(v1) << 16);
        }
    }
    *(u32x4*)(out + (size_t)row * 2048 + tid * 8) = ov;
}

// ---------------- RMSNorm over D=2048: f32 in -> bf16 hi/lo out ----------------
__global__ __launch_bounds__(256) void rmsnorm_split(const float* __restrict__ in,
                                                     const float* __restrict__ sc,
                                                     u16* __restrict__ ohi,
                                                     u16* __restrict__ olo)
{
    __shared__ float red[4];
    const int row = blockIdx.x, tid = threadIdx.x;
    const float* p = in + (size_t)row * 2048 + tid * 8;
    f32x4 a = *(const f32x4*)p;
    f32x4 b = *(const f32x4*)(p + 4);
    float ss = a[0]*a[0] + a[1]*a[1] + a[2]*a[2] + a[3]*a[3]
             + b[0]*b[0] + b[1]*b[1] + b[2]*b[2] + b[3]*b[3];
    for (int d = 1; d < 64; d <<= 1) ss += __shfl_xor(ss, d, 64);
    if ((tid & 63) == 0) red[tid >> 6] = ss;
    __syncthreads();
    float rs = rsqrtf((red[0] + red[1] + red[2] + red[3]) * (1.0f / 2048.0f) + 1e-6f);
    const float* s = sc + tid * 8;
    u32x4 oh, ol;
#pragma unroll
    for (int i = 0; i < 2; ++i) {
        f32x4 v = i ? b : a;
#pragma unroll
        for (int j = 0; j < 2; ++j) {
            float v0 = v[j * 2] * rs * s[i * 4 + j * 2];
            float v1 = v[j * 2 + 1] * rs * s[i * 4 + j * 2 + 1];
            u16 h0 = f2bf(v0), h1 = f2bf(v1);
            u16 l0 = f2bf(v0 - bf2f(h0)), l1 = f2bf(v1 - bf2f(h1));
            oh[i * 2 + j] = (u32)h0 | ((u32)h1 << 16);
            ol[i * 2 + j] = (u32)l0 | ((u32)l1 << 16);
        }
    }
    *(u32x4*)(ohi + (size_t)row * 2048 + tid * 8) = oh;
    *(u32x4*)(olo + (size_t)row * 2048 + tid * 8) = ol;
}

// ---------------- 8-wave pipelined GEMM: C[M,N] = A[M,K] x Bt[N,K] ----------------
template <int EPI>
__global__ __launch_bounds__(512, 2)
void gemm_bt8(const u16* __restrict__ Ap, const u16* __restrict__ Bt,
              float* __restrict__ outf, u16* __restrict__ outb,
              const float* __restrict__ resf, int M, int N, int K)
{
    extern __shared__ char lds[];
    char* AB = lds;
    char* BB = lds + 49152;
    const int tid = threadIdx.x, w = tid >> 6, l = tid & 63;
    const int lr = l & 15, lg = l >> 4;
    const int m0 = blockIdx.y * 128, n0 = blockIdx.x * 256;
    const int wr = (w >> 2) * 64, wc = (w & 3) * 64;
    const size_t ldb = (size_t)K * 2;
    const char* Ag = (const char*)Ap;
    const char* Bg = (const char*)Bt;
    const int ldsw = w * 1024;

    size_t ago[2], bgo[4];
#pragma unroll
    for (int i = 0; i < 2; ++i) {
        int p = (i * 512 + tid) * 16;
        int pr = p >> 7;
        int pc = (p ^ ((pr & 7) << 4)) & 127;
        ago[i] = (size_t)(m0 + pr) * ldb + pc;
    }
#pragma unroll
    for (int i = 0; i < 4; ++i) {
        int p = (i * 512 + tid) * 16;
        int pr = p >> 7;
        int pc = (p ^ ((pr & 7) << 4)) & 127;
        bgo[i] = (size_t)(n0 + pr) * ldb + pc;
    }

    f32x4 acc[4][4] = {};
    const int nkt = K / 64;

    GLL16(Ag + ago[0], AB + ldsw);
    GLL16(Ag + ago[1], AB + 8192 + ldsw);
    GLL16(Bg + bgo[0], BB + ldsw);
    GLL16(Bg + bgo[1], BB + 8192 + ldsw);
    GLL16(Bg + bgo[2], BB + 16384 + ldsw);
    GLL16(Bg + bgo[3], BB + 24576 + ldsw);
    if (nkt > 1) {
        char* Ad = AB + 16384;
        char* Bd = BB + 32768;
        GLL16(Ag + ago[0] + 128, Ad + ldsw);
        GLL16(Ag + ago[1] + 128, Ad + 8192 + ldsw);
        GLL16(Bg + bgo[0] + 128, Bd + ldsw);
        GLL16(Bg + bgo[1] + 128, Bd + 8192 + ldsw);
        GLL16(Bg + bgo[2] + 128, Bd + 16384 + ldsw);
        GLL16(Bg + bgo[3] + 128, Bd + 24576 + ldsw);
        asm volatile("s_waitcnt vmcnt(6)" ::: "memory");
    } else {
        asm volatile("s_waitcnt vmcnt(0)" ::: "memory");
    }
    __builtin_amdgcn_s_barrier();

    int cur = 0, stg = 2;
    for (int kt = 0; kt < nkt; ++kt) {
        char* Ac = AB + cur * 16384;
        char* Bc = BB + cur * 32768;
        char* Asd = AB + stg * 16384;
        char* Bsd = BB + stg * 32768;
        const bool dost = (kt + 2 < nkt);
        const size_t koff = (size_t)(kt + 2) * 128;

        bf16x8 af[4], bfa, bfb;
#pragma unroll
        for (int mf = 0; mf < 4; ++mf) {
            int ra = wr + mf * 16 + lr;
            af[mf] = *(const bf16x8*)(Ac + ((ra * 128 + lg * 16) ^ ((ra & 7) << 4)));
        }
        {
            int rb = wc + lr;
            bfa = *(const bf16x8*)(Bc + ((rb * 128 + lg * 16) ^ ((rb & 7) << 4)));
            rb = wc + 16 + lr;
            bfb = *(const bf16x8*)(Bc + ((rb * 128 + lg * 16) ^ ((rb & 7) << 4)));
        }
        if (dost) {
            GLL16(Ag + ago[0] + koff, Asd + ldsw);
            GLL16(Ag + ago[1] + koff, Asd + 8192 + ldsw);
        }
        __builtin_amdgcn_s_barrier();
        __builtin_amdgcn_s_setprio(1);
#pragma unroll
        for (int mf = 0; mf < 4; ++mf) acc[mf][0] = MFMA16(af[mf], bfa, acc[mf][0]);
#pragma unroll
        for (int mf = 0; mf < 4; ++mf) acc[mf][1] = MFMA16(af[mf], bfb, acc[mf][1]);
        __builtin_amdgcn_s_setprio(0);
        __builtin_amdgcn_s_barrier();
        {
            int rb = wc + 32 + lr;
            bfa = *(const bf16x8*)(Bc + ((rb * 128 + lg * 16) ^ ((rb & 7) << 4)));
            rb = wc + 48 + lr;
            bfb = *(const bf16x8*)(Bc + ((rb * 128 + lg * 16) ^ ((rb & 7) << 4)));
        }
        if (dost) {
            GLL16(Bg + bgo[0] + koff, Bsd + ldsw);
            GLL16(Bg + bgo[1] + koff, Bsd + 8192 + ldsw);
        }
        __builtin_amdgcn_s_barrier();
        __builtin_amdgcn_s_setprio(1);
#pragma unroll
        for (int mf = 0; mf < 4; ++mf) acc[mf][2] = MFMA16(af[mf], bfa, acc[mf][2]);
#pragma unroll
        for (int mf = 0; mf < 4; ++mf) acc[mf][3] = MFMA16(af[mf], bfb, acc[mf][3]);
        __builtin_amdgcn_s_setprio(0);
        __builtin_amdgcn_s_barrier();
#pragma unroll
        for (int mf = 0; mf < 4; ++mf) {
            int ra = wr + mf * 16 + lr;
            af[mf] = *(const bf16x8*)(Ac + ((ra * 128 + 64 + lg * 16) ^ ((ra & 7) << 4)));
        }
        {
            int rb = wc + lr;
            bfa = *(const bf16x8*)(Bc + ((rb * 128 + 64 + lg * 16) ^ ((rb & 7) << 4)));
            rb = wc + 16 + lr;
            bfb = *(const bf16x8*)(Bc + ((rb * 128 + 64 + lg * 16) ^ ((rb & 7) << 4)));
        }
        if (dost) {
            GLL16(Bg + bgo[2] + koff, Bsd + 16384 + ldsw);
        }
        __builtin_amdgcn_s_barrier();
        __builtin_amdgcn_s_setprio(1);
#pragma unroll
        for (int mf = 0; mf < 4; ++mf) acc[mf][0] = MFMA16(af[mf], bfa, acc[mf][0]);
#pragma unroll
        for (int mf = 0; mf < 4; ++mf) acc[mf][1] = MFMA16(af[mf], bfb, acc[mf][1]);
        __builtin_amdgcn_s_setprio(0);
        __builtin_amdgcn_s_barrier();
        {
            int rb = wc + 32 + lr;
            bfa = *(const bf16x8*)(Bc + ((rb * 128 + 64 + lg * 16) ^ ((rb & 7) << 4)));
            rb = wc + 48 + lr;
            bfb = *(const bf16x8*)(Bc + ((rb * 128 + 64 + lg * 16) ^ ((rb & 7) << 4)));
        }
        if (dost) {
            GLL16(Bg + bgo[3] + koff, Bsd + 24576 + ldsw);
        }
        __builtin_amdgcn_s_barrier();
        __builtin_amdgcn_s_setprio(1);
#pragma unroll
        for (int mf = 0; mf < 4; ++mf) acc[mf][2] = MFMA16(af[mf], bfa, acc[mf][2]);
#pragma unroll
        for (int mf = 0; mf < 4; ++mf) acc[mf][3] = MFMA16(af[mf], bfb, acc[mf][3]);
        __builtin_amdgcn_s_setprio(0);
        if (kt < nkt - 2) {
            asm volatile("s_waitcnt vmcnt(6)" ::: "memory");
            __builtin_amdgcn_s_barrier();
        } else if (kt == nkt - 2) {
            asm volatile("s_waitcnt vmcnt(0)" ::: "memory");
            __builtin_amdgcn_s_barrier();
        }
        cur = (cur == 2) ? 0 : cur + 1;
        stg = (stg == 2) ? 0 : stg + 1;
    }

#pragma unroll
    for (int mf = 0; mf < 4; ++mf) {
#pragma unroll
        for (int nf = 0; nf < 4; ++nf) {
#pragma unroll
            for (int r = 0; r < 4; ++r) {
                int m = m0 + wr + mf * 16 + lg * 4 + r;
                int n = n0 + wc + nf * 16 + lr;
                float v = acc[mf][nf][r];
                if constexpr (EPI == 0) {
                    outb[(((m >> 11) * 16 + (n >> 7)) << 18) + ((m & 2047) << 7) + (n & 127)] = f2bf(v);
                } else {
                    size_t idx = (size_t)m * N + n;
                    outf[idx] = v + resf[idx];
                }
            }
        }
    }
}

// ---------------- fused Q+K split GEMM + per-head RMSNorm + hi/lo split ----------------
// Q = (Ahi+Alo)Bq^T, K = (Ahi+Alo)Bk^T; A staged once for both.
// Each output rmsnorm'd over the block's 128 cols (= one head), written bf16 hi/lo to [BH,S,128].
__global__ __launch_bounds__(256, 2)
void gemm2qk(const u16* __restrict__ Ahi, const u16* __restrict__ Alo,
             const u16* __restrict__ Bq, const u16* __restrict__ Bk,
             const float* __restrict__ qsc, const float* __restrict__ ksc,
             u16* __restrict__ qhi, u16* __restrict__ qlo,
             u16* __restrict__ khi, u16* __restrict__ klo, int M, int N, int K)
{
    __shared__ u16 Ah[128 * 64];
    __shared__ u16 Al[128 * 64];
    __shared__ u16 Bqs[128 * 64];
    __shared__ u16 Bks[128 * 64];
    __shared__ float ssq[128][2];
    __shared__ float ssk[128][2];
    const int tid = threadIdx.x, w = tid >> 6, l = tid & 63;
    const int lr = l & 15, lg = l >> 4;
    const int m0 = blockIdx.y * 128, n0 = blockIdx.x * 128;
    const int wr = (w >> 1) * 64, wc = (w & 1) * 64;
    f32x4 accq[4][4] = {}, acck[4][4] = {};
    int prow[4], pcol[4];
#pragma unroll
    for (int j = 0; j < 4; ++j) {
        int p = (j * 4 + w) * 1024 + l * 16;
        prow[j] = p >> 7;
        pcol[j] = (p ^ ((prow[j] & 7) << 4)) & 127;
    }
    const size_t ldb = (size_t)K * 2;
    const int nkt = K / 64;
    for (int kt = 0; kt < nkt; ++kt) {
#pragma unroll
        for (int j = 0; j < 4; ++j) {
            size_t ao = (size_t)(m0 + prow[j]) * ldb + kt * 128 + pcol[j];
            size_t bo = (size_t)(n0 + prow[j]) * ldb + kt * 128 + pcol[j];
            GLL16((const char*)Ahi + ao, (char*)Ah + (j * 4 + w) * 1024);
            GLL16((const char*)Alo + ao, (char*)Al + (j * 4 + w) * 1024);
            GLL16((const char*)Bq + bo, (char*)Bqs + (j * 4 + w) * 1024);
            GLL16((const char*)Bk + bo, (char*)Bks + (j * 4 + w) * 1024);
        }
        __syncthreads();
#pragma unroll
        for (int kc = 0; kc < 2; ++kc) {
            bf16x8 ahf[4], alf[4], bqf[4], bkf[4];
#pragma unroll
            for (int f = 0; f < 4; ++f) {
                int ra = wr + f * 16 + lr;
                int oa = (ra * 128 + kc * 64 + lg * 16) ^ ((ra & 7) << 4);
                ahf[f] = *(const bf16x8*)((const char*)Ah + oa);
                alf[f] = *(const bf16x8*)((const char*)Al + oa);
                int rb = wc + f * 16 + lr;
                int ob = (rb * 128 + kc * 64 + lg * 16) ^ ((rb & 7) << 4);
                bqf[f] = *(const bf16x8*)((const char*)Bqs + ob);
                bkf[f] = *(const bf16x8*)((const char*)Bks + ob);
            }
#pragma unroll
            for (int mf = 0; mf < 4; ++mf)
#pragma unroll
                for (int nf = 0; nf < 4; ++nf) {
                    accq[mf][nf] = MFMA16(ahf[mf], bqf[nf], accq[mf][nf]);
                    accq[mf][nf] = MFMA16(alf[mf], bqf[nf], accq[mf][nf]);
                    acck[mf][nf] = MFMA16(ahf[mf], bkf[nf], acck[mf][nf]);
                    acck[mf][nf] = MFMA16(alf[mf], bkf[nf], acck[mf][nf]);
                }
        }
        __syncthreads();
    }
    // ---- fused per-head RMSNorm epilogue (Q and K) ----
    float spq[4][4], spk[4][4];
#pragma unroll
    for (int mf = 0; mf < 4; ++mf)
#pragma unroll
        for (int r = 0; r < 4; ++r) {
            float sq = 0.0f, sk = 0.0f;
#pragma unroll
            for (int nf = 0; nf < 4; ++nf) {
                float vq = accq[mf][nf][r]; sq += vq * vq;
                float vk = acck[mf][nf][r]; sk += vk * vk;
            }
            sq += __shfl_xor(sq, 1, 64); sq += __shfl_xor(sq, 2, 64);
            sq += __shfl_xor(sq, 4, 64); sq += __shfl_xor(sq, 8, 64);
            sk += __shfl_xor(sk, 1, 64); sk += __shfl_xor(sk, 2, 64);
            sk += __shfl_xor(sk, 4, 64); sk += __shfl_xor(sk, 8, 64);
            spq[mf][r] = sq;
            spk[mf][r] = sk;
        }
    if (lr == 0) {
#pragma unroll
        for (int mf = 0; mf < 4; ++mf)
#pragma unroll
            for (int r = 0; r < 4; ++r) {
                int mloc = wr + mf * 16 + lg * 4 + r;
                ssq[mloc][w & 1] = spq[mf][r];
                ssk[mloc][w & 1] = spk[mf][r];
            }
    }
    __syncthreads();
    const int head = n0 >> 7;
#pragma unroll
    for (int mf = 0; mf < 4; ++mf)
#pragma unroll
        for (int r = 0; r < 4; ++r) {
            int mloc = wr + mf * 16 + lg * 4 + r;
            int m = m0 + mloc;
            float rsq = rsqrtf((ssq[mloc][0] + ssq[mloc][1]) * (1.0f / 128.0f) + 1e-6f);
            float rsk = rsqrtf((ssk[mloc][0] + ssk[mloc][1]) * (1.0f / 128.0f) + 1e-6f);
            size_t base = (((size_t)(m >> 11) * 16 + head) << 18) + ((size_t)(m & 2047) << 7);
#pragma unroll
            for (int nf = 0; nf < 4; ++nf) {
                int hd = wc + nf * 16 + lr;
                float vq = accq[mf][nf][r] * rsq * qsc[hd];
                u16 hq = f2bf(vq);
                qhi[base + hd] = hq;
                qlo[base + hd] = f2bf(vq - bf2f(hq));
                float vk = acck[mf][nf][r] * rsk * ksc[hd];
                u16 hk = f2bf(vk);
                khi[base + hd] = hk;
                klo[base + hd] = f2bf(vk - bf2f(hk));
            }
        }
}

// ---------------- fused MLP up: g = silu(A@wi0) * (A@wi1), bf16 out ----------------
__global__ __launch_bounds__(256, 2)
void gemm_up(const u16* __restrict__ A, const u16* __restrict__ B0, const u16* __restrict__ B1,
             u16* __restrict__ G, int M, int N, int K)
{
    __shared__ u16 As[128 * 64];
    __shared__ u16 Bs0[128 * 64];
    __shared__ u16 Bs1[128 * 64];
    const int tid = threadIdx.x, w = tid >> 6, l = tid & 63;
    const int lr = l & 15, lg = l >> 4;
    const int m0 = blockIdx.y * 128, n0 = blockIdx.x * 128;
    const int wr = (w >> 1) * 64, wc = (w & 1) * 64;
    f32x4 acc0[4][4] = {}, acc1[4][4] = {};
    int prow[4], pcol[4];
#pragma unroll
    for (int j = 0; j < 4; ++j) {
        int p = (j * 4 + w) * 1024 + l * 16;
        prow[j] = p >> 7;
        pcol[j] = (p ^ ((prow[j] & 7) << 4)) & 127;
    }
    const size_t ldb = (size_t)K * 2;
    const int nkt = K / 64;
    for (int kt = 0; kt < nkt; ++kt) {
#pragma unroll
        for (int j = 0; j < 4; ++j) {
            GLL16((const char*)A + (size_t)(m0 + prow[j]) * ldb + kt * 128 + pcol[j], (char*)As + (j * 4 + w) * 1024);
            GLL16((const char*)B0 + (size_t)(n0 + prow[j]) * ldb + kt * 128 + pcol[j], (char*)Bs0 + (j * 4 + w) * 1024);
            GLL16((const char*)B1 + (size_t)(n0 + prow[j]) * ldb + kt * 128 + pcol[j], (char*)Bs1 + (j * 4 + w) * 1024);
        }
        __syncthreads();
#pragma unroll
        for (int kc = 0; kc < 2; ++kc) {
            bf16x8 af[4], b0f[4], b1f[4];
#pragma unroll
            for (int f = 0; f < 4; ++f) {
                int ra = wr + f * 16 + lr;
                af[f] = *(const bf16x8*)((const char*)As + ((ra * 128 + kc * 64 + lg * 16) ^ ((ra & 7) << 4)));
                int rb = wc + f * 16 + lr;
                int ob = (rb * 128 + kc * 64 + lg * 16) ^ ((rb & 7) << 4);
                b0f[f] = *(const bf16x8*)((const char*)Bs0 + ob);
                b1f[f] = *(const bf16x8*)((const char*)Bs1 + ob);
            }
#pragma unroll
            for (int mf = 0; mf < 4; ++mf)
#pragma unroll
                for (int nf = 0; nf < 4; ++nf) {
                    acc0[mf][nf] = MFMA16(af[mf], b0f[nf], acc0[mf][nf]);
                    acc1[mf][nf] = MFMA16(af[mf], b1f[nf], acc1[mf][nf]);
                }
        }
        __syncthreads();
    }
#pragma unroll
    for (int mf = 0; mf < 4; ++mf) {
#pragma unroll
        for (int nf = 0; nf < 4; ++nf) {
#pragma unroll
            for (int r = 0; r < 4; ++r) {
                int m = m0 + wr + mf * 16 + lg * 4 + r;
                int n = n0 + wc + nf * 16 + lr;
                float a = acc0[mf][nf][r];
                float b = acc1[mf][nf][r];
                G[(size_t)m * N + n] = f2bf(a / (1.0f + __expf(-a)) * b);
            }
        }
    }
}

// ---------------- causal flash attention, split-precision Q,K ----------------
__global__ __launch_bounds__(256, 2)
void flash(const u16* __restrict__ Qh, const u16* __restrict__ Ql,
           const u16* __restrict__ Kh, const u16* __restrict__ Kl,
           const u16* __restrict__ Vt, u16* __restrict__ O)
{
    __shared__ u16 Ksh[64 * 128];
    __shared__ u16 Ksl[64 * 128];
    __shared__ u16 Vs[128 * 64];
    __shared__ u16 Ps[4][16 * 64];
    const int tid = threadIdx.x, w = tid >> 6, l = tid & 63;
    const int lr = l & 15, lg = l >> 4;
    const int qb0 = blockIdx.x * 64, bh = blockIdx.y;

    const size_t qoff = ((size_t)bh * 2048 + qb0 + w * 16) * 128;
    bf16x8 qfh[4], qfl[4];
#pragma unroll
    for (int kc = 0; kc < 4; ++kc) {
        qfh[kc] = *(const bf16x8*)(Qh + qoff + lr * 128 + kc * 32 + lg * 8);
        qfl[kc] = *(const bf16x8*)(Ql + qoff + lr * 128 + kc * 32 + lg * 8);
    }

    f32x4 o[8] = {};
    float mrun[4] = {-1e30f, -1e30f, -1e30f, -1e30f};
    float lrun[4] = {};

    int kgo[4], vdo[4], voff[4];
#pragma unroll
    for (int j = 0; j < 4; ++j) {
        int p = (j * 4 + w) * 1024 + l * 16;
        kgo[j] = p ^ (((p >> 8) & 7) << 4);
        int d = p >> 7, c0 = (p >> 4) & 7;
        vdo[j] = d;
        voff[j] = (c0 ^ (d & 7)) << 4;
    }
    const char* kbh = (const char*)(Kh + (size_t)bh * 2048 * 128);
    const char* kbl = (const char*)(Kl + (size_t)bh * 2048 * 128);
    const char* vbase = (const char*)(Vt + (size_t)bh * 128 * 2048);
    const int tmax = blockIdx.x;

    for (int t = 0; t <= tmax; ++t) {
        const char* kgh = kbh + (size_t)t * 16384;
        const char* kgl = kbl + (size_t)t * 16384;
        const char* vg = vbase + t * 128;
#pragma unroll
        for (int j = 0; j < 4; ++j) {
            GLL16(kgh + kgo[j], (char*)Ksh + (j * 4 + w) * 1024);
            GLL16(kgl + kgo[j], (char*)Ksl + (j * 4 + w) * 1024);
            GLL16(vg + (size_t)vdo[j] * 4096 + voff[j], (char*)Vs + (j * 4 + w) * 1024);
        }
        __syncthreads();

        f32x4 sf[4];
#pragma unroll
        for (int kf = 0; kf < 4; ++kf) {
            f32x4 a = {};
            int row = kf * 16 + lr;
#pragma unroll
            for (int kc = 0; kc < 4; ++kc) {
                int off = (row * 256 + kc * 64 + lg * 16) ^ ((row & 7) << 4);
                bf16x8 khf = *(const bf16x8*)((const char*)Ksh + off);
                bf16x8 klf = *(const bf16x8*)((const char*)Ksl + off);
                a = MFMA16(qfh[kc], khf, a);
                a = MFMA16(qfh[kc], klf, a);
                a = MFMA16(qfl[kc], khf, a);
            }
            sf[kf] = a;
        }
        if (t == tmax) {
#pragma unroll
            for (int kf = 0; kf < 4; ++kf)
#pragma unroll
                for (int r = 0; r < 4; ++r)
                    if (t * 64 + kf * 16 + lr > qb0 + w * 16 + lg * 4 + r) sf[kf][r] = -1e30f;
        }
        float scl[4];
#pragma unroll
        for (int r = 0; r < 4; ++r) {
            float m_ = fmaxf(fmaxf(sf[0][r], sf[1][r]), fmaxf(sf[2][r], sf[3][r]));
            m_ = fmaxf(m_, __shfl_xor(m_, 1, 64));
            m_ = fmaxf(m_, __shfl_xor(m_, 2, 64));
            m_ = fmaxf(m_, __shfl_xor(m_, 4, 64));
            m_ = fmaxf(m_, __shfl_xor(m_, 8, 64));
            float mn = fmaxf(mrun[r], m_);
            scl[r] = __expf(mrun[r] - mn);
            mrun[r] = mn;
            float s_ = 0.0f;
#pragma unroll
            for (int kf = 0; kf < 4; ++kf) {
                float e = __expf(sf[kf][r] - mn);
                sf[kf][r] = e;
                s_ += e;
            }
            s_ += __shfl_xor(s_, 1, 64);
            s_ += __shfl_xor(s_, 2, 64);
            s_ += __shfl_xor(s_, 4, 64);
            s_ += __shfl_xor(s_, 8, 64);
            lrun[r] = lrun[r] * scl[r] + s_;
        }
#pragma unroll
        for (int f = 0; f < 8; ++f) {
            o[f][0] *= scl[0]; o[f][1] *= scl[1]; o[f][2] *= scl[2]; o[f][3] *= scl[3];
        }
        char* pb = (char*)&Ps[w][0];
#pragma unroll
        for (int kf = 0; kf < 4; ++kf)
#pragma unroll
            for (int r = 0; r < 4; ++r) {
                int q = lg * 4 + r;
                int byte = (q * 128 + kf * 32 + lr * 2) ^ ((q & 7) << 4);
                *(u16*)(pb + byte) = f2bf(sf[kf][r]);
            }
        __syncthreads();
#pragma unroll
        for (int kc = 0; kc < 2; ++kc) {
            bf16x8 pa = *(const bf16x8*)(pb + ((lr * 128 + kc * 64 + lg * 16) ^ ((lr & 7) << 4)));
#pragma unroll
            for (int df = 0; df < 8; ++df) {
                int vr = df * 16 + lr;
                bf16x8 vf = *(const bf16x8*)((const char*)Vs +
                    ((vr * 128 + kc * 64 + lg * 16) ^ ((vr & 7) << 4)));
                o[df] = MFMA16(pa, vf, o[df]);
            }
        }
        __syncthreads();
    }
    float inv[4];
#pragma unroll
    for (int r = 0; r < 4; ++r) inv[r] = 1.0f / lrun[r];
    const int b = bh >> 4, h = bh & 15;
#pragma unroll
    for (int df = 0; df < 8; ++df)
#pragma unroll
        for (int r = 0; r < 4; ++r) {
            int q = qb0 + w * 16 + lg * 4 + r;
            int d = df * 16 + lr;
            O[(((size_t)b * 2048 + q) * 16 + h) * 128 + d] = f2bf(o[df][r] * inv[r]);
        }
}

extern "C" void kernel_launch(void* const* d_in, const int* in_sizes, int n_in,
                              void* d_out, int out_size, void* d_ws, size_t ws_size,
                              hipStream_t stream)
{
    (void)in_sizes; (void)n_in;
    const float* x    = (const float*)d_in[0];
    const float* ln1  = (const float*)d_in[1];
    const float* wq   = (const float*)d_in[2];
    const float* wk   = (const float*)d_in[3];
    const float* wv   = (const float*)d_in[4];
    const float* qln  = (const float*)d_in[5];
    const float* kln  = (const float*)d_in[6];
    const float* wo   = (const float*)d_in[7];
    const float* ln2  = (const float*)d_in[8];
    const float* wi0  = (const float*)d_in[9];
    const float* wi1  = (const float*)d_in[10];
    const float* wout = (const float*)d_in[11];

    const size_t MB = 1ull << 20;
    char* ws = (char*)d_ws;
    if (ws_size < 256 * MB) {
        fillsent<<<2048, 256, 0, stream>>>((float*)d_out, out_size, (float)(ws_size >> 20));
        return;
    }

    (void)hipFuncSetAttribute((const void*)gemm_bt8<0>,
                              hipFuncAttributeMaxDynamicSharedMemorySize, 147456);
    (void)hipFuncSetAttribute((const void*)gemm_bt8<1>,
                              hipFuncAttributeMaxDynamicSharedMemorySize, 147456);

    // Arena, live-span audited (same as round 12):
    //  [0,16)    lnx_hi -> attn        [16,32)  lnx_lo -> h
    //  [32,64)   q_hi,q_lo -> g.lo     [64,96)  k_hi,k_lo -> g.hi
    //  [96,112)  v \                    [112,128) vt \   -> wo2t [96,128)
    //  [128,136) wqt  [136,144) wkt  -> interp [128,160) f32 (born at wo-gemm)
    //  [160,192) wi0t  [192,224) wi1t  [224,232) wvt  [232,240) wot
    u16* lnx_hi = (u16*)(ws + 0 * MB);
    u16* attn   = (u16*)(ws + 0 * MB);
    u16* lnx_lo = (u16*)(ws + 16 * MB);
    u16* h      = (u16*)(ws + 16 * MB);
    u16* q_hi   = (u16*)(ws + 32 * MB);
    u16* q_lo   = (u16*)(ws + 48 * MB);
    u16* g      = (u16*)(ws + 32 * MB);
    u16* k_hi   = (u16*)(ws + 64 * MB);
    u16* k_lo   = (u16*)(ws + 80 * MB);
    u16* v      = (u16*)(ws + 96 * MB);
    u16* vt     = (u16*)(ws + 112 * MB);
    u16* wo2t   = (u16*)(ws + 96 * MB);
    u16* wqt    = (u16*)(ws + 128 * MB);
    u16* wkt    = (u16*)(ws + 136 * MB);
    float* interp = (float*)(ws + 128 * MB);
    u16* wi0t   = (u16*)(ws + 160 * MB);
    u16* wi1t   = (u16*)(ws + 192 * MB);
    u16* wvt    = (u16*)(ws + 224 * MB);
    u16* wot    = (u16*)(ws + 232 * MB);

    dim3 blk(256);
    wtrans4<<<dim3(32, 32, 4), blk, 0, stream>>>(wq, wk, wv, wo, wqt, wkt, wvt, wot);
    wtrans<<<dim3(128, 32), blk, 0, stream>>>(wi0, wi0t, 2048, 8192);
    wtrans<<<dim3(128, 32), blk, 0, stream>>>(wi1, wi1t, 2048, 8192);

    rmsnorm_split<<<4096, blk, 0, stream>>>(x, ln1, lnx_hi, lnx_lo);

    // fused Q+K: 2-term split GEMM, A staged once, per-head norms fused
    gemm2qk<<<dim3(16, 32), blk, 0, stream>>>(lnx_hi, lnx_lo, wqt, wkt, qln, kln,
                                              q_hi, q_lo, k_hi, k_lo, 4096, 2048, 2048);

    gemm_bt8<0><<<dim3(8, 32), dim3(512), 147456, stream>>>(lnx_hi, wvt, nullptr, v, nullptr, 4096, 2048, 2048);
    vtrans<<<dim3(2, 32, 32), blk, 0, stream>>>(v, vt);

    flash<<<dim3(32, 32), blk, 0, stream>>>(q_hi, q_lo, k_hi, k_lo, vt, attn);

    gemm_bt8<1><<<dim3(8, 32), dim3(512), 147456, stream>>>(attn, wot, interp, nullptr, x, 4096, 2048, 2048);

    rmsnorm_d<<<4096, blk, 0, stream>>>(interp, ln2, h);

    gemm_up<<<dim3(64, 32), blk, 0, stream>>>(h, wi0t, wi1t, g, 4096, 8192, 2048);

    wtrans<<<dim3(32, 128), blk, 0, stream>>>(wout, wo2t, 8192, 2048);
    gemm_bt8<1><<<dim3(8, 32), dim3(512), 147456, stream>>>(g, wo2t, (float*)d_out, nullptr, interp, 4096, 2048, 8192);
}

// Round 14
// 841.383 us; speedup vs baseline: 15.6225x; 1.0654x over previous
//
#include <hip/hip_runtime.h>

typedef unsigned short u16;
typedef unsigned int u32;
typedef __attribute__((ext_vector_type(8))) short bf16x8;
typedef __attribute__((ext_vector_type(2))) float f32x2;
typedef __attribute__((ext_vector_type(4))) float f32x4;
typedef __attribute__((ext_vector_type(4))) u32 u32x4;
typedef __attribute__((ext_vector_type(4))) unsigned short u16x4;

#define DEV __device__ __forceinline__

DEV u16 f2bf(float x) {
    u32 u = __builtin_bit_cast(u32, x);
    u += 0x7fffu + ((u >> 16) & 1u);
    return (u16)(u >> 16);
}
DEV float bf2f(u16 b) {
    u32 u = ((u32)b) << 16;
    return __builtin_bit_cast(float, u);
}

#define MFMA16(a, b, c) __builtin_amdgcn_mfma_f32_16x16x32_bf16((a), (b), (c), 0, 0, 0)

// async global->LDS, 16B per lane; LDS dest = wave-uniform base + lane*16
#define GLL16(gp, lp)                                                      \
    __builtin_amdgcn_global_load_lds(                                      \
        (const __attribute__((address_space(1))) u32*)(const void*)(gp),   \
        (__attribute__((address_space(3))) u32*)(void*)(lp), 16, 0, 0)

// ---------------- sentinel (workspace too small -> report ws MiB via absmax) ----------------
__global__ void fillsent(float* __restrict__ out, int n, float val)
{
    for (int i = blockIdx.x * blockDim.x + threadIdx.x; i < n; i += gridDim.x * blockDim.x)
        out[i] = val;
}

// ---------------- weight cast+transpose: f32 [K,N] -> bf16 [N,K], vectorized ----------------
__global__ void wtrans(const float* __restrict__ in, u16* __restrict__ out, int K, int N)
{
    __shared__ u16 t[64][66];
    const int n0 = blockIdx.x * 64, k0 = blockIdx.y * 64, tid = threadIdx.x;
#pragma unroll
    for (int i = 0; i < 4; ++i) {
        int e = (i * 256 + tid) * 4;
        int r = e >> 6, c = e & 63;
        f32x4 v = *(const f32x4*)&in[(size_t)(k0 + r) * N + n0 + c];
        t[r][c] = f2bf(v[0]); t[r][c + 1] = f2bf(v[1]);
        t[r][c + 2] = f2bf(v[2]); t[r][c + 3] = f2bf(v[3]);
    }
    __syncthreads();
#pragma unroll
    for (int i = 0; i < 4; ++i) {
        int e = (i * 256 + tid) * 4;
        int r = e >> 6, c = e & 63;
        u16x4 wv;
        wv[0] = t[c][r]; wv[1] = t[c + 1][r]; wv[2] = t[c + 2][r]; wv[3] = t[c + 3][r];
        *(u16x4*)&out[(size_t)(n0 + r) * K + k0 + c] = wv;
    }
}

// ---------------- dual-weight cast+transpose (one launch, z selects) ----------------
__global__ void wtrans2(const float* __restrict__ sa, const float* __restrict__ sb,
                        u16* __restrict__ da, u16* __restrict__ db, int K, int N)
{
    const float* in = blockIdx.z ? sb : sa;
    u16* out = blockIdx.z ? db : da;
    __shared__ u16 t[64][66];
    const int n0 = blockIdx.x * 64, k0 = blockIdx.y * 64, tid = threadIdx.x;
#pragma unroll
    for (int i = 0; i < 4; ++i) {
        int e = (i * 256 + tid) * 4;
        int r = e >> 6, c = e & 63;
        f32x4 v = *(const f32x4*)&in[(size_t)(k0 + r) * N + n0 + c];
        t[r][c] = f2bf(v[0]); t[r][c + 1] = f2bf(v[1]);
        t[r][c + 2] = f2bf(v[2]); t[r][c + 3] = f2bf(v[3]);
    }
    __syncthreads();
#pragma unroll
    for (int i = 0; i < 4; ++i) {
        int e = (i * 256 + tid) * 4;
        int r = e >> 6, c = e & 63;
        u16x4 wv;
        wv[0] = t[c][r]; wv[1] = t[c + 1][r]; wv[2] = t[c + 2][r]; wv[3] = t[c + 3][r];
        *(u16x4*)&out[(size_t)(n0 + r) * K + k0 + c] = wv;
    }
}

// ---------------- merged 4x D x D cast+transpose (one launch), vectorized ----------------
__global__ void wtrans4(const float* __restrict__ s0, const float* __restrict__ s1,
                        const float* __restrict__ s2, const float* __restrict__ s3,
                        u16* __restrict__ d0, u16* __restrict__ d1,
                        u16* __restrict__ d2, u16* __restrict__ d3)
{
    const float* in;
    u16* out;
    switch (blockIdx.z) {
        case 0: in = s0; out = d0; break;
        case 1: in = s1; out = d1; break;
        case 2: in = s2; out = d2; break;
        default: in = s3; out = d3; break;
    }
    __shared__ u16 t[64][66];
    const int n0 = blockIdx.x * 64, k0 = blockIdx.y * 64, tid = threadIdx.x;
#pragma unroll
    for (int i = 0; i < 4; ++i) {
        int e = (i * 256 + tid) * 4;
        int r = e >> 6, c = e & 63;
        f32x4 v = *(const f32x4*)&in[(size_t)(k0 + r) * 2048 + n0 + c];
        t[r][c] = f2bf(v[0]); t[r][c + 1] = f2bf(v[1]);
        t[r][c + 2] = f2bf(v[2]); t[r][c + 3] = f2bf(v[3]);
    }
    __syncthreads();
#pragma unroll
    for (int i = 0; i < 4; ++i) {
        int e = (i * 256 + tid) * 4;
        int r = e >> 6, c = e & 63;
        u16x4 wv;
        wv[0] = t[c][r]; wv[1] = t[c + 1][r]; wv[2] = t[c + 2][r]; wv[3] = t[c + 3][r];
        *(u16x4*)&out[(size_t)(n0 + r) * 2048 + k0 + c] = wv;
    }
}

// ---------------- V relayout: bf16 [BH,S,128] -> [BH,128,S], vectorized ----------------
__global__ void vtrans(const u16* __restrict__ in, u16* __restrict__ out)
{
    __shared__ u16 t[64][68];
    const int d0 = blockIdx.x * 64, s0 = blockIdx.y * 64, bh = blockIdx.z, tid = threadIdx.x;
    const u16* ip = in + (size_t)bh * 2048 * 128;
    u16* op = out + (size_t)bh * 128 * 2048;
#pragma unroll
    for (int i = 0; i < 4; ++i) {
        int e = (i * 256 + tid) * 4;
        int r = e >> 6, c = e & 63;
        u16x4 v = *(const u16x4*)&ip[(size_t)(s0 + r) * 128 + d0 + c];
        t[r][c] = v[0]; t[r][c + 1] = v[1]; t[r][c + 2] = v[2]; t[r][c + 3] = v[3];
    }
    __syncthreads();
#pragma unroll
    for (int i = 0; i < 4; ++i) {
        int e = (i * 256 + tid) * 4;
        int r = e >> 6, c = e & 63;
        u16x4 v;
        v[0] = t[c][r]; v[1] = t[c + 1][r]; v[2] = t[c + 2][r]; v[3] = t[c + 3][r];
        *(u16x4*)&op[(size_t)(d0 + r) * 2048 + s0 + c] = v;
    }
}

// ---------------- RMSNorm over D=2048: f32 in -> bf16 out (single) ----------------
__global__ __launch_bounds__(256) void rmsnorm_d(const float* __restrict__ in,
                                                 const float* __restrict__ sc,
                                                 u16* __restrict__ out)
{
    __shared__ float red[4];
    const int row = blockIdx.x, tid = threadIdx.x;
    const float* p = in + (size_t)row * 2048 + tid * 8;
    f32x4 a = *(const f32x4*)p;
    f32x4 b = *(const f32x4*)(p + 4);
    float ss = a[0]*a[0] + a[1]*a[1] + a[2]*a[2] + a[3]*a[3]
             + b[0]*b[0] + b[1]*b[1] + b[2]*b[2] + b[3]*b[3];
    for (int d = 1; d < 64; d <<= 1) ss += __shfl_xor(ss, d, 64);
    if ((tid & 63) == 0) red[tid >> 6] = ss;
    __syncthreads();
    float rs = rsqrtf((red[0] + red[1] + red[2] + red[3]) * (1.0f / 2048.0f) + 1e-6f);
    const float* s = sc + tid * 8;
    u32x4 ov;
#pragma unroll
    for (int i = 0; i < 2; ++i) {
        f32x4 v = i ? b : a;
#pragma unroll
        for (int j = 0; j < 2; ++j) {
            float v0 = v[j * 2] * rs * s[i * 4 + j * 2];
            float v1 = v[j * 2 + 1] * rs * s[i * 4 + j * 2 + 1];
            ov[i * 2 + j] = (u32)f2bf(v0) | ((u32)f2bf(v1) << 16);
        }
    }
    *(u32x4*)(out + (size_t)row * 2048 + tid * 8) = ov;
}

// ---------------- RMSNorm over D=2048: f32 in -> bf16 hi/lo out ----------------
__global__ __launch_bounds__(256) void rmsnorm_split(const float* __restrict__ in,
                                                     const float* __restrict__ sc,
                                                     u16* __restrict__ ohi,
                                                     u16* __restrict__ olo)
{
    __shared__ float red[4];
    const int row = blockIdx.x, tid = threadIdx.x;
    const float* p = in + (size_t)row * 2048 + tid * 8;
    f32x4 a = *(const f32x4*)p;
    f32x4 b = *(const f32x4*)(p + 4);
    float ss = a[0]*a[0] + a[1]*a[1] + a[2]*a[2] + a[3]*a[3]
             + b[0]*b[0] + b[1]*b[1] + b[2]*b[2] + b[3]*b[3];
    for (int d = 1; d < 64; d <<= 1) ss += __shfl_xor(ss, d, 64);
    if ((tid & 63) == 0) red[tid >> 6] = ss;
    __syncthreads();
    float rs = rsqrtf((red[0] + red[1] + red[2] + red[3]) * (1.0f / 2048.0f) + 1e-6f);
    const float* s = sc + tid * 8;
    u32x4 oh, ol;
#pragma unroll
    for (int i = 0; i < 2; ++i) {
        f32x4 v = i ? b : a;
#pragma unroll
        for (int j = 0; j < 2; ++j) {
            float v0 = v[j * 2] * rs * s[i * 4 + j * 2];
            float v1 = v[j * 2 + 1] * rs * s[i * 4 + j * 2 + 1];
            u16 h0 = f2bf(v0), h1 = f2bf(v1);
            u16 l0 = f2bf(v0 - bf2f(h0)), l1 = f2bf(v1 - bf2f(h1));
            oh[i * 2 + j] = (u32)h0 | ((u32)h1 << 16);
            ol[i * 2 + j] = (u32)l0 | ((u32)l1 << 16);
        }
    }
    *(u32x4*)(ohi + (size_t)row * 2048 + tid * 8) = oh;
    *(u32x4*)(olo + (size_t)row * 2048 + tid * 8) = ol;
}

// ---------------- 8-wave pipelined GEMM: C[M,N] = A[M,K] x Bt[N,K] ----------------
template <int EPI>
__global__ __launch_bounds__(512, 2)
void gemm_bt8(const u16* __restrict__ Ap, const u16* __restrict__ Bt,
              float* __restrict__ outf, u16* __restrict__ outb,
              const float* __restrict__ resf, int M, int N, int K)
{
    extern __shared__ char lds[];
    char* AB = lds;
    char* BB = lds + 49152;
    const int tid = threadIdx.x, w = tid >> 6, l = tid & 63;
    const int lr = l & 15, lg = l >> 4;
    const int m0 = blockIdx.y * 128, n0 = blockIdx.x * 256;
    const int wr = (w >> 2) * 64, wc = (w & 3) * 64;
    const size_t ldb = (size_t)K * 2;
    const char* Ag = (const char*)Ap;
    const char* Bg = (const char*)Bt;
    const int ldsw = w * 1024;

    size_t ago[2], bgo[4];
#pragma unroll
    for (int i = 0; i < 2; ++i) {
        int p = (i * 512 + tid) * 16;
        int pr = p >> 7;
        int pc = (p ^ ((pr & 7) << 4)) & 127;
        ago[i] = (size_t)(m0 + pr) * ldb + pc;
    }
#pragma unroll
    for (int i = 0; i < 4; ++i) {
        int p = (i * 512 + tid) * 16;
        int pr = p >> 7;
        int pc = (p ^ ((pr & 7) << 4)) & 127;
        bgo[i] = (size_t)(n0 + pr) * ldb + pc;
    }

    f32x4 acc[4][4] = {};
    const int nkt = K / 64;

    GLL16(Ag + ago[0], AB + ldsw);
    GLL16(Ag + ago[1], AB + 8192 + ldsw);
    GLL16(Bg + bgo[0], BB + ldsw);
    GLL16(Bg + bgo[1], BB + 8192 + ldsw);
    GLL16(Bg + bgo[2], BB + 16384 + ldsw);
    GLL16(Bg + bgo[3], BB + 24576 + ldsw);
    if (nkt > 1) {
        char* Ad = AB + 16384;
        char* Bd = BB + 32768;
        GLL16(Ag + ago[0] + 128, Ad + ldsw);
        GLL16(Ag + ago[1] + 128, Ad + 8192 + ldsw);
        GLL16(Bg + bgo[0] + 128, Bd + ldsw);
        GLL16(Bg + bgo[1] + 128, Bd + 8192 + ldsw);
        GLL16(Bg + bgo[2] + 128, Bd + 16384 + ldsw);
        GLL16(Bg + bgo[3] + 128, Bd + 24576 + ldsw);
        asm volatile("s_waitcnt vmcnt(6)" ::: "memory");
    } else {
        asm volatile("s_waitcnt vmcnt(0)" ::: "memory");
    }
    __builtin_amdgcn_s_barrier();

    int cur = 0, stg = 2;
    for (int kt = 0; kt < nkt; ++kt) {
        char* Ac = AB + cur * 16384;
        char* Bc = BB + cur * 32768;
        char* Asd = AB + stg * 16384;
        char* Bsd = BB + stg * 32768;
        const bool dost = (kt + 2 < nkt);
        const size_t koff = (size_t)(kt + 2) * 128;

        bf16x8 af[4], bfa, bfb;
#pragma unroll
        for (int mf = 0; mf < 4; ++mf) {
            int ra = wr + mf * 16 + lr;
            af[mf] = *(const bf16x8*)(Ac + ((ra * 128 + lg * 16) ^ ((ra & 7) << 4)));
        }
        {
            int rb = wc + lr;
            bfa = *(const bf16x8*)(Bc + ((rb * 128 + lg * 16) ^ ((rb & 7) << 4)));
            rb = wc + 16 + lr;
            bfb = *(const bf16x8*)(Bc + ((rb * 128 + lg * 16) ^ ((rb & 7) << 4)));
        }
        if (dost) {
            GLL16(Ag + ago[0] + koff, Asd + ldsw);
            GLL16(Ag + ago[1] + koff, Asd + 8192 + ldsw);
        }
        __builtin_amdgcn_s_barrier();
        __builtin_amdgcn_s_setprio(1);
#pragma unroll
        for (int mf = 0; mf < 4; ++mf) acc[mf][0] = MFMA16(af[mf], bfa, acc[mf][0]);
#pragma unroll
        for (int mf = 0; mf < 4; ++mf) acc[mf][1] = MFMA16(af[mf], bfb, acc[mf][1]);
        __builtin_amdgcn_s_setprio(0);
        __builtin_amdgcn_s_barrier();
        {
            int rb = wc + 32 + lr;
            bfa = *(const bf16x8*)(Bc + ((rb * 128 + lg * 16) ^ ((rb & 7) << 4)));
            rb = wc + 48 + lr;
            bfb = *(const bf16x8*)(Bc + ((rb * 128 + lg * 16) ^ ((rb & 7) << 4)));
        }
        if (dost) {
            GLL16(Bg + bgo[0] + koff, Bsd + ldsw);
            GLL16(Bg + bgo[1] + koff, Bsd + 8192 + ldsw);
        }
        __builtin_amdgcn_s_barrier();
        __builtin_amdgcn_s_setprio(1);
#pragma unroll
        for (int mf = 0; mf < 4; ++mf) acc[mf][2] = MFMA16(af[mf], bfa, acc[mf][2]);
#pragma unroll
        for (int mf = 0; mf < 4; ++mf) acc[mf][3] = MFMA16(af[mf], bfb, acc[mf][3]);
        __builtin_amdgcn_s_setprio(0);
        __builtin_amdgcn_s_barrier();
#pragma unroll
        for (int mf = 0; mf < 4; ++mf) {
            int ra = wr + mf * 16 + lr;
            af[mf] = *(const bf16x8*)(Ac + ((ra * 128 + 64 + lg * 16) ^ ((ra & 7) << 4)));
        }
        {
            int rb = wc + lr;
            bfa = *(const bf16x8*)(Bc + ((rb * 128 + 64 + lg * 16) ^ ((rb & 7) << 4)));
            rb = wc + 16 + lr;
            bfb = *(const bf16x8*)(Bc + ((rb * 128 + 64 + lg * 16) ^ ((rb & 7) << 4)));
        }
        if (dost) {
            GLL16(Bg + bgo[2] + koff, Bsd + 16384 + ldsw);
        }
        __builtin_amdgcn_s_barrier();
        __builtin_amdgcn_s_setprio(1);
#pragma unroll
        for (int mf = 0; mf < 4; ++mf) acc[mf][0] = MFMA16(af[mf], bfa, acc[mf][0]);
#pragma unroll
        for (int mf = 0; mf < 4; ++mf) acc[mf][1] = MFMA16(af[mf], bfb, acc[mf][1]);
        __builtin_amdgcn_s_setprio(0);
        __builtin_amdgcn_s_barrier();
        {
            int rb = wc + 32 + lr;
            bfa = *(const bf16x8*)(Bc + ((rb * 128 + 64 + lg * 16) ^ ((rb & 7) << 4)));
            rb = wc + 48 + lr;
            bfb = *(const bf16x8*)(Bc + ((rb * 128 + 64 + lg * 16) ^ ((rb & 7) << 4)));
        }
        if (dost) {
            GLL16(Bg + bgo[3] + koff, Bsd + 24576 + ldsw);
        }
        __builtin_amdgcn_s_barrier();
        __builtin_amdgcn_s_setprio(1);
#pragma unroll
        for (int mf = 0; mf < 4; ++mf) acc[mf][2] = MFMA16(af[mf], bfa, acc[mf][2]);
#pragma unroll
        for (int mf = 0; mf < 4; ++mf) acc[mf][3] = MFMA16(af[mf], bfb, acc[mf][3]);
        __builtin_amdgcn_s_setprio(0);
        if (kt < nkt - 2) {
            asm volatile("s_waitcnt vmcnt(6)" ::: "memory");
            __builtin_amdgcn_s_barrier();
        } else if (kt == nkt - 2) {
            asm volatile("s_waitcnt vmcnt(0)" ::: "memory");
            __builtin_amdgcn_s_barrier();
        }
        cur = (cur == 2) ? 0 : cur + 1;
        stg = (stg == 2) ? 0 : stg + 1;
    }

#pragma unroll
    for (int mf = 0; mf < 4; ++mf) {
#pragma unroll
        for (int nf = 0; nf < 4; ++nf) {
#pragma unroll
            for (int r = 0; r < 4; ++r) {
                int m = m0 + wr + mf * 16 + lg * 4 + r;
                int n = n0 + wc + nf * 16 + lr;
                float v = acc[mf][nf][r];
                if constexpr (EPI == 0) {
                    outb[(((m >> 11) * 16 + (n >> 7)) << 18) + ((m & 2047) << 7) + (n & 127)] = f2bf(v);
                } else {
                    size_t idx = (size_t)m * N + n;
                    outf[idx] = v + resf[idx];
                }
            }
        }
    }
}

// ---------------- fused Q+K split GEMM + per-head RMSNorm ----------------
// Q = (Ahi+Alo)Bq^T -> bf16 hi/lo; K = (Ahi+Alo)Bk^T -> bf16 single.
__global__ __launch_bounds__(256, 2)
void gemm2qk(const u16* __restrict__ Ahi, const u16* __restrict__ Alo,
             const u16* __restrict__ Bq, const u16* __restrict__ Bk,
             const float* __restrict__ qsc, const float* __restrict__ ksc,
             u16* __restrict__ qhi, u16* __restrict__ qlo,
             u16* __restrict__ khi, int M, int N, int K)
{
    __shared__ u16 Ah[128 * 64];
    __shared__ u16 Al[128 * 64];
    __shared__ u16 Bqs[128 * 64];
    __shared__ u16 Bks[128 * 64];
    __shared__ float ssq[128][2];
    __shared__ float ssk[128][2];
    const int tid = threadIdx.x, w = tid >> 6, l = tid & 63;
    const int lr = l & 15, lg = l >> 4;
    const int m0 = blockIdx.y * 128, n0 = blockIdx.x * 128;
    const int wr = (w >> 1) * 64, wc = (w & 1) * 64;
    f32x4 accq[4][4] = {}, acck[4][4] = {};
    int prow[4], pcol[4];
#pragma unroll
    for (int j = 0; j < 4; ++j) {
        int p = (j * 4 + w) * 1024 + l * 16;
        prow[j] = p >> 7;
        pcol[j] = (p ^ ((prow[j] & 7) << 4)) & 127;
    }
    const size_t ldb = (size_t)K * 2;
    const int nkt = K / 64;
    for (int kt = 0; kt < nkt; ++kt) {
#pragma unroll
        for (int j = 0; j < 4; ++j) {
            size_t ao = (size_t)(m0 + prow[j]) * ldb + kt * 128 + pcol[j];
            size_t bo = (size_t)(n0 + prow[j]) * ldb + kt * 128 + pcol[j];
            GLL16((const char*)Ahi + ao, (char*)Ah + (j * 4 + w) * 1024);
            GLL16((const char*)Alo + ao, (char*)Al + (j * 4 + w) * 1024);
            GLL16((const char*)Bq + bo, (char*)Bqs + (j * 4 + w) * 1024);
            GLL16((const char*)Bk + bo, (char*)Bks + (j * 4 + w) * 1024);
        }
        __syncthreads();
#pragma unroll
        for (int kc = 0; kc < 2; ++kc) {
            bf16x8 ahf[4], alf[4], bqf[4], bkf[4];
#pragma unroll
            for (int f = 0; f < 4; ++f) {
                int ra = wr + f * 16 + lr;
                int oa = (ra * 128 + kc * 64 + lg * 16) ^ ((ra & 7) << 4);
                ahf[f] = *(const bf16x8*)((const char*)Ah + oa);
                alf[f] = *(const bf16x8*)((const char*)Al + oa);
                int rb = wc + f * 16 + lr;
                int ob = (rb * 128 + kc * 64 + lg * 16) ^ ((rb & 7) << 4);
                bqf[f] = *(const bf16x8*)((const char*)Bqs + ob);
                bkf[f] = *(const bf16x8*)((const char*)Bks + ob);
            }
#pragma unroll
            for (int mf = 0; mf < 4; ++mf)
#pragma unroll
                for (int nf = 0; nf < 4; ++nf) {
                    accq[mf][nf] = MFMA16(ahf[mf], bqf[nf], accq[mf][nf]);
                    accq[mf][nf] = MFMA16(alf[mf], bqf[nf], accq[mf][nf]);
                    acck[mf][nf] = MFMA16(ahf[mf], bkf[nf], acck[mf][nf]);
                    acck[mf][nf] = MFMA16(alf[mf], bkf[nf], acck[mf][nf]);
                }
        }
        __syncthreads();
    }
    // ---- fused per-head RMSNorm epilogue (Q and K) ----
    float spq[4][4], spk[4][4];
#pragma unroll
    for (int mf = 0; mf < 4; ++mf)
#pragma unroll
        for (int r = 0; r < 4; ++r) {
            float sq = 0.0f, sk = 0.0f;
#pragma unroll
            for (int nf = 0; nf < 4; ++nf) {
                float vq = accq[mf][nf][r]; sq += vq * vq;
                float vk = acck[mf][nf][r]; sk += vk * vk;
            }
            sq += __shfl_xor(sq, 1, 64); sq += __shfl_xor(sq, 2, 64);
            sq += __shfl_xor(sq, 4, 64); sq += __shfl_xor(sq, 8, 64);
            sk += __shfl_xor(sk, 1, 64); sk += __shfl_xor(sk, 2, 64);
            sk += __shfl_xor(sk, 4, 64); sk += __shfl_xor(sk, 8, 64);
            spq[mf][r] = sq;
            spk[mf][r] = sk;
        }
    if (lr == 0) {
#pragma unroll
        for (int mf = 0; mf < 4; ++mf)
#pragma unroll
            for (int r = 0; r < 4; ++r) {
                int mloc = wr + mf * 16 + lg * 4 + r;
                ssq[mloc][w & 1] = spq[mf][r];
                ssk[mloc][w & 1] = spk[mf][r];
            }
    }
    __syncthreads();
    const int head = n0 >> 7;
#pragma unroll
    for (int mf = 0; mf < 4; ++mf)
#pragma unroll
        for (int r = 0; r < 4; ++r) {
            int mloc = wr + mf * 16 + lg * 4 + r;
            int m = m0 + mloc;
            float rsq = rsqrtf((ssq[mloc][0] + ssq[mloc][1]) * (1.0f / 128.0f) + 1e-6f);
            float rsk = rsqrtf((ssk[mloc][0] + ssk[mloc][1]) * (1.0f / 128.0f) + 1e-6f);
            size_t base = (((size_t)(m >> 11) * 16 + head) << 18) + ((size_t)(m & 2047) << 7);
#pragma unroll
            for (int nf = 0; nf < 4; ++nf) {
                int hd = wc + nf * 16 + lr;
                float vq = accq[mf][nf][r] * rsq * qsc[hd];
                u16 hq = f2bf(vq);
                qhi[base + hd] = hq;
                qlo[base + hd] = f2bf(vq - bf2f(hq));
                khi[base + hd] = f2bf(acck[mf][nf][r] * rsk * ksc[hd]);
            }
        }
}

// ---------------- fused MLP up: g = silu(A@wi0) * (A@wi1), bf16 out ----------------
__global__ __launch_bounds__(256, 2)
void gemm_up(const u16* __restrict__ A, const u16* __restrict__ B0, const u16* __restrict__ B1,
             u16* __restrict__ G, int M, int N, int K)
{
    __shared__ u16 As[128 * 64];
    __shared__ u16 Bs0[128 * 64];
    __shared__ u16 Bs1[128 * 64];
    const int tid = threadIdx.x, w = tid >> 6, l = tid & 63;
    const int lr = l & 15, lg = l >> 4;
    const int m0 = blockIdx.y * 128, n0 = blockIdx.x * 128;
    const int wr = (w >> 1) * 64, wc = (w & 1) * 64;
    f32x4 acc0[4][4] = {}, acc1[4][4] = {};
    int prow[4], pcol[4];
#pragma unroll
    for (int j = 0; j < 4; ++j) {
        int p = (j * 4 + w) * 1024 + l * 16;
        prow[j] = p >> 7;
        pcol[j] = (p ^ ((prow[j] & 7) << 4)) & 127;
    }
    const size_t ldb = (size_t)K * 2;
    const int nkt = K / 64;
    for (int kt = 0; kt < nkt; ++kt) {
#pragma unroll
        for (int j = 0; j < 4; ++j) {
            GLL16((const char*)A + (size_t)(m0 + prow[j]) * ldb + kt * 128 + pcol[j], (char*)As + (j * 4 + w) * 1024);
            GLL16((const char*)B0 + (size_t)(n0 + prow[j]) * ldb + kt * 128 + pcol[j], (char*)Bs0 + (j * 4 + w) * 1024);
            GLL16((const char*)B1 + (size_t)(n0 + prow[j]) * ldb + kt * 128 + pcol[j], (char*)Bs1 + (j * 4 + w) * 1024);
        }
        __syncthreads();
#pragma unroll
        for (int kc = 0; kc < 2; ++kc) {
            bf16x8 af[4], b0f[4], b1f[4];
#pragma unroll
            for (int f = 0; f < 4; ++f) {
                int ra = wr + f * 16 + lr;
                af[f] = *(const bf16x8*)((const char*)As + ((ra * 128 + kc * 64 + lg * 16) ^ ((ra & 7) << 4)));
                int rb = wc + f * 16 + lr;
                int ob = (rb * 128 + kc * 64 + lg * 16) ^ ((rb & 7) << 4);
                b0f[f] = *(const bf16x8*)((const char*)Bs0 + ob);
                b1f[f] = *(const bf16x8*)((const char*)Bs1 + ob);
            }
#pragma unroll
            for (int mf = 0; mf < 4; ++mf)
#pragma unroll
                for (int nf = 0; nf < 4; ++nf) {
                    acc0[mf][nf] = MFMA16(af[mf], b0f[nf], acc0[mf][nf]);
                    acc1[mf][nf] = MFMA16(af[mf], b1f[nf], acc1[mf][nf]);
                }
        }
        __syncthreads();
    }
#pragma unroll
    for (int mf = 0; mf < 4; ++mf) {
#pragma unroll
        for (int nf = 0; nf < 4; ++nf) {
#pragma unroll
            for (int r = 0; r < 4; ++r) {
                int m = m0 + wr + mf * 16 + lg * 4 + r;
                int n = n0 + wc + nf * 16 + lr;
                float a = acc0[mf][nf][r];
                float b = acc1[mf][nf][r];
                G[(size_t)m * N + n] = f2bf(a / (1.0f + __expf(-a)) * b);
            }
        }
    }
}

// ---------------- causal flash attention: Q split (hi+lo), K single bf16 ----------------
__global__ __launch_bounds__(256, 2)
void flash(const u16* __restrict__ Qh, const u16* __restrict__ Ql,
           const u16* __restrict__ Kh, const u16* __restrict__ Vt,
           u16* __restrict__ O)
{
    __shared__ u16 Ksh[64 * 128];  // 16KB
    __shared__ u16 Vs[128 * 64];   // 16KB
    __shared__ u16 Ps[4][16 * 64]; // 8KB
    const int tid = threadIdx.x, w = tid >> 6, l = tid & 63;
    const int lr = l & 15, lg = l >> 4;
    const int qb0 = blockIdx.x * 64, bh = blockIdx.y;

    const size_t qoff = ((size_t)bh * 2048 + qb0 + w * 16) * 128;
    bf16x8 qfh[4], qfl[4];
#pragma unroll
    for (int kc = 0; kc < 4; ++kc) {
        qfh[kc] = *(const bf16x8*)(Qh + qoff + lr * 128 + kc * 32 + lg * 8);
        qfl[kc] = *(const bf16x8*)(Ql + qoff + lr * 128 + kc * 32 + lg * 8);
    }

    f32x4 o[8] = {};
    float mrun[4] = {-1e30f, -1e30f, -1e30f, -1e30f};
    float lrun[4] = {};

    int kgo[4], vdo[4], voff[4];
#pragma unroll
    for (int j = 0; j < 4; ++j) {
        int p = (j * 4 + w) * 1024 + l * 16;
        kgo[j] = p ^ (((p >> 8) & 7) << 4);
        int d = p >> 7, c0 = (p >> 4) & 7;
        vdo[j] = d;
        voff[j] = (c0 ^ (d & 7)) << 4;
    }
    const char* kbh = (const char*)(Kh + (size_t)bh * 2048 * 128);
    const char* vbase = (const char*)(Vt + (size_t)bh * 128 * 2048);
    const int tmax = blockIdx.x;

    for (int t = 0; t <= tmax; ++t) {
        const char* kgh = kbh + (size_t)t * 16384;
        const char* vg = vbase + t * 128;
#pragma unroll
        for (int j = 0; j < 4; ++j) {
            GLL16(kgh + kgo[j], (char*)Ksh + (j * 4 + w) * 1024);
            GLL16(vg + (size_t)vdo[j] * 4096 + voff[j], (char*)Vs + (j * 4 + w) * 1024);
        }
        __syncthreads();

        // S = (Qh+Ql) K^T
        f32x4 sf[4];
#pragma unroll
        for (int kf = 0; kf < 4; ++kf) {
            f32x4 a = {};
            int row = kf * 16 + lr;
#pragma unroll
            for (int kc = 0; kc < 4; ++kc) {
                int off = (row * 256 + kc * 64 + lg * 16) ^ ((row & 7) << 4);
                bf16x8 khf = *(const bf16x8*)((const char*)Ksh + off);
                a = MFMA16(qfh[kc], khf, a);
                a = MFMA16(qfl[kc], khf, a);
            }
            sf[kf] = a;
        }
        if (t == tmax) {
#pragma unroll
            for (int kf = 0; kf < 4; ++kf)
#pragma unroll
                for (int r = 0; r < 4; ++r)
                    if (t * 64 + kf * 16 + lr > qb0 + w * 16 + lg * 4 + r) sf[kf][r] = -1e30f;
        }
        float scl[4];
#pragma unroll
        for (int r = 0; r < 4; ++r) {
            float m_ = fmaxf(fmaxf(sf[0][r], sf[1][r]), fmaxf(sf[2][r], sf[3][r]));
            m_ = fmaxf(m_, __shfl_xor(m_, 1, 64));
            m_ = fmaxf(m_, __shfl_xor(m_, 2, 64));
            m_ = fmaxf(m_, __shfl_xor(m_, 4, 64));
            m_ = fmaxf(m_, __shfl_xor(m_, 8, 64));
            float mn = fmaxf(mrun[r], m_);
            scl[r] = __expf(mrun[r] - mn);
            mrun[r] = mn;
            float s_ = 0.0f;
#pragma unroll
            for (int kf = 0; kf < 4; ++kf) {
                float e = __expf(sf[kf][r] - mn);
                sf[kf][r] = e;
                s_ += e;
            }
            s_ += __shfl_xor(s_, 1, 64);
            s_ += __shfl_xor(s_, 2, 64);
            s_ += __shfl_xor(s_, 4, 64);
            s_ += __shfl_xor(s_, 8, 64);
            lrun[r] = lrun[r] * scl[r] + s_;
        }
#pragma unroll
        for (int f = 0; f < 8; ++f) {
            o[f][0] *= scl[0]; o[f][1] *= scl[1]; o[f][2] *= scl[2]; o[f][3] *= scl[3];
        }
        char* pb = (char*)&Ps[w][0];
#pragma unroll
        for (int kf = 0; kf < 4; ++kf)
#pragma unroll
            for (int r = 0; r < 4; ++r) {
                int q = lg * 4 + r;
                int byte = (q * 128 + kf * 32 + lr * 2) ^ ((q & 7) << 4);
                *(u16*)(pb + byte) = f2bf(sf[kf][r]);
            }
        __syncthreads();
#pragma unroll
        for (int kc = 0; kc < 2; ++kc) {
            bf16x8 pa = *(const bf16x8*)(pb + ((lr * 128 + kc * 64 + lg * 16) ^ ((lr & 7) << 4)));
#pragma unroll
            for (int df = 0; df < 8; ++df) {
                int vr = df * 16 + lr;
                bf16x8 vf = *(const bf16x8*)((const char*)Vs +
                    ((vr * 128 + kc * 64 + lg * 16) ^ ((vr & 7) << 4)));
                o[df] = MFMA16(pa, vf, o[df]);
            }
        }
        __syncthreads();
    }
    float inv[4];
#pragma unroll
    for (int r = 0; r < 4; ++r) inv[r] = 1.0f / lrun[r];
    const int b = bh >> 4, h = bh & 15;
#pragma unroll
    for (int df = 0; df < 8; ++df)
#pragma unroll
        for (int r = 0; r < 4; ++r) {
            int q = qb0 + w * 16 + lg * 4 + r;
            int d = df * 16 + lr;
            O[(((size_t)b * 2048 + q) * 16 + h) * 128 + d] = f2bf(o[df][r] * inv[r]);
        }
}

extern "C" void kernel_launch(void* const* d_in, const int* in_sizes, int n_in,
                              void* d_out, int out_size, void* d_ws, size_t ws_size,
                              hipStream_t stream)
{
    (void)in_sizes; (void)n_in;
    const float* x    = (const float*)d_in[0];
    const float* ln1  = (const float*)d_in[1];
    const float* wq   = (const float*)d_in[2];
    const float* wk   = (const float*)d_in[3];
    const float* wv   = (const float*)d_in[4];
    const float* qln  = (const float*)d_in[5];
    const float* kln  = (const float*)d_in[6];
    const float* wo   = (const float*)d_in[7];
    const float* ln2  = (const float*)d_in[8];
    const float* wi0  = (const float*)d_in[9];
    const float* wi1  = (const float*)d_in[10];
    const float* wout = (const float*)d_in[11];

    const size_t MB = 1ull << 20;
    char* ws = (char*)d_ws;
    if (ws_size < 256 * MB) {
        fillsent<<<2048, 256, 0, stream>>>((float*)d_out, out_size, (float)(ws_size >> 20));
        return;
    }

    (void)hipFuncSetAttribute((const void*)gemm_bt8<0>,
                              hipFuncAttributeMaxDynamicSharedMemorySize, 147456);
    (void)hipFuncSetAttribute((const void*)gemm_bt8<1>,
                              hipFuncAttributeMaxDynamicSharedMemorySize, 147456);

    // Arena, live-span audited (delta from round 13: k_lo slot unused):
    //  [0,16)    lnx_hi -> attn        [16,32)  lnx_lo -> h
    //  [32,64)   q_hi,q_lo -> g.lo     [64,80)  k (single) ; [80,96) free -> g.hi
    //  [96,112)  v \                    [112,128) vt \   -> wo2t [96,128)
    //  [128,136) wqt  [136,144) wkt  -> interp [128,160) f32 (born at wo-gemm)
    //  [160,192) wi0t  [192,224) wi1t  [224,232) wvt  [232,240) wot
    u16* lnx_hi = (u16*)(ws + 0 * MB);
    u16* attn   = (u16*)(ws + 0 * MB);
    u16* lnx_lo = (u16*)(ws + 16 * MB);
    u16* h      = (u16*)(ws + 16 * MB);
    u16* q_hi   = (u16*)(ws + 32 * MB);
    u16* q_lo   = (u16*)(ws + 48 * MB);
    u16* g      = (u16*)(ws + 32 * MB);
    u16* k_hi   = (u16*)(ws + 64 * MB);
    u16* v      = (u16*)(ws + 96 * MB);
    u16* vt     = (u16*)(ws + 112 * MB);
    u16* wo2t   = (u16*)(ws + 96 * MB);
    u16* wqt    = (u16*)(ws + 128 * MB);
    u16* wkt    = (u16*)(ws + 136 * MB);
    float* interp = (float*)(ws + 128 * MB);
    u16* wi0t   = (u16*)(ws + 160 * MB);
    u16* wi1t   = (u16*)(ws + 192 * MB);
    u16* wvt    = (u16*)(ws + 224 * MB);
    u16* wot    = (u16*)(ws + 232 * MB);

    dim3 blk(256);
    wtrans4<<<dim3(32, 32, 4), blk, 0, stream>>>(wq, wk, wv, wo, wqt, wkt, wvt, wot);
    wtrans2<<<dim3(128, 32, 2), blk, 0, stream>>>(wi0, wi1, wi0t, wi1t, 2048, 8192);

    rmsnorm_split<<<4096, blk, 0, stream>>>(x, ln1, lnx_hi, lnx_lo);

    // fused Q+K: Q split hi/lo, K single bf16
    gemm2qk<<<dim3(16, 32), blk, 0, stream>>>(lnx_hi, lnx_lo, wqt, wkt, qln, kln,
                                              q_hi, q_lo, k_hi, 4096, 2048, 2048);

    gemm_bt8<0><<<dim3(8, 32), dim3(512), 147456, stream>>>(lnx_hi, wvt, nullptr, v, nullptr, 4096, 2048, 2048);
    vtrans<<<dim3(2, 32, 32), blk, 0, stream>>>(v, vt);

    flash<<<dim3(32, 32), blk, 0, stream>>>(q_hi, q_lo, k_hi, vt, attn);

    gemm_bt8<1><<<dim3(8, 32), dim3(512), 147456, stream>>>(attn, wot, interp, nullptr, x, 4096, 2048, 2048);

    rmsnorm_d<<<4096, blk, 0, stream>>>(interp, ln2, h);

    gemm_up<<<dim3(64, 32), blk, 0, stream>>>(h, wi0t, wi1t, g, 4096, 8192, 2048);

    wtrans<<<dim3(32, 128), blk, 0, stream>>>(wout, wo2t, 8192, 2048);
    gemm_bt8<1><<<dim3(8, 32), dim3(512), 147456, stream>>>(g, wo2t, (float*)d_out, nullptr, interp, 4096, 2048, 8192);
}